// Round 20
// baseline (735.312 us; speedup 1.0000x reference)
//
#include <hip/hip_runtime.h>
#include <cstdint>

#define S_LEN 2048
#define DM 4096
#define NQH 32
#define NKVH 8
#define HD 128

typedef __bf16 bf16x8 __attribute__((ext_vector_type(8)));
typedef float f32x4 __attribute__((ext_vector_type(4)));
typedef unsigned short u16;
typedef unsigned short u16x8 __attribute__((ext_vector_type(8)));
typedef unsigned int u32;

__device__ __forceinline__ float bf2f(u16 h) {
  union { u32 u; float f; } v; v.u = ((u32)h) << 16; return v.f;
}
__device__ __forceinline__ u16 f2bf(float f) {
  union { float f; u32 u; } v; v.f = f;
  u32 u = v.u;
  return (u16)((u + 0x7FFFu + ((u >> 16) & 1u)) >> 16);
}

// global -> LDS direct DMA, 16B/lane. LDS dest = wave-uniform base + lane*16;
// global source is per-lane (bit-validated vs reg-staged path).
__device__ __forceinline__ void gload16(const void* g, const void* l) {
  __builtin_amdgcn_global_load_lds(
      (const __attribute__((address_space(1))) u32*)(uintptr_t)g,
      (__attribute__((address_space(3))) u32*)(u32)(uintptr_t)l,
      16, 0, 0);
}

// ---- reg-staging helpers (fallback path): 16 elements global -> LDS
__device__ __forceinline__ void stage16(const float* __restrict__ g, u16* l) {
  const float4* gp = reinterpret_cast<const float4*>(g);
  float4 v0 = gp[0], v1 = gp[1], v2 = gp[2], v3 = gp[3];
  u16x8 a, b;
  a[0] = f2bf(v0.x); a[1] = f2bf(v0.y); a[2] = f2bf(v0.z); a[3] = f2bf(v0.w);
  a[4] = f2bf(v1.x); a[5] = f2bf(v1.y); a[6] = f2bf(v1.z); a[7] = f2bf(v1.w);
  b[0] = f2bf(v2.x); b[1] = f2bf(v2.y); b[2] = f2bf(v2.z); b[3] = f2bf(v2.w);
  b[4] = f2bf(v3.x); b[5] = f2bf(v3.y); b[6] = f2bf(v3.z); b[7] = f2bf(v3.w);
  *reinterpret_cast<u16x8*>(l) = a;
  *reinterpret_cast<u16x8*>(l + 8) = b;
}
__device__ __forceinline__ void stage16(const u16* __restrict__ g, u16* l) {
  *reinterpret_cast<u16x8*>(l) = *reinterpret_cast<const u16x8*>(g);
  *reinterpret_cast<u16x8*>(l + 8) = *reinterpret_cast<const u16x8*>(g + 8);
}

// output store: bf16 (intermediates) or f32 (final d_out)
__device__ __forceinline__ void stc(u16* p, float v) { *p = f2bf(v); }
__device__ __forceinline__ void stc(float* p, float v) { *p = v; }

// ---------------- mega convert: all 5 f32 inputs -> bf16, one launch --------
__device__ __forceinline__ void cvt8(const float* in, u16* out, size_t i8) {
  const float4* gp = reinterpret_cast<const float4*>(in) + i8 * 2;
  float4 a = gp[0], b = gp[1];
  u16x8 o;
  o[0] = f2bf(a.x); o[1] = f2bf(a.y); o[2] = f2bf(a.z); o[3] = f2bf(a.w);
  o[4] = f2bf(b.x); o[5] = f2bf(b.y); o[6] = f2bf(b.z); o[7] = f2bf(b.w);
  reinterpret_cast<u16x8*>(out)[i8] = o;
}
__global__ void cvt_all(const float* x, const float* wq, const float* wk,
                        const float* wv, const float* wo,
                        u16* xb, u16* wqkvb, u16* wob) {
  const size_t NX8 = (size_t)2 * S_LEN * DM / 8;     // 2.097M
  const size_t NW8 = (size_t)DM * DM / 8;            // 2.097M
  const size_t NK8 = (size_t)NKVH * HD * DM / 8;     // 0.524M
  const size_t total = NX8 + NW8 + 2 * NK8 + NW8;
  size_t stride = (size_t)gridDim.x * blockDim.x;
  for (size_t i = (size_t)blockIdx.x * blockDim.x + threadIdx.x; i < total; i += stride) {
    if (i < NX8)                       cvt8(x,  xb,                    i);
    else if (i < NX8 + NW8)            cvt8(wq, wqkvb,                 i - NX8);
    else if (i < NX8 + NW8 + NK8)      cvt8(wk, wqkvb + NW8 * 8,       i - NX8 - NW8);
    else if (i < NX8 + NW8 + 2 * NK8)  cvt8(wv, wqkvb + (NW8 + NK8) * 8, i - NX8 - NW8 - NK8);
    else                               cvt8(wo, wob,                   i - NX8 - NW8 - 2 * NK8);
  }
}

// ---------------- RoPE table (llama3 scaling), fp64 ----------------
__global__ void rope_table_kernel(float* __restrict__ sin_t, float* __restrict__ cos_t) {
  int idx = blockIdx.x * blockDim.x + threadIdx.x;
  if (idx >= S_LEN * 64) return;
  int s = idx >> 6, i = idx & 63;
  const double PI = 3.14159265358979323846;
  double freq = pow(500000.0, -((double)i) / 64.0);
  double wavelen = 2.0 * PI / freq;
  double inv = (wavelen > 8192.0) ? freq / 32.0 : freq;
  if (!(wavelen < 2048.0) && !(wavelen > 8192.0)) {
    double smooth = (8192.0 / wavelen - 1.0) / 3.0;
    inv = (1.0 - smooth) * (freq / 32.0) + smooth * freq;
  }
  double ang = (double)s * inv;
  sin_t[idx] = (float)sin(ang);
  cos_t[idx] = (float)cos(ang);
}

// ---------------- RoPE apply: Q (scaled) and K in ONE launch ----------------
__global__ void rope_apply2(u16* __restrict__ Xq, u16* __restrict__ Xk,
                            const float* __restrict__ sin_t,
                            const float* __restrict__ cos_t,
                            float scale, int nrq, int nrk) {
  int idx = blockIdx.x * blockDim.x + threadIdx.x;
  if (idx >= (nrq + nrk) * 64) return;
  int row = idx >> 6, i = idx & 63;
  u16* X;
  float sc;
  if (row < nrq) { X = Xq; sc = scale; }
  else { X = Xk; row -= nrq; sc = 1.0f; }
  int s = row & (S_LEN - 1);
  size_t base = (size_t)row * HD;
  float lo = bf2f(X[base + i]);
  float hi = bf2f(X[base + i + 64]);
  float sn = sin_t[s * 64 + i];
  float cs = cos_t[s * 64 + i];
  X[base + i] = f2bf((lo * cs - hi * sn) * sc);
  X[base + i + 64] = f2bf((hi * cs + lo * sn) * sc);
}

// ================= GEMM (bf16 inputs, gload16 staging, m97 structure) ========
// C = A(MxK) * B(NxK)^T, f32 acc.  MODE 0: C[m*N+n].
// XCD-bijective block swizzle (nwg % 8 == 0): each XCD gets a contiguous
// chunk of flat ids -> contiguous bm rows -> A-panel fits its private L2.
template <int MODE, typename TC>
__global__ __launch_bounds__(256, 2)
void gemm16(const u16* __restrict__ A, const u16* __restrict__ B,
            TC* __restrict__ C, int M, int N, int K, int H) {
  __shared__ u16 sA[128 * 32];
  __shared__ u16 sB[128 * 32];
  const int tid = threadIdx.x;
  const int lane = tid & 63;
  const int wv = tid >> 6;
  const int wr = wv >> 1, wc = wv & 1;
  const int f = blockIdx.y * gridDim.x + blockIdx.x;
  const int cpx = (gridDim.x * gridDim.y) >> 3;
  const int swz = (f & 7) * cpx + (f >> 3);
  const int bm = (swz / gridDim.x) * 128;
  const int bn = (swz % gridDim.x) * 128;
  const int fr = lane & 15, fq = lane >> 4;
  const int srow = lane >> 2;
  const int scol = (lane & 3) * 8;

  f32x4 zero4 = {0.f, 0.f, 0.f, 0.f};
  f32x4 acc[4][4];
#pragma unroll
  for (int i = 0; i < 4; ++i)
#pragma unroll
    for (int j = 0; j < 4; ++j) acc[i][j] = zero4;

  for (int k0 = 0; k0 < K; k0 += 32) {
    __syncthreads();
#pragma unroll
    for (int j = 0; j < 2; ++j) {
      int c = j * 4 + wv;
      int row = c * 16 + srow;
      gload16(A + (size_t)(bm + row) * K + k0 + scol, sA + c * 512);
      gload16(B + (size_t)(bn + row) * K + k0 + scol, sB + c * 512);
    }
    __syncthreads();
    bf16x8 af[4], bg[4];
#pragma unroll
    for (int i = 0; i < 4; ++i) {
      af[i] = *(const bf16x8*)(sA + (wr * 64 + i * 16 + fr) * 32 + fq * 8);
      bg[i] = *(const bf16x8*)(sB + (wc * 64 + i * 16 + fr) * 32 + fq * 8);
    }
#pragma unroll
    for (int i = 0; i < 4; ++i)
#pragma unroll
      for (int j = 0; j < 4; ++j)
        acc[i][j] = __builtin_amdgcn_mfma_f32_16x16x32_bf16(af[i], bg[j], acc[i][j], 0, 0, 0);
  }

#pragma unroll
  for (int i = 0; i < 4; ++i)
#pragma unroll
    for (int j = 0; j < 4; ++j)
#pragma unroll
      for (int r = 0; r < 4; ++r) {
        int m = bm + wr * 64 + i * 16 + fq * 4 + r;
        int n = bn + wc * 64 + j * 16 + fr;
        stc(C + (size_t)m * N + n, acc[i][j][r]);
      }
}

// ========== fused QKV projection GEMM: A=x[4096x4096], B=[wq;wk;wv] =========
// N=6144. XCD-bijective swizzle as gemm16. Epilogue scatter by segment
// (block-uniform: boundaries %128==0): n<4096: Q [B,32,S,128];
// 4096<=n<5120: K [B,8,S,128]; else V^T [B,8,128,S].
__global__ __launch_bounds__(256, 2)
void gemm_qkv(const u16* __restrict__ A, const u16* __restrict__ B,
              u16* __restrict__ Cq, u16* __restrict__ Ck, u16* __restrict__ Cv,
              int K) {
  __shared__ u16 sA[128 * 32];
  __shared__ u16 sB[128 * 32];
  const int tid = threadIdx.x;
  const int lane = tid & 63;
  const int wv = tid >> 6;
  const int wr = wv >> 1, wc = wv & 1;
  const int f = blockIdx.y * gridDim.x + blockIdx.x;
  const int cpx = (gridDim.x * gridDim.y) >> 3;
  const int swz = (f & 7) * cpx + (f >> 3);
  const int bm = (swz / gridDim.x) * 128;
  const int bn = (swz % gridDim.x) * 128;
  const int fr = lane & 15, fq = lane >> 4;
  const int srow = lane >> 2;
  const int scol = (lane & 3) * 8;

  f32x4 zero4 = {0.f, 0.f, 0.f, 0.f};
  f32x4 acc[4][4];
#pragma unroll
  for (int i = 0; i < 4; ++i)
#pragma unroll
    for (int j = 0; j < 4; ++j) acc[i][j] = zero4;

  for (int k0 = 0; k0 < K; k0 += 32) {
    __syncthreads();
#pragma unroll
    for (int j = 0; j < 2; ++j) {
      int c = j * 4 + wv;
      int row = c * 16 + srow;
      gload16(A + (size_t)(bm + row) * K + k0 + scol, sA + c * 512);
      gload16(B + (size_t)(bn + row) * K + k0 + scol, sB + c * 512);
    }
    __syncthreads();
    bf16x8 af[4], bg[4];
#pragma unroll
    for (int i = 0; i < 4; ++i) {
      af[i] = *(const bf16x8*)(sA + (wr * 64 + i * 16 + fr) * 32 + fq * 8);
      bg[i] = *(const bf16x8*)(sB + (wc * 64 + i * 16 + fr) * 32 + fq * 8);
    }
#pragma unroll
    for (int i = 0; i < 4; ++i)
#pragma unroll
      for (int j = 0; j < 4; ++j)
        acc[i][j] = __builtin_amdgcn_mfma_f32_16x16x32_bf16(af[i], bg[j], acc[i][j], 0, 0, 0);
  }

#pragma unroll
  for (int i = 0; i < 4; ++i)
#pragma unroll
    for (int j = 0; j < 4; ++j)
#pragma unroll
      for (int r = 0; r < 4; ++r) {
        int m = bm + wr * 64 + i * 16 + fq * 4 + r;
        int n = bn + wc * 64 + j * 16 + fr;
        int b = m >> 11, s = m & 2047;
        u16 hval = f2bf(acc[i][j][r]);
        if (n < 4096) {
          int hh = n >> 7, d = n & 127;
          Cq[(((size_t)(b * NQH + hh)) * S_LEN + s) * HD + d] = hval;
        } else if (n < 5120) {
          int nn = n - 4096;
          int hh = nn >> 7, d = nn & 127;
          Ck[(((size_t)(b * NKVH + hh)) * S_LEN + s) * HD + d] = hval;
        } else {
          int nn = n - 5120;
          int hh = nn >> 7, d = nn & 127;
          Cv[(((size_t)(b * NKVH + hh)) * HD + d) * S_LEN + s] = hval;
        }
      }
}

// ================= GEMM fallback (reg-staged; round-10, templated A/B) =======
template <int MODE, typename TA, typename TB, typename TC>
__global__ __launch_bounds__(256, 2)
void gemm_bt(const TA* __restrict__ A, const TB* __restrict__ B,
             TC* __restrict__ C, int M, int N, int K, int H) {
  __shared__ u16 sA[128 * 32];
  __shared__ u16 sB[128 * 32];
  const int tid = threadIdx.x;
  const int lane = tid & 63;
  const int wv = tid >> 6;
  const int wr = wv >> 1, wc = wv & 1;
  const int bm = blockIdx.y * 128;
  const int bn = blockIdx.x * 128;
  const int fr = lane & 15, fq = lane >> 4;
  const int srow = tid >> 1;
  const int shalf = (tid & 1) * 16;

  f32x4 zero4 = {0.f, 0.f, 0.f, 0.f};
  f32x4 acc[4][4];
#pragma unroll
  for (int i = 0; i < 4; ++i)
#pragma unroll
    for (int j = 0; j < 4; ++j) acc[i][j] = zero4;

  for (int k0 = 0; k0 < K; k0 += 32) {
    __syncthreads();
    stage16(A + (size_t)(bm + srow) * K + k0 + shalf, sA + srow * 32 + shalf);
    stage16(B + (size_t)(bn + srow) * K + k0 + shalf, sB + srow * 32 + shalf);
    __syncthreads();
    bf16x8 af[4], bg[4];
#pragma unroll
    for (int i = 0; i < 4; ++i) {
      af[i] = *(const bf16x8*)(sA + (wr * 64 + i * 16 + fr) * 32 + fq * 8);
      bg[i] = *(const bf16x8*)(sB + (wc * 64 + i * 16 + fr) * 32 + fq * 8);
    }
#pragma unroll
    for (int i = 0; i < 4; ++i)
#pragma unroll
      for (int j = 0; j < 4; ++j)
        acc[i][j] = __builtin_amdgcn_mfma_f32_16x16x32_bf16(af[i], bg[j], acc[i][j], 0, 0, 0);
  }

#pragma unroll
  for (int i = 0; i < 4; ++i)
#pragma unroll
    for (int j = 0; j < 4; ++j)
#pragma unroll
      for (int r = 0; r < 4; ++r) {
        int m = bm + wr * 64 + i * 16 + fq * 4 + r;
        int n = bn + wc * 64 + j * 16 + fr;
        float v = acc[i][j][r];
        if (MODE == 0) {
          stc(C + (size_t)m * N + n, v);
        } else if (MODE == 1) {
          int b = m >> 11, s = m & 2047, hh = n >> 7, d = n & 127;
          stc(C + (((size_t)(b * H + hh)) * S_LEN + s) * HD + d, v);
        } else {
          int b = m >> 11, s = m & 2047, hh = n >> 7, d = n & 127;
          stc(C + (((size_t)(b * H + hh)) * HD + d) * S_LEN + s, v);
        }
      }
}

// ====== causal GQA flash attention (QBLK=128, LPT, defer-max, 40KB LDS) ======
// Q [B,32,S,128], K [B,8,S,128], V^T [B,8,128,S]; out [B*S,4096] bf16.
// grid (16, B*32), block 256. LPT: q0=(15-bx)*128. Wave owns 32 q-rows.
// XOR swizzle granule ^= (row&7) on K/V/P; gload16 with pre-swizzled source.
// Defer-max THR=8; l lane-local, epilogue-reduced. sP is HALVED (8KB): one
// 16-row buffer reused across the two u-fragments (write-u0 -> read-pa0 ->
// write-u1 -> read-pa1; same-wave LDS ordering, WAR via lgkmcnt) -> LDS 40KB
// -> up to 4 blocks/CU resident.
__global__ __launch_bounds__(256, 2)
void attn_kernel(const u16* __restrict__ Q, const u16* __restrict__ K,
                 const u16* __restrict__ V, u16* __restrict__ O) {
  __shared__ u16 sK[64 * 128];   // [kv][d], swizzled (16 KB)
  __shared__ u16 sV[128 * 64];   // [d][kv], swizzled (16 KB)
  __shared__ u16 sP[4][16 * 64]; // per-wave P (16 rows, reused per u) (8 KB)

  const int tid = threadIdx.x, lane = tid & 63, wv = tid >> 6;
  const int fr = lane & 15, fq = lane >> 4;
  const int q0 = (15 - blockIdx.x) * 128;  // LPT
  const int bh = blockIdx.y;
  const int b = bh >> 5, h = bh & 31;
  const int hkv = h >> 2;
  const u16* Qb = Q + (size_t)bh * S_LEN * HD;
  const u16* Kb = K + (size_t)(b * NKVH + hkv) * S_LEN * HD;
  const u16* Vb = V + (size_t)(b * NKVH + hkv) * HD * S_LEN;

  bf16x8 qf[2][4];
#pragma unroll
  for (int u = 0; u < 2; ++u) {
    int qrow = q0 + wv * 32 + u * 16 + fr;
#pragma unroll
    for (int ks = 0; ks < 4; ++ks)
      qf[u][ks] = *(const bf16x8*)(Qb + (size_t)qrow * HD + ks * 32 + fq * 8);
  }

  f32x4 zero4 = {0.f, 0.f, 0.f, 0.f};
  f32x4 o[2][8];
  float m[2][4], l[2][4];
#pragma unroll
  for (int u = 0; u < 2; ++u) {
#pragma unroll
    for (int dt = 0; dt < 8; ++dt) o[u][dt] = zero4;
#pragma unroll
    for (int r = 0; r < 4; ++r) { m[u][r] = -3.0e38f; l[u][r] = 0.f; }
  }

  const int ntiles = (q0 >> 6) + 2;
  for (int t = 0; t < ntiles; ++t) {
    const int s0 = t * 64;
    __syncthreads();
#pragma unroll
    for (int j = 0; j < 4; ++j) {
      int c = j * 4 + wv;
      {
        int row = c * 4 + (lane >> 4);
        int e = ((lane & 15) ^ (row & 7)) * 8;
        gload16(Kb + (size_t)(s0 + row) * HD + e, sK + c * 512);
      }
      {
        int row = c * 8 + (lane >> 3);
        int e = ((lane & 7) ^ (row & 7)) * 8;
        gload16(Vb + (size_t)row * S_LEN + s0 + e, sV + c * 512);
      }
    }
    __syncthreads();

    f32x4 sc[2][4];
#pragma unroll
    for (int u = 0; u < 2; ++u)
#pragma unroll
      for (int j = 0; j < 4; ++j) sc[u][j] = zero4;
#pragma unroll
    for (int j = 0; j < 4; ++j) {
#pragma unroll
      for (int ks = 0; ks < 4; ++ks) {
        int row = j * 16 + fr;
        int e = (ks * 32 + fq * 8) ^ ((row & 7) << 3);
        bf16x8 kf = *(const bf16x8*)(sK + row * 128 + e);
#pragma unroll
        for (int u = 0; u < 2; ++u)
          sc[u][j] = __builtin_amdgcn_mfma_f32_16x16x32_bf16(qf[u][ks], kf, sc[u][j], 0, 0, 0);
      }
    }

    if (t >= ntiles - 2) {
#pragma unroll
      for (int u = 0; u < 2; ++u)
#pragma unroll
        for (int j = 0; j < 4; ++j)
#pragma unroll
          for (int r = 0; r < 4; ++r) {
            int kvp = s0 + j * 16 + fr;
            int qp = q0 + wv * 32 + u * 16 + fq * 4 + r;
            if (kvp > qp) sc[u][j][r] = -3.0e38f;
          }
    }

    // softmax + P-repack per u-fragment (sP reused across u)
    bf16x8 pa[2][2];
#pragma unroll
    for (int u = 0; u < 2; ++u) {
      float al[4];
      bool resc = false;
#pragma unroll
      for (int r = 0; r < 4; ++r) {
        float v = fmaxf(fmaxf(sc[u][0][r], sc[u][1][r]), fmaxf(sc[u][2][r], sc[u][3][r]));
        v = fmaxf(v, __shfl_xor(v, 1, 64));
        v = fmaxf(v, __shfl_xor(v, 2, 64));
        v = fmaxf(v, __shfl_xor(v, 4, 64));
        v = fmaxf(v, __shfl_xor(v, 8, 64));
        if (v > m[u][r] + 8.f) {
          al[r] = __expf(m[u][r] - v);
          m[u][r] = v;
          resc = true;
        } else {
          al[r] = 1.f;
        }
      }
#pragma unroll
      for (int r = 0; r < 4; ++r) {
        float rs = 0.f;
        int prow = fq * 4 + r;
#pragma unroll
        for (int j = 0; j < 4; ++j) {
          float pv = __expf(sc[u][j][r] - m[u][r]);
          rs += pv;
          int e = (j * 16 + fr) ^ ((prow & 7) << 3);
          sP[wv][prow * 64 + e] = f2bf(pv);
        }
        l[u][r] = l[u][r] * al[r] + rs;
      }
      if (resc) {
#pragma unroll
        for (int r = 0; r < 4; ++r)
#pragma unroll
          for (int dt = 0; dt < 8; ++dt) o[u][dt][r] *= al[r];
      }
#pragma unroll
      for (int ks = 0; ks < 2; ++ks) {
        int e = (ks * 32 + fq * 8) ^ ((fr & 7) << 3);
        pa[u][ks] = *(const bf16x8*)(&sP[wv][fr * 64 + e]);
      }
    }

    // PV: o[u][dt] rows q, cols d=dt*16+fr; each vf feeds both u-fragments
#pragma unroll
    for (int dt = 0; dt < 8; ++dt) {
#pragma unroll
      for (int ks = 0; ks < 2; ++ks) {
        int row = dt * 16 + fr;
        int e = (ks * 32 + fq * 8) ^ ((row & 7) << 3);
        bf16x8 vf = *(const bf16x8*)(sV + row * 64 + e);
#pragma unroll
        for (int u = 0; u < 2; ++u)
          o[u][dt] = __builtin_amdgcn_mfma_f32_16x16x32_bf16(pa[u][ks], vf, o[u][dt], 0, 0, 0);
      }
    }
  }

#pragma unroll
  for (int u = 0; u < 2; ++u)
#pragma unroll
    for (int r = 0; r < 4; ++r) {
      float lt = l[u][r];
      lt += __shfl_xor(lt, 1, 64);
      lt += __shfl_xor(lt, 2, 64);
      lt += __shfl_xor(lt, 4, 64);
      lt += __shfl_xor(lt, 8, 64);
      int qp = q0 + wv * 32 + u * 16 + fq * 4 + r;
      float inv_l = 1.0f / lt;
      size_t base = ((size_t)b * S_LEN + qp) * DM + h * HD;
#pragma unroll
      for (int dt = 0; dt < 8; ++dt)
        O[base + dt * 16 + fr] = f2bf(o[u][dt][r] * inv_l);
    }
}

// ---------------- RoPE apply (fallback path, single-buffer) ----------------
__global__ void rope_apply(u16* __restrict__ X, const float* __restrict__ sin_t,
                           const float* __restrict__ cos_t, float scale, int nrows) {
  int idx = blockIdx.x * blockDim.x + threadIdx.x;
  if (idx >= nrows * 64) return;
  int row = idx >> 6, i = idx & 63;
  int s = row & (S_LEN - 1);
  size_t base = (size_t)row * HD;
  float lo = bf2f(X[base + i]);
  float hi = bf2f(X[base + i + 64]);
  float sn = sin_t[s * 64 + i];
  float cs = cos_t[s * 64 + i];
  X[base + i] = f2bf((lo * cs - hi * sn) * scale);
  X[base + i + 64] = f2bf((hi * cs + lo * sn) * scale);
}

extern "C" void kernel_launch(void* const* d_in, const int* in_sizes, int n_in,
                              void* d_out, int out_size, void* d_ws, size_t ws_size,
                              hipStream_t stream) {
  const float* x  = (const float*)d_in[0];
  const float* wq = (const float*)d_in[1];
  const float* wk = (const float*)d_in[2];
  const float* wv = (const float*)d_in[3];
  const float* wo = (const float*)d_in[4];

  char* ws = (char*)d_ws;
  size_t off = 0;
  auto alloc = [&](size_t bytes) {
    void* p = ws + off;
    off += (bytes + 255) & ~(size_t)255;
    return p;
  };

  const size_t nx  = (size_t)2 * S_LEN * DM;       // 16.78M elements
  const size_t nwq = (size_t)DM * DM;              // 16.78M
  const size_t nwk = (size_t)(NKVH * HD) * DM;     // 4.19M

  const float scale = 0.08838834764831845f;  // 1/sqrt(128), folded into Q
  const int nrq = 2 * NQH * S_LEN, nrk = 2 * NKVH * S_LEN;
  dim3 blk(256);

  if (ws_size >= ((size_t)180 << 20)) {
    // -------- fast path: mega-cvt + fused QKV GEMM + fused rope --------
    u16* xb    = (u16*)alloc(nx * 2);                 // aob aliases after use
    u16* wqkvb = (u16*)alloc((nwq + 2 * nwk) * 2);    // [wq;wk;wv] 6144x4096
    u16* wob   = (u16*)alloc(nwq * 2);
    u16* qb    = (u16*)alloc(nx * 2);
    u16* kb    = (u16*)alloc(nwk * 2);
    u16* vtb   = (u16*)alloc(nwk * 2);
    float* sin_t = (float*)alloc((size_t)S_LEN * 64 * 4);
    float* cos_t = (float*)alloc((size_t)S_LEN * 64 * 4);
    u16* aob = xb;  // alias: x (bf16) dead after QKV projection

    cvt_all<<<2048, 256, 0, stream>>>(x, wq, wk, wv, wo, xb, wqkvb, wob);
    rope_table_kernel<<<(S_LEN * 64 + 255) / 256, 256, 0, stream>>>(sin_t, cos_t);

    gemm_qkv<<<dim3(48, 32), blk, 0, stream>>>(xb, wqkvb, qb, kb, vtb, DM);

    rope_apply2<<<(((size_t)(nrq + nrk)) * 64 + 255) / 256, 256, 0, stream>>>(
        qb, kb, sin_t, cos_t, scale, nrq, nrk);

    attn_kernel<<<dim3(16, 64), blk, 0, stream>>>(qb, kb, vtb, aob);

    gemm16<0, float><<<dim3(32, 32), blk, 0, stream>>>(aob, wob, (float*)d_out, 4096, DM, DM, 0);
  } else {
    // -------- fallback: proven round-10 path (f32 reg-staged GEMMs) --------
    u16* qb  = (u16*)alloc(nx * 2);
    u16* kb  = (u16*)alloc(nwk * 2);
    u16* vtb = (u16*)alloc(nwk * 2);
    u16* aob = (u16*)alloc(nx * 2);
    float* sin_t = (float*)alloc((size_t)S_LEN * 64 * 4);
    float* cos_t = (float*)alloc((size_t)S_LEN * 64 * 4);

    rope_table_kernel<<<(S_LEN * 64 + 255) / 256, 256, 0, stream>>>(sin_t, cos_t);

    gemm_bt<1, float, float, u16><<<dim3(32, 32), blk, 0, stream>>>(x, wq, qb, 4096, DM, DM, NQH);
    gemm_bt<1, float, float, u16><<<dim3(8, 32), blk, 0, stream>>>(x, wk, kb, 4096, 1024, DM, NKVH);
    gemm_bt<2, float, float, u16><<<dim3(8, 32), blk, 0, stream>>>(x, wv, vtb, 4096, 1024, DM, NKVH);

    rope_apply<<<((size_t)nrq * 64 + 255) / 256, 256, 0, stream>>>(qb, sin_t, cos_t, scale, nrq);
    rope_apply<<<((size_t)nrk * 64 + 255) / 256, 256, 0, stream>>>(kb, sin_t, cos_t, 1.0f, nrk);

    attn_kernel<<<dim3(16, 64), blk, 0, stream>>>(qb, kb, vtb, aob);

    gemm_bt<0, u16, float, float><<<dim3(32, 32), blk, 0, stream>>>(aob, wo, (float*)d_out, 4096, DM, DM, 0);
  }
}

// Round 21
// 717.887 us; speedup vs baseline: 1.0243x; 1.0243x over previous
//
#include <hip/hip_runtime.h>
#include <cstdint>

#define S_LEN 2048
#define DM 4096
#define NQH 32
#define NKVH 8
#define HD 128

typedef __bf16 bf16x8 __attribute__((ext_vector_type(8)));
typedef float f32x4 __attribute__((ext_vector_type(4)));
typedef unsigned short u16;
typedef unsigned short u16x8 __attribute__((ext_vector_type(8)));
typedef unsigned int u32;

__device__ __forceinline__ float bf2f(u16 h) {
  union { u32 u; float f; } v; v.u = ((u32)h) << 16; return v.f;
}
__device__ __forceinline__ u16 f2bf(float f) {
  union { float f; u32 u; } v; v.f = f;
  u32 u = v.u;
  return (u16)((u + 0x7FFFu + ((u >> 16) & 1u)) >> 16);
}

// global -> LDS direct DMA, 16B/lane. LDS dest = wave-uniform base + lane*16;
// global source is per-lane (bit-validated vs reg-staged path).
__device__ __forceinline__ void gload16(const void* g, const void* l) {
  __builtin_amdgcn_global_load_lds(
      (const __attribute__((address_space(1))) u32*)(uintptr_t)g,
      (__attribute__((address_space(3))) u32*)(u32)(uintptr_t)l,
      16, 0, 0);
}

// ---- reg-staging helpers (fallback path): 16 elements global -> LDS
__device__ __forceinline__ void stage16(const float* __restrict__ g, u16* l) {
  const float4* gp = reinterpret_cast<const float4*>(g);
  float4 v0 = gp[0], v1 = gp[1], v2 = gp[2], v3 = gp[3];
  u16x8 a, b;
  a[0] = f2bf(v0.x); a[1] = f2bf(v0.y); a[2] = f2bf(v0.z); a[3] = f2bf(v0.w);
  a[4] = f2bf(v1.x); a[5] = f2bf(v1.y); a[6] = f2bf(v1.z); a[7] = f2bf(v1.w);
  b[0] = f2bf(v2.x); b[1] = f2bf(v2.y); b[2] = f2bf(v2.z); b[3] = f2bf(v2.w);
  b[4] = f2bf(v3.x); b[5] = f2bf(v3.y); b[6] = f2bf(v3.z); b[7] = f2bf(v3.w);
  *reinterpret_cast<u16x8*>(l) = a;
  *reinterpret_cast<u16x8*>(l + 8) = b;
}
__device__ __forceinline__ void stage16(const u16* __restrict__ g, u16* l) {
  *reinterpret_cast<u16x8*>(l) = *reinterpret_cast<const u16x8*>(g);
  *reinterpret_cast<u16x8*>(l + 8) = *reinterpret_cast<const u16x8*>(g + 8);
}

// output store: bf16 (intermediates) or f32 (final d_out)
__device__ __forceinline__ void stc(u16* p, float v) { *p = f2bf(v); }
__device__ __forceinline__ void stc(float* p, float v) { *p = v; }

// ---------------- mega convert: all 5 f32 inputs -> bf16, one launch --------
__device__ __forceinline__ void cvt8(const float* in, u16* out, size_t i8) {
  const float4* gp = reinterpret_cast<const float4*>(in) + i8 * 2;
  float4 a = gp[0], b = gp[1];
  u16x8 o;
  o[0] = f2bf(a.x); o[1] = f2bf(a.y); o[2] = f2bf(a.z); o[3] = f2bf(a.w);
  o[4] = f2bf(b.x); o[5] = f2bf(b.y); o[6] = f2bf(b.z); o[7] = f2bf(b.w);
  reinterpret_cast<u16x8*>(out)[i8] = o;
}
__global__ void cvt_all(const float* x, const float* wq, const float* wk,
                        const float* wv, const float* wo,
                        u16* xb, u16* wqkvb, u16* wob) {
  const size_t NX8 = (size_t)2 * S_LEN * DM / 8;     // 2.097M
  const size_t NW8 = (size_t)DM * DM / 8;            // 2.097M
  const size_t NK8 = (size_t)NKVH * HD * DM / 8;     // 0.524M
  const size_t total = NX8 + NW8 + 2 * NK8 + NW8;
  size_t stride = (size_t)gridDim.x * blockDim.x;
  for (size_t i = (size_t)blockIdx.x * blockDim.x + threadIdx.x; i < total; i += stride) {
    if (i < NX8)                       cvt8(x,  xb,                    i);
    else if (i < NX8 + NW8)            cvt8(wq, wqkvb,                 i - NX8);
    else if (i < NX8 + NW8 + NK8)      cvt8(wk, wqkvb + NW8 * 8,       i - NX8 - NW8);
    else if (i < NX8 + NW8 + 2 * NK8)  cvt8(wv, wqkvb + (NW8 + NK8) * 8, i - NX8 - NW8 - NK8);
    else                               cvt8(wo, wob,                   i - NX8 - NW8 - 2 * NK8);
  }
}

// ---------------- RoPE table (llama3 scaling), fp64 ----------------
__global__ void rope_table_kernel(float* __restrict__ sin_t, float* __restrict__ cos_t) {
  int idx = blockIdx.x * blockDim.x + threadIdx.x;
  if (idx >= S_LEN * 64) return;
  int s = idx >> 6, i = idx & 63;
  const double PI = 3.14159265358979323846;
  double freq = pow(500000.0, -((double)i) / 64.0);
  double wavelen = 2.0 * PI / freq;
  double inv = (wavelen > 8192.0) ? freq / 32.0 : freq;
  if (!(wavelen < 2048.0) && !(wavelen > 8192.0)) {
    double smooth = (8192.0 / wavelen - 1.0) / 3.0;
    inv = (1.0 - smooth) * (freq / 32.0) + smooth * freq;
  }
  double ang = (double)s * inv;
  sin_t[idx] = (float)sin(ang);
  cos_t[idx] = (float)cos(ang);
}

// ---------------- RoPE apply: Q (scaled) and K in ONE launch ----------------
__global__ void rope_apply2(u16* __restrict__ Xq, u16* __restrict__ Xk,
                            const float* __restrict__ sin_t,
                            const float* __restrict__ cos_t,
                            float scale, int nrq, int nrk) {
  int idx = blockIdx.x * blockDim.x + threadIdx.x;
  if (idx >= (nrq + nrk) * 64) return;
  int row = idx >> 6, i = idx & 63;
  u16* X;
  float sc;
  if (row < nrq) { X = Xq; sc = scale; }
  else { X = Xk; row -= nrq; sc = 1.0f; }
  int s = row & (S_LEN - 1);
  size_t base = (size_t)row * HD;
  float lo = bf2f(X[base + i]);
  float hi = bf2f(X[base + i + 64]);
  float sn = sin_t[s * 64 + i];
  float cs = cos_t[s * 64 + i];
  X[base + i] = f2bf((lo * cs - hi * sn) * sc);
  X[base + i + 64] = f2bf((hi * cs + lo * sn) * sc);
}

// ================= GEMM (bf16 inputs, gload16 staging, m97 structure) ========
// C = A(MxK) * B(NxK)^T, f32 acc.  MODE 0: C[m*N+n]. Plain blockIdx mapping
// (XCD-chunked swizzle REVERTED: round-20 measured FETCH 200->600MB, +20us).
template <int MODE, typename TC>
__global__ __launch_bounds__(256, 2)
void gemm16(const u16* __restrict__ A, const u16* __restrict__ B,
            TC* __restrict__ C, int M, int N, int K, int H) {
  __shared__ u16 sA[128 * 32];
  __shared__ u16 sB[128 * 32];
  const int tid = threadIdx.x;
  const int lane = tid & 63;
  const int wv = tid >> 6;
  const int wr = wv >> 1, wc = wv & 1;
  const int bm = blockIdx.y * 128;
  const int bn = blockIdx.x * 128;
  const int fr = lane & 15, fq = lane >> 4;
  const int srow = lane >> 2;
  const int scol = (lane & 3) * 8;

  f32x4 zero4 = {0.f, 0.f, 0.f, 0.f};
  f32x4 acc[4][4];
#pragma unroll
  for (int i = 0; i < 4; ++i)
#pragma unroll
    for (int j = 0; j < 4; ++j) acc[i][j] = zero4;

  for (int k0 = 0; k0 < K; k0 += 32) {
    __syncthreads();
#pragma unroll
    for (int j = 0; j < 2; ++j) {
      int c = j * 4 + wv;
      int row = c * 16 + srow;
      gload16(A + (size_t)(bm + row) * K + k0 + scol, sA + c * 512);
      gload16(B + (size_t)(bn + row) * K + k0 + scol, sB + c * 512);
    }
    __syncthreads();
    bf16x8 af[4], bg[4];
#pragma unroll
    for (int i = 0; i < 4; ++i) {
      af[i] = *(const bf16x8*)(sA + (wr * 64 + i * 16 + fr) * 32 + fq * 8);
      bg[i] = *(const bf16x8*)(sB + (wc * 64 + i * 16 + fr) * 32 + fq * 8);
    }
#pragma unroll
    for (int i = 0; i < 4; ++i)
#pragma unroll
      for (int j = 0; j < 4; ++j)
        acc[i][j] = __builtin_amdgcn_mfma_f32_16x16x32_bf16(af[i], bg[j], acc[i][j], 0, 0, 0);
  }

#pragma unroll
  for (int i = 0; i < 4; ++i)
#pragma unroll
    for (int j = 0; j < 4; ++j)
#pragma unroll
      for (int r = 0; r < 4; ++r) {
        int m = bm + wr * 64 + i * 16 + fq * 4 + r;
        int n = bn + wc * 64 + j * 16 + fr;
        stc(C + (size_t)m * N + n, acc[i][j][r]);
      }
}

// ========== fused QKV projection GEMM: A=x[4096x4096], B=[wq;wk;wv] =========
// N=6144. Plain blockIdx mapping (swizzle reverted). Epilogue scatter by
// segment (block-uniform: boundaries %128==0): n<4096: Q [B,32,S,128];
// 4096<=n<5120: K [B,8,S,128]; else V^T [B,8,128,S].
__global__ __launch_bounds__(256, 2)
void gemm_qkv(const u16* __restrict__ A, const u16* __restrict__ B,
              u16* __restrict__ Cq, u16* __restrict__ Ck, u16* __restrict__ Cv,
              int K) {
  __shared__ u16 sA[128 * 32];
  __shared__ u16 sB[128 * 32];
  const int tid = threadIdx.x;
  const int lane = tid & 63;
  const int wv = tid >> 6;
  const int wr = wv >> 1, wc = wv & 1;
  const int bm = blockIdx.y * 128;
  const int bn = blockIdx.x * 128;
  const int fr = lane & 15, fq = lane >> 4;
  const int srow = lane >> 2;
  const int scol = (lane & 3) * 8;

  f32x4 zero4 = {0.f, 0.f, 0.f, 0.f};
  f32x4 acc[4][4];
#pragma unroll
  for (int i = 0; i < 4; ++i)
#pragma unroll
    for (int j = 0; j < 4; ++j) acc[i][j] = zero4;

  for (int k0 = 0; k0 < K; k0 += 32) {
    __syncthreads();
#pragma unroll
    for (int j = 0; j < 2; ++j) {
      int c = j * 4 + wv;
      int row = c * 16 + srow;
      gload16(A + (size_t)(bm + row) * K + k0 + scol, sA + c * 512);
      gload16(B + (size_t)(bn + row) * K + k0 + scol, sB + c * 512);
    }
    __syncthreads();
    bf16x8 af[4], bg[4];
#pragma unroll
    for (int i = 0; i < 4; ++i) {
      af[i] = *(const bf16x8*)(sA + (wr * 64 + i * 16 + fr) * 32 + fq * 8);
      bg[i] = *(const bf16x8*)(sB + (wc * 64 + i * 16 + fr) * 32 + fq * 8);
    }
#pragma unroll
    for (int i = 0; i < 4; ++i)
#pragma unroll
      for (int j = 0; j < 4; ++j)
        acc[i][j] = __builtin_amdgcn_mfma_f32_16x16x32_bf16(af[i], bg[j], acc[i][j], 0, 0, 0);
  }

#pragma unroll
  for (int i = 0; i < 4; ++i)
#pragma unroll
    for (int j = 0; j < 4; ++j)
#pragma unroll
      for (int r = 0; r < 4; ++r) {
        int m = bm + wr * 64 + i * 16 + fq * 4 + r;
        int n = bn + wc * 64 + j * 16 + fr;
        int b = m >> 11, s = m & 2047;
        u16 hval = f2bf(acc[i][j][r]);
        if (n < 4096) {
          int hh = n >> 7, d = n & 127;
          Cq[(((size_t)(b * NQH + hh)) * S_LEN + s) * HD + d] = hval;
        } else if (n < 5120) {
          int nn = n - 4096;
          int hh = nn >> 7, d = nn & 127;
          Ck[(((size_t)(b * NKVH + hh)) * S_LEN + s) * HD + d] = hval;
        } else {
          int nn = n - 5120;
          int hh = nn >> 7, d = nn & 127;
          Cv[(((size_t)(b * NKVH + hh)) * HD + d) * S_LEN + s] = hval;
        }
      }
}

// ================= GEMM fallback (reg-staged; round-10, templated A/B) =======
template <int MODE, typename TA, typename TB, typename TC>
__global__ __launch_bounds__(256, 2)
void gemm_bt(const TA* __restrict__ A, const TB* __restrict__ B,
             TC* __restrict__ C, int M, int N, int K, int H) {
  __shared__ u16 sA[128 * 32];
  __shared__ u16 sB[128 * 32];
  const int tid = threadIdx.x;
  const int lane = tid & 63;
  const int wv = tid >> 6;
  const int wr = wv >> 1, wc = wv & 1;
  const int bm = blockIdx.y * 128;
  const int bn = blockIdx.x * 128;
  const int fr = lane & 15, fq = lane >> 4;
  const int srow = tid >> 1;
  const int shalf = (tid & 1) * 16;

  f32x4 zero4 = {0.f, 0.f, 0.f, 0.f};
  f32x4 acc[4][4];
#pragma unroll
  for (int i = 0; i < 4; ++i)
#pragma unroll
    for (int j = 0; j < 4; ++j) acc[i][j] = zero4;

  for (int k0 = 0; k0 < K; k0 += 32) {
    __syncthreads();
    stage16(A + (size_t)(bm + srow) * K + k0 + shalf, sA + srow * 32 + shalf);
    stage16(B + (size_t)(bn + srow) * K + k0 + shalf, sB + srow * 32 + shalf);
    __syncthreads();
    bf16x8 af[4], bg[4];
#pragma unroll
    for (int i = 0; i < 4; ++i) {
      af[i] = *(const bf16x8*)(sA + (wr * 64 + i * 16 + fr) * 32 + fq * 8);
      bg[i] = *(const bf16x8*)(sB + (wc * 64 + i * 16 + fr) * 32 + fq * 8);
    }
#pragma unroll
    for (int i = 0; i < 4; ++i)
#pragma unroll
      for (int j = 0; j < 4; ++j)
        acc[i][j] = __builtin_amdgcn_mfma_f32_16x16x32_bf16(af[i], bg[j], acc[i][j], 0, 0, 0);
  }

#pragma unroll
  for (int i = 0; i < 4; ++i)
#pragma unroll
    for (int j = 0; j < 4; ++j)
#pragma unroll
      for (int r = 0; r < 4; ++r) {
        int m = bm + wr * 64 + i * 16 + fq * 4 + r;
        int n = bn + wc * 64 + j * 16 + fr;
        float v = acc[i][j][r];
        if (MODE == 0) {
          stc(C + (size_t)m * N + n, v);
        } else if (MODE == 1) {
          int b = m >> 11, s = m & 2047, hh = n >> 7, d = n & 127;
          stc(C + (((size_t)(b * H + hh)) * S_LEN + s) * HD + d, v);
        } else {
          int b = m >> 11, s = m & 2047, hh = n >> 7, d = n & 127;
          stc(C + (((size_t)(b * H + hh)) * HD + d) * S_LEN + s, v);
        }
      }
}

// ====== causal GQA flash attention (QBLK=128, LPT, defer-max, 40KB LDS) ======
// Q [B,32,S,128], K [B,8,S,128], V^T [B,8,128,S]; out [B*S,4096] bf16.
// grid (16, B*32), block 256. LPT: q0=(15-bx)*128. Wave owns 32 q-rows.
// XOR swizzle granule ^= (row&7) on K/V/P; gload16 with pre-swizzled source.
// Defer-max THR=8; l lane-local, epilogue-reduced. sP halved (8KB): one
// 16-row buffer reused across the two u-fragments -> LDS 40KB -> 4 blocks/CU.
__global__ __launch_bounds__(256, 2)
void attn_kernel(const u16* __restrict__ Q, const u16* __restrict__ K,
                 const u16* __restrict__ V, u16* __restrict__ O) {
  __shared__ u16 sK[64 * 128];   // [kv][d], swizzled (16 KB)
  __shared__ u16 sV[128 * 64];   // [d][kv], swizzled (16 KB)
  __shared__ u16 sP[4][16 * 64]; // per-wave P (16 rows, reused per u) (8 KB)

  const int tid = threadIdx.x, lane = tid & 63, wv = tid >> 6;
  const int fr = lane & 15, fq = lane >> 4;
  const int q0 = (15 - blockIdx.x) * 128;  // LPT
  const int bh = blockIdx.y;
  const int b = bh >> 5, h = bh & 31;
  const int hkv = h >> 2;
  const u16* Qb = Q + (size_t)bh * S_LEN * HD;
  const u16* Kb = K + (size_t)(b * NKVH + hkv) * S_LEN * HD;
  const u16* Vb = V + (size_t)(b * NKVH + hkv) * HD * S_LEN;

  bf16x8 qf[2][4];
#pragma unroll
  for (int u = 0; u < 2; ++u) {
    int qrow = q0 + wv * 32 + u * 16 + fr;
#pragma unroll
    for (int ks = 0; ks < 4; ++ks)
      qf[u][ks] = *(const bf16x8*)(Qb + (size_t)qrow * HD + ks * 32 + fq * 8);
  }

  f32x4 zero4 = {0.f, 0.f, 0.f, 0.f};
  f32x4 o[2][8];
  float m[2][4], l[2][4];
#pragma unroll
  for (int u = 0; u < 2; ++u) {
#pragma unroll
    for (int dt = 0; dt < 8; ++dt) o[u][dt] = zero4;
#pragma unroll
    for (int r = 0; r < 4; ++r) { m[u][r] = -3.0e38f; l[u][r] = 0.f; }
  }

  const int ntiles = (q0 >> 6) + 2;
  for (int t = 0; t < ntiles; ++t) {
    const int s0 = t * 64;
    __syncthreads();
#pragma unroll
    for (int j = 0; j < 4; ++j) {
      int c = j * 4 + wv;
      {
        int row = c * 4 + (lane >> 4);
        int e = ((lane & 15) ^ (row & 7)) * 8;
        gload16(Kb + (size_t)(s0 + row) * HD + e, sK + c * 512);
      }
      {
        int row = c * 8 + (lane >> 3);
        int e = ((lane & 7) ^ (row & 7)) * 8;
        gload16(Vb + (size_t)row * S_LEN + s0 + e, sV + c * 512);
      }
    }
    __syncthreads();

    f32x4 sc[2][4];
#pragma unroll
    for (int u = 0; u < 2; ++u)
#pragma unroll
      for (int j = 0; j < 4; ++j) sc[u][j] = zero4;
#pragma unroll
    for (int j = 0; j < 4; ++j) {
#pragma unroll
      for (int ks = 0; ks < 4; ++ks) {
        int row = j * 16 + fr;
        int e = (ks * 32 + fq * 8) ^ ((row & 7) << 3);
        bf16x8 kf = *(const bf16x8*)(sK + row * 128 + e);
#pragma unroll
        for (int u = 0; u < 2; ++u)
          sc[u][j] = __builtin_amdgcn_mfma_f32_16x16x32_bf16(qf[u][ks], kf, sc[u][j], 0, 0, 0);
      }
    }

    if (t >= ntiles - 2) {
#pragma unroll
      for (int u = 0; u < 2; ++u)
#pragma unroll
        for (int j = 0; j < 4; ++j)
#pragma unroll
          for (int r = 0; r < 4; ++r) {
            int kvp = s0 + j * 16 + fr;
            int qp = q0 + wv * 32 + u * 16 + fq * 4 + r;
            if (kvp > qp) sc[u][j][r] = -3.0e38f;
          }
    }

    // softmax + P-repack per u-fragment (sP reused across u)
    bf16x8 pa[2][2];
#pragma unroll
    for (int u = 0; u < 2; ++u) {
      float al[4];
      bool resc = false;
#pragma unroll
      for (int r = 0; r < 4; ++r) {
        float v = fmaxf(fmaxf(sc[u][0][r], sc[u][1][r]), fmaxf(sc[u][2][r], sc[u][3][r]));
        v = fmaxf(v, __shfl_xor(v, 1, 64));
        v = fmaxf(v, __shfl_xor(v, 2, 64));
        v = fmaxf(v, __shfl_xor(v, 4, 64));
        v = fmaxf(v, __shfl_xor(v, 8, 64));
        if (v > m[u][r] + 8.f) {
          al[r] = __expf(m[u][r] - v);
          m[u][r] = v;
          resc = true;
        } else {
          al[r] = 1.f;
        }
      }
#pragma unroll
      for (int r = 0; r < 4; ++r) {
        float rs = 0.f;
        int prow = fq * 4 + r;
#pragma unroll
        for (int j = 0; j < 4; ++j) {
          float pv = __expf(sc[u][j][r] - m[u][r]);
          rs += pv;
          int e = (j * 16 + fr) ^ ((prow & 7) << 3);
          sP[wv][prow * 64 + e] = f2bf(pv);
        }
        l[u][r] = l[u][r] * al[r] + rs;
      }
      if (resc) {
#pragma unroll
        for (int r = 0; r < 4; ++r)
#pragma unroll
          for (int dt = 0; dt < 8; ++dt) o[u][dt][r] *= al[r];
      }
#pragma unroll
      for (int ks = 0; ks < 2; ++ks) {
        int e = (ks * 32 + fq * 8) ^ ((fr & 7) << 3);
        pa[u][ks] = *(const bf16x8*)(&sP[wv][fr * 64 + e]);
      }
    }

    // PV: o[u][dt] rows q, cols d=dt*16+fr; each vf feeds both u-fragments
#pragma unroll
    for (int dt = 0; dt < 8; ++dt) {
#pragma unroll
      for (int ks = 0; ks < 2; ++ks) {
        int row = dt * 16 + fr;
        int e = (ks * 32 + fq * 8) ^ ((row & 7) << 3);
        bf16x8 vf = *(const bf16x8*)(sV + row * 64 + e);
#pragma unroll
        for (int u = 0; u < 2; ++u)
          o[u][dt] = __builtin_amdgcn_mfma_f32_16x16x32_bf16(pa[u][ks], vf, o[u][dt], 0, 0, 0);
      }
    }
  }

#pragma unroll
  for (int u = 0; u < 2; ++u)
#pragma unroll
    for (int r = 0; r < 4; ++r) {
      float lt = l[u][r];
      lt += __shfl_xor(lt, 1, 64);
      lt += __shfl_xor(lt, 2, 64);
      lt += __shfl_xor(lt, 4, 64);
      lt += __shfl_xor(lt, 8, 64);
      int qp = q0 + wv * 32 + u * 16 + fq * 4 + r;
      float inv_l = 1.0f / lt;
      size_t base = ((size_t)b * S_LEN + qp) * DM + h * HD;
#pragma unroll
      for (int dt = 0; dt < 8; ++dt)
        O[base + dt * 16 + fr] = f2bf(o[u][dt][r] * inv_l);
    }
}

// ---------------- RoPE apply (fallback path, single-buffer) ----------------
__global__ void rope_apply(u16* __restrict__ X, const float* __restrict__ sin_t,
                           const float* __restrict__ cos_t, float scale, int nrows) {
  int idx = blockIdx.x * blockDim.x + threadIdx.x;
  if (idx >= nrows * 64) return;
  int row = idx >> 6, i = idx & 63;
  int s = row & (S_LEN - 1);
  size_t base = (size_t)row * HD;
  float lo = bf2f(X[base + i]);
  float hi = bf2f(X[base + i + 64]);
  float sn = sin_t[s * 64 + i];
  float cs = cos_t[s * 64 + i];
  X[base + i] = f2bf((lo * cs - hi * sn) * scale);
  X[base + i + 64] = f2bf((hi * cs + lo * sn) * scale);
}

extern "C" void kernel_launch(void* const* d_in, const int* in_sizes, int n_in,
                              void* d_out, int out_size, void* d_ws, size_t ws_size,
                              hipStream_t stream) {
  const float* x  = (const float*)d_in[0];
  const float* wq = (const float*)d_in[1];
  const float* wk = (const float*)d_in[2];
  const float* wv = (const float*)d_in[3];
  const float* wo = (const float*)d_in[4];

  char* ws = (char*)d_ws;
  size_t off = 0;
  auto alloc = [&](size_t bytes) {
    void* p = ws + off;
    off += (bytes + 255) & ~(size_t)255;
    return p;
  };

  const size_t nx  = (size_t)2 * S_LEN * DM;       // 16.78M elements
  const size_t nwq = (size_t)DM * DM;              // 16.78M
  const size_t nwk = (size_t)(NKVH * HD) * DM;     // 4.19M

  const float scale = 0.08838834764831845f;  // 1/sqrt(128), folded into Q
  const int nrq = 2 * NQH * S_LEN, nrk = 2 * NKVH * S_LEN;
  dim3 blk(256);

  if (ws_size >= ((size_t)180 << 20)) {
    // -------- fast path: mega-cvt + fused QKV GEMM + fused rope --------
    u16* xb    = (u16*)alloc(nx * 2);                 // aob aliases after use
    u16* wqkvb = (u16*)alloc((nwq + 2 * nwk) * 2);    // [wq;wk;wv] 6144x4096
    u16* wob   = (u16*)alloc(nwq * 2);
    u16* qb    = (u16*)alloc(nx * 2);
    u16* kb    = (u16*)alloc(nwk * 2);
    u16* vtb   = (u16*)alloc(nwk * 2);
    float* sin_t = (float*)alloc((size_t)S_LEN * 64 * 4);
    float* cos_t = (float*)alloc((size_t)S_LEN * 64 * 4);
    u16* aob = xb;  // alias: x (bf16) dead after QKV projection

    cvt_all<<<2048, 256, 0, stream>>>(x, wq, wk, wv, wo, xb, wqkvb, wob);
    rope_table_kernel<<<(S_LEN * 64 + 255) / 256, 256, 0, stream>>>(sin_t, cos_t);

    gemm_qkv<<<dim3(48, 32), blk, 0, stream>>>(xb, wqkvb, qb, kb, vtb, DM);

    rope_apply2<<<(((size_t)(nrq + nrk)) * 64 + 255) / 256, 256, 0, stream>>>(
        qb, kb, sin_t, cos_t, scale, nrq, nrk);

    attn_kernel<<<dim3(16, 64), blk, 0, stream>>>(qb, kb, vtb, aob);

    gemm16<0, float><<<dim3(32, 32), blk, 0, stream>>>(aob, wob, (float*)d_out, 4096, DM, DM, 0);
  } else {
    // -------- fallback: proven round-10 path (f32 reg-staged GEMMs) --------
    u16* qb  = (u16*)alloc(nx * 2);
    u16* kb  = (u16*)alloc(nwk * 2);
    u16* vtb = (u16*)alloc(nwk * 2);
    u16* aob = (u16*)alloc(nx * 2);
    float* sin_t = (float*)alloc((size_t)S_LEN * 64 * 4);
    float* cos_t = (float*)alloc((size_t)S_LEN * 64 * 4);

    rope_table_kernel<<<(S_LEN * 64 + 255) / 256, 256, 0, stream>>>(sin_t, cos_t);

    gemm_bt<1, float, float, u16><<<dim3(32, 32), blk, 0, stream>>>(x, wq, qb, 4096, DM, DM, NQH);
    gemm_bt<1, float, float, u16><<<dim3(8, 32), blk, 0, stream>>>(x, wk, kb, 4096, 1024, DM, NKVH);
    gemm_bt<2, float, float, u16><<<dim3(8, 32), blk, 0, stream>>>(x, wv, vtb, 4096, 1024, DM, NKVH);

    rope_apply<<<((size_t)nrq * 64 + 255) / 256, 256, 0, stream>>>(qb, sin_t, cos_t, scale, nrq);
    rope_apply<<<((size_t)nrk * 64 + 255) / 256, 256, 0, stream>>>(kb, sin_t, cos_t, 1.0f, nrk);

    attn_kernel<<<dim3(16, 64), blk, 0, stream>>>(qb, kb, vtb, aob);

    gemm_bt<0, u16, float, float><<<dim3(32, 32), blk, 0, stream>>>(aob, wo, (float*)d_out, 4096, DM, DM, 0);
  }
}

// Round 22
// 716.664 us; speedup vs baseline: 1.0260x; 1.0017x over previous
//
#include <hip/hip_runtime.h>
#include <cstdint>

#define S_LEN 2048
#define DM 4096
#define NQH 32
#define NKVH 8
#define HD 128

typedef __bf16 bf16x8 __attribute__((ext_vector_type(8)));
typedef float f32x4 __attribute__((ext_vector_type(4)));
typedef unsigned short u16;
typedef unsigned short u16x8 __attribute__((ext_vector_type(8)));
typedef unsigned int u32;

__device__ __forceinline__ float bf2f(u16 h) {
  union { u32 u; float f; } v; v.u = ((u32)h) << 16; return v.f;
}
__device__ __forceinline__ u16 f2bf(float f) {
  union { float f; u32 u; } v; v.f = f;
  u32 u = v.u;
  return (u16)((u + 0x7FFFu + ((u >> 16) & 1u)) >> 16);
}

// global -> LDS direct DMA, 16B/lane. LDS dest = wave-uniform base + lane*16;
// global source is per-lane (bit-validated vs reg-staged path).
__device__ __forceinline__ void gload16(const void* g, const void* l) {
  __builtin_amdgcn_global_load_lds(
      (const __attribute__((address_space(1))) u32*)(uintptr_t)g,
      (__attribute__((address_space(3))) u32*)(u32)(uintptr_t)l,
      16, 0, 0);
}

// ---- reg-staging helpers (fallback path): 16 elements global -> LDS
__device__ __forceinline__ void stage16(const float* __restrict__ g, u16* l) {
  const float4* gp = reinterpret_cast<const float4*>(g);
  float4 v0 = gp[0], v1 = gp[1], v2 = gp[2], v3 = gp[3];
  u16x8 a, b;
  a[0] = f2bf(v0.x); a[1] = f2bf(v0.y); a[2] = f2bf(v0.z); a[3] = f2bf(v0.w);
  a[4] = f2bf(v1.x); a[5] = f2bf(v1.y); a[6] = f2bf(v1.z); a[7] = f2bf(v1.w);
  b[0] = f2bf(v2.x); b[1] = f2bf(v2.y); b[2] = f2bf(v2.z); b[3] = f2bf(v2.w);
  b[4] = f2bf(v3.x); b[5] = f2bf(v3.y); b[6] = f2bf(v3.z); b[7] = f2bf(v3.w);
  *reinterpret_cast<u16x8*>(l) = a;
  *reinterpret_cast<u16x8*>(l + 8) = b;
}
__device__ __forceinline__ void stage16(const u16* __restrict__ g, u16* l) {
  *reinterpret_cast<u16x8*>(l) = *reinterpret_cast<const u16x8*>(g);
  *reinterpret_cast<u16x8*>(l + 8) = *reinterpret_cast<const u16x8*>(g + 8);
}

// output store: bf16 (intermediates) or f32 (final d_out)
__device__ __forceinline__ void stc(u16* p, float v) { *p = f2bf(v); }
__device__ __forceinline__ void stc(float* p, float v) { *p = v; }

// ---------------- mega convert: all 5 f32 inputs -> bf16, one launch --------
__device__ __forceinline__ void cvt8(const float* in, u16* out, size_t i8) {
  const float4* gp = reinterpret_cast<const float4*>(in) + i8 * 2;
  float4 a = gp[0], b = gp[1];
  u16x8 o;
  o[0] = f2bf(a.x); o[1] = f2bf(a.y); o[2] = f2bf(a.z); o[3] = f2bf(a.w);
  o[4] = f2bf(b.x); o[5] = f2bf(b.y); o[6] = f2bf(b.z); o[7] = f2bf(b.w);
  reinterpret_cast<u16x8*>(out)[i8] = o;
}
__global__ void cvt_all(const float* x, const float* wq, const float* wk,
                        const float* wv, const float* wo,
                        u16* xb, u16* wqkvb, u16* wob) {
  const size_t NX8 = (size_t)2 * S_LEN * DM / 8;     // 2.097M
  const size_t NW8 = (size_t)DM * DM / 8;            // 2.097M
  const size_t NK8 = (size_t)NKVH * HD * DM / 8;     // 0.524M
  const size_t total = NX8 + NW8 + 2 * NK8 + NW8;
  size_t stride = (size_t)gridDim.x * blockDim.x;
  for (size_t i = (size_t)blockIdx.x * blockDim.x + threadIdx.x; i < total; i += stride) {
    if (i < NX8)                       cvt8(x,  xb,                    i);
    else if (i < NX8 + NW8)            cvt8(wq, wqkvb,                 i - NX8);
    else if (i < NX8 + NW8 + NK8)      cvt8(wk, wqkvb + NW8 * 8,       i - NX8 - NW8);
    else if (i < NX8 + NW8 + 2 * NK8)  cvt8(wv, wqkvb + (NW8 + NK8) * 8, i - NX8 - NW8 - NK8);
    else                               cvt8(wo, wob,                   i - NX8 - NW8 - 2 * NK8);
  }
}

// ---------------- RoPE table (llama3 scaling), fp64 ----------------
__global__ void rope_table_kernel(float* __restrict__ sin_t, float* __restrict__ cos_t) {
  int idx = blockIdx.x * blockDim.x + threadIdx.x;
  if (idx >= S_LEN * 64) return;
  int s = idx >> 6, i = idx & 63;
  const double PI = 3.14159265358979323846;
  double freq = pow(500000.0, -((double)i) / 64.0);
  double wavelen = 2.0 * PI / freq;
  double inv = (wavelen > 8192.0) ? freq / 32.0 : freq;
  if (!(wavelen < 2048.0) && !(wavelen > 8192.0)) {
    double smooth = (8192.0 / wavelen - 1.0) / 3.0;
    inv = (1.0 - smooth) * (freq / 32.0) + smooth * freq;
  }
  double ang = (double)s * inv;
  sin_t[idx] = (float)sin(ang);
  cos_t[idx] = (float)cos(ang);
}

// ---------------- RoPE apply: Q (scaled) and K in ONE launch ----------------
__global__ void rope_apply2(u16* __restrict__ Xq, u16* __restrict__ Xk,
                            const float* __restrict__ sin_t,
                            const float* __restrict__ cos_t,
                            float scale, int nrq, int nrk) {
  int idx = blockIdx.x * blockDim.x + threadIdx.x;
  if (idx >= (nrq + nrk) * 64) return;
  int row = idx >> 6, i = idx & 63;
  u16* X;
  float sc;
  if (row < nrq) { X = Xq; sc = scale; }
  else { X = Xk; row -= nrq; sc = 1.0f; }
  int s = row & (S_LEN - 1);
  size_t base = (size_t)row * HD;
  float lo = bf2f(X[base + i]);
  float hi = bf2f(X[base + i + 64]);
  float sn = sin_t[s * 64 + i];
  float cs = cos_t[s * 64 + i];
  X[base + i] = f2bf((lo * cs - hi * sn) * sc);
  X[base + i + 64] = f2bf((hi * cs + lo * sn) * sc);
}

// ================= GEMM (bf16 inputs, gload16 staging, m97 structure) ========
// C = A(MxK) * B(NxK)^T, f32 acc.  MODE 0: C[m*N+n].
// LDS bank-conflict fix (T2, both-sides XOR): 16B granule g of row r holds
// global granule g ^ ((r>>1)&3). Staging pre-swizzles the GLOBAL source
// (LDS dest linear, as gload16 requires); reads XOR the granule index.
// Turns the 8-way fragment-read conflict into free 2-way. Bit-identical math.
template <int MODE, typename TC>
__global__ __launch_bounds__(256, 2)
void gemm16(const u16* __restrict__ A, const u16* __restrict__ B,
            TC* __restrict__ C, int M, int N, int K, int H) {
  __shared__ u16 sA[128 * 32];
  __shared__ u16 sB[128 * 32];
  const int tid = threadIdx.x;
  const int lane = tid & 63;
  const int wv = tid >> 6;
  const int wr = wv >> 1, wc = wv & 1;
  const int bm = blockIdx.y * 128;
  const int bn = blockIdx.x * 128;
  const int fr = lane & 15, fq = lane >> 4;
  const int srow = lane >> 2;                               // row within 16-row chunk
  const int scol = (((lane & 3) ^ ((lane >> 3) & 3)) * 8);  // swizzled source granule
  const int rsw = (fr >> 1) & 3;                            // read-side XOR (lane const)

  f32x4 zero4 = {0.f, 0.f, 0.f, 0.f};
  f32x4 acc[4][4];
#pragma unroll
  for (int i = 0; i < 4; ++i)
#pragma unroll
    for (int j = 0; j < 4; ++j) acc[i][j] = zero4;

  for (int k0 = 0; k0 < K; k0 += 32) {
    __syncthreads();
#pragma unroll
    for (int j = 0; j < 2; ++j) {
      int c = j * 4 + wv;
      int row = c * 16 + srow;
      gload16(A + (size_t)(bm + row) * K + k0 + scol, sA + c * 512);
      gload16(B + (size_t)(bn + row) * K + k0 + scol, sB + c * 512);
    }
    __syncthreads();
    bf16x8 af[4], bg[4];
#pragma unroll
    for (int i = 0; i < 4; ++i) {
      af[i] = *(const bf16x8*)(sA + (wr * 64 + i * 16 + fr) * 32 + (fq ^ rsw) * 8);
      bg[i] = *(const bf16x8*)(sB + (wc * 64 + i * 16 + fr) * 32 + (fq ^ rsw) * 8);
    }
#pragma unroll
    for (int i = 0; i < 4; ++i)
#pragma unroll
      for (int j = 0; j < 4; ++j)
        acc[i][j] = __builtin_amdgcn_mfma_f32_16x16x32_bf16(af[i], bg[j], acc[i][j], 0, 0, 0);
  }

#pragma unroll
  for (int i = 0; i < 4; ++i)
#pragma unroll
    for (int j = 0; j < 4; ++j)
#pragma unroll
      for (int r = 0; r < 4; ++r) {
        int m = bm + wr * 64 + i * 16 + fq * 4 + r;
        int n = bn + wc * 64 + j * 16 + fr;
        stc(C + (size_t)m * N + n, acc[i][j][r]);
      }
}

// ========== fused QKV projection GEMM: A=x[4096x4096], B=[wq;wk;wv] =========
// N=6144. Same T2 both-sides LDS swizzle as gemm16. Epilogue scatter by
// segment (block-uniform: boundaries %128==0): n<4096: Q [B,32,S,128];
// 4096<=n<5120: K [B,8,S,128]; else V^T [B,8,128,S].
__global__ __launch_bounds__(256, 2)
void gemm_qkv(const u16* __restrict__ A, const u16* __restrict__ B,
              u16* __restrict__ Cq, u16* __restrict__ Ck, u16* __restrict__ Cv,
              int K) {
  __shared__ u16 sA[128 * 32];
  __shared__ u16 sB[128 * 32];
  const int tid = threadIdx.x;
  const int lane = tid & 63;
  const int wv = tid >> 6;
  const int wr = wv >> 1, wc = wv & 1;
  const int bm = blockIdx.y * 128;
  const int bn = blockIdx.x * 128;
  const int fr = lane & 15, fq = lane >> 4;
  const int srow = lane >> 2;
  const int scol = (((lane & 3) ^ ((lane >> 3) & 3)) * 8);  // swizzled source granule
  const int rsw = (fr >> 1) & 3;

  f32x4 zero4 = {0.f, 0.f, 0.f, 0.f};
  f32x4 acc[4][4];
#pragma unroll
  for (int i = 0; i < 4; ++i)
#pragma unroll
    for (int j = 0; j < 4; ++j) acc[i][j] = zero4;

  for (int k0 = 0; k0 < K; k0 += 32) {
    __syncthreads();
#pragma unroll
    for (int j = 0; j < 2; ++j) {
      int c = j * 4 + wv;
      int row = c * 16 + srow;
      gload16(A + (size_t)(bm + row) * K + k0 + scol, sA + c * 512);
      gload16(B + (size_t)(bn + row) * K + k0 + scol, sB + c * 512);
    }
    __syncthreads();
    bf16x8 af[4], bg[4];
#pragma unroll
    for (int i = 0; i < 4; ++i) {
      af[i] = *(const bf16x8*)(sA + (wr * 64 + i * 16 + fr) * 32 + (fq ^ rsw) * 8);
      bg[i] = *(const bf16x8*)(sB + (wc * 64 + i * 16 + fr) * 32 + (fq ^ rsw) * 8);
    }
#pragma unroll
    for (int i = 0; i < 4; ++i)
#pragma unroll
      for (int j = 0; j < 4; ++j)
        acc[i][j] = __builtin_amdgcn_mfma_f32_16x16x32_bf16(af[i], bg[j], acc[i][j], 0, 0, 0);
  }

#pragma unroll
  for (int i = 0; i < 4; ++i)
#pragma unroll
    for (int j = 0; j < 4; ++j)
#pragma unroll
      for (int r = 0; r < 4; ++r) {
        int m = bm + wr * 64 + i * 16 + fq * 4 + r;
        int n = bn + wc * 64 + j * 16 + fr;
        int b = m >> 11, s = m & 2047;
        u16 hval = f2bf(acc[i][j][r]);
        if (n < 4096) {
          int hh = n >> 7, d = n & 127;
          Cq[(((size_t)(b * NQH + hh)) * S_LEN + s) * HD + d] = hval;
        } else if (n < 5120) {
          int nn = n - 4096;
          int hh = nn >> 7, d = nn & 127;
          Ck[(((size_t)(b * NKVH + hh)) * S_LEN + s) * HD + d] = hval;
        } else {
          int nn = n - 5120;
          int hh = nn >> 7, d = nn & 127;
          Cv[(((size_t)(b * NKVH + hh)) * HD + d) * S_LEN + s] = hval;
        }
      }
}

// ================= GEMM fallback (reg-staged; round-10, templated A/B) =======
template <int MODE, typename TA, typename TB, typename TC>
__global__ __launch_bounds__(256, 2)
void gemm_bt(const TA* __restrict__ A, const TB* __restrict__ B,
             TC* __restrict__ C, int M, int N, int K, int H) {
  __shared__ u16 sA[128 * 32];
  __shared__ u16 sB[128 * 32];
  const int tid = threadIdx.x;
  const int lane = tid & 63;
  const int wv = tid >> 6;
  const int wr = wv >> 1, wc = wv & 1;
  const int bm = blockIdx.y * 128;
  const int bn = blockIdx.x * 128;
  const int fr = lane & 15, fq = lane >> 4;
  const int srow = tid >> 1;
  const int shalf = (tid & 1) * 16;

  f32x4 zero4 = {0.f, 0.f, 0.f, 0.f};
  f32x4 acc[4][4];
#pragma unroll
  for (int i = 0; i < 4; ++i)
#pragma unroll
    for (int j = 0; j < 4; ++j) acc[i][j] = zero4;

  for (int k0 = 0; k0 < K; k0 += 32) {
    __syncthreads();
    stage16(A + (size_t)(bm + srow) * K + k0 + shalf, sA + srow * 32 + shalf);
    stage16(B + (size_t)(bn + srow) * K + k0 + shalf, sB + srow * 32 + shalf);
    __syncthreads();
    bf16x8 af[4], bg[4];
#pragma unroll
    for (int i = 0; i < 4; ++i) {
      af[i] = *(const bf16x8*)(sA + (wr * 64 + i * 16 + fr) * 32 + fq * 8);
      bg[i] = *(const bf16x8*)(sB + (wc * 64 + i * 16 + fr) * 32 + fq * 8);
    }
#pragma unroll
    for (int i = 0; i < 4; ++i)
#pragma unroll
      for (int j = 0; j < 4; ++j)
        acc[i][j] = __builtin_amdgcn_mfma_f32_16x16x32_bf16(af[i], bg[j], acc[i][j], 0, 0, 0);
  }

#pragma unroll
  for (int i = 0; i < 4; ++i)
#pragma unroll
    for (int j = 0; j < 4; ++j)
#pragma unroll
      for (int r = 0; r < 4; ++r) {
        int m = bm + wr * 64 + i * 16 + fq * 4 + r;
        int n = bn + wc * 64 + j * 16 + fr;
        float v = acc[i][j][r];
        if (MODE == 0) {
          stc(C + (size_t)m * N + n, v);
        } else if (MODE == 1) {
          int b = m >> 11, s = m & 2047, hh = n >> 7, d = n & 127;
          stc(C + (((size_t)(b * H + hh)) * S_LEN + s) * HD + d, v);
        } else {
          int b = m >> 11, s = m & 2047, hh = n >> 7, d = n & 127;
          stc(C + (((size_t)(b * H + hh)) * HD + d) * S_LEN + s, v);
        }
      }
}

// ====== causal GQA flash attention (QBLK=128, LPT, defer-max, 40KB LDS) ======
// Q [B,32,S,128], K [B,8,S,128], V^T [B,8,128,S]; out [B*S,4096] bf16.
// grid (16, B*32), block 256. LPT: q0=(15-bx)*128. Wave owns 32 q-rows.
// XOR swizzle granule ^= (row&7) on K/V/P; gload16 with pre-swizzled source.
// Defer-max THR=8; l lane-local, epilogue-reduced. sP halved (8KB): one
// 16-row buffer reused across the two u-fragments -> LDS 40KB -> 4 blocks/CU.
__global__ __launch_bounds__(256, 2)
void attn_kernel(const u16* __restrict__ Q, const u16* __restrict__ K,
                 const u16* __restrict__ V, u16* __restrict__ O) {
  __shared__ u16 sK[64 * 128];   // [kv][d], swizzled (16 KB)
  __shared__ u16 sV[128 * 64];   // [d][kv], swizzled (16 KB)
  __shared__ u16 sP[4][16 * 64]; // per-wave P (16 rows, reused per u) (8 KB)

  const int tid = threadIdx.x, lane = tid & 63, wv = tid >> 6;
  const int fr = lane & 15, fq = lane >> 4;
  const int q0 = (15 - blockIdx.x) * 128;  // LPT
  const int bh = blockIdx.y;
  const int b = bh >> 5, h = bh & 31;
  const int hkv = h >> 2;
  const u16* Qb = Q + (size_t)bh * S_LEN * HD;
  const u16* Kb = K + (size_t)(b * NKVH + hkv) * S_LEN * HD;
  const u16* Vb = V + (size_t)(b * NKVH + hkv) * HD * S_LEN;

  bf16x8 qf[2][4];
#pragma unroll
  for (int u = 0; u < 2; ++u) {
    int qrow = q0 + wv * 32 + u * 16 + fr;
#pragma unroll
    for (int ks = 0; ks < 4; ++ks)
      qf[u][ks] = *(const bf16x8*)(Qb + (size_t)qrow * HD + ks * 32 + fq * 8);
  }

  f32x4 zero4 = {0.f, 0.f, 0.f, 0.f};
  f32x4 o[2][8];
  float m[2][4], l[2][4];
#pragma unroll
  for (int u = 0; u < 2; ++u) {
#pragma unroll
    for (int dt = 0; dt < 8; ++dt) o[u][dt] = zero4;
#pragma unroll
    for (int r = 0; r < 4; ++r) { m[u][r] = -3.0e38f; l[u][r] = 0.f; }
  }

  const int ntiles = (q0 >> 6) + 2;
  for (int t = 0; t < ntiles; ++t) {
    const int s0 = t * 64;
    __syncthreads();
#pragma unroll
    for (int j = 0; j < 4; ++j) {
      int c = j * 4 + wv;
      {
        int row = c * 4 + (lane >> 4);
        int e = ((lane & 15) ^ (row & 7)) * 8;
        gload16(Kb + (size_t)(s0 + row) * HD + e, sK + c * 512);
      }
      {
        int row = c * 8 + (lane >> 3);
        int e = ((lane & 7) ^ (row & 7)) * 8;
        gload16(Vb + (size_t)row * S_LEN + s0 + e, sV + c * 512);
      }
    }
    __syncthreads();

    f32x4 sc[2][4];
#pragma unroll
    for (int u = 0; u < 2; ++u)
#pragma unroll
      for (int j = 0; j < 4; ++j) sc[u][j] = zero4;
#pragma unroll
    for (int j = 0; j < 4; ++j) {
#pragma unroll
      for (int ks = 0; ks < 4; ++ks) {
        int row = j * 16 + fr;
        int e = (ks * 32 + fq * 8) ^ ((row & 7) << 3);
        bf16x8 kf = *(const bf16x8*)(sK + row * 128 + e);
#pragma unroll
        for (int u = 0; u < 2; ++u)
          sc[u][j] = __builtin_amdgcn_mfma_f32_16x16x32_bf16(qf[u][ks], kf, sc[u][j], 0, 0, 0);
      }
    }

    if (t >= ntiles - 2) {
#pragma unroll
      for (int u = 0; u < 2; ++u)
#pragma unroll
        for (int j = 0; j < 4; ++j)
#pragma unroll
          for (int r = 0; r < 4; ++r) {
            int kvp = s0 + j * 16 + fr;
            int qp = q0 + wv * 32 + u * 16 + fq * 4 + r;
            if (kvp > qp) sc[u][j][r] = -3.0e38f;
          }
    }

    // softmax + P-repack per u-fragment (sP reused across u)
    bf16x8 pa[2][2];
#pragma unroll
    for (int u = 0; u < 2; ++u) {
      float al[4];
      bool resc = false;
#pragma unroll
      for (int r = 0; r < 4; ++r) {
        float v = fmaxf(fmaxf(sc[u][0][r], sc[u][1][r]), fmaxf(sc[u][2][r], sc[u][3][r]));
        v = fmaxf(v, __shfl_xor(v, 1, 64));
        v = fmaxf(v, __shfl_xor(v, 2, 64));
        v = fmaxf(v, __shfl_xor(v, 4, 64));
        v = fmaxf(v, __shfl_xor(v, 8, 64));
        if (v > m[u][r] + 8.f) {
          al[r] = __expf(m[u][r] - v);
          m[u][r] = v;
          resc = true;
        } else {
          al[r] = 1.f;
        }
      }
#pragma unroll
      for (int r = 0; r < 4; ++r) {
        float rs = 0.f;
        int prow = fq * 4 + r;
#pragma unroll
        for (int j = 0; j < 4; ++j) {
          float pv = __expf(sc[u][j][r] - m[u][r]);
          rs += pv;
          int e = (j * 16 + fr) ^ ((prow & 7) << 3);
          sP[wv][prow * 64 + e] = f2bf(pv);
        }
        l[u][r] = l[u][r] * al[r] + rs;
      }
      if (resc) {
#pragma unroll
        for (int r = 0; r < 4; ++r)
#pragma unroll
          for (int dt = 0; dt < 8; ++dt) o[u][dt][r] *= al[r];
      }
#pragma unroll
      for (int ks = 0; ks < 2; ++ks) {
        int e = (ks * 32 + fq * 8) ^ ((fr & 7) << 3);
        pa[u][ks] = *(const bf16x8*)(&sP[wv][fr * 64 + e]);
      }
    }

    // PV: o[u][dt] rows q, cols d=dt*16+fr; each vf feeds both u-fragments
#pragma unroll
    for (int dt = 0; dt < 8; ++dt) {
#pragma unroll
      for (int ks = 0; ks < 2; ++ks) {
        int row = dt * 16 + fr;
        int e = (ks * 32 + fq * 8) ^ ((row & 7) << 3);
        bf16x8 vf = *(const bf16x8*)(sV + row * 64 + e);
#pragma unroll
        for (int u = 0; u < 2; ++u)
          o[u][dt] = __builtin_amdgcn_mfma_f32_16x16x32_bf16(pa[u][ks], vf, o[u][dt], 0, 0, 0);
      }
    }
  }

#pragma unroll
  for (int u = 0; u < 2; ++u)
#pragma unroll
    for (int r = 0; r < 4; ++r) {
      float lt = l[u][r];
      lt += __shfl_xor(lt, 1, 64);
      lt += __shfl_xor(lt, 2, 64);
      lt += __shfl_xor(lt, 4, 64);
      lt += __shfl_xor(lt, 8, 64);
      int qp = q0 + wv * 32 + u * 16 + fq * 4 + r;
      float inv_l = 1.0f / lt;
      size_t base = ((size_t)b * S_LEN + qp) * DM + h * HD;
#pragma unroll
      for (int dt = 0; dt < 8; ++dt)
        O[base + dt * 16 + fr] = f2bf(o[u][dt][r] * inv_l);
    }
}

// ---------------- RoPE apply (fallback path, single-buffer) ----------------
__global__ void rope_apply(u16* __restrict__ X, const float* __restrict__ sin_t,
                           const float* __restrict__ cos_t, float scale, int nrows) {
  int idx = blockIdx.x * blockDim.x + threadIdx.x;
  if (idx >= nrows * 64) return;
  int row = idx >> 6, i = idx & 63;
  int s = row & (S_LEN - 1);
  size_t base = (size_t)row * HD;
  float lo = bf2f(X[base + i]);
  float hi = bf2f(X[base + i + 64]);
  float sn = sin_t[s * 64 + i];
  float cs = cos_t[s * 64 + i];
  X[base + i] = f2bf((lo * cs - hi * sn) * scale);
  X[base + i + 64] = f2bf((hi * cs + lo * sn) * scale);
}

extern "C" void kernel_launch(void* const* d_in, const int* in_sizes, int n_in,
                              void* d_out, int out_size, void* d_ws, size_t ws_size,
                              hipStream_t stream) {
  const float* x  = (const float*)d_in[0];
  const float* wq = (const float*)d_in[1];
  const float* wk = (const float*)d_in[2];
  const float* wv = (const float*)d_in[3];
  const float* wo = (const float*)d_in[4];

  char* ws = (char*)d_ws;
  size_t off = 0;
  auto alloc = [&](size_t bytes) {
    void* p = ws + off;
    off += (bytes + 255) & ~(size_t)255;
    return p;
  };

  const size_t nx  = (size_t)2 * S_LEN * DM;       // 16.78M elements
  const size_t nwq = (size_t)DM * DM;              // 16.78M
  const size_t nwk = (size_t)(NKVH * HD) * DM;     // 4.19M

  const float scale = 0.08838834764831845f;  // 1/sqrt(128), folded into Q
  const int nrq = 2 * NQH * S_LEN, nrk = 2 * NKVH * S_LEN;
  dim3 blk(256);

  if (ws_size >= ((size_t)180 << 20)) {
    // -------- fast path: mega-cvt + fused QKV GEMM + fused rope --------
    u16* xb    = (u16*)alloc(nx * 2);                 // aob aliases after use
    u16* wqkvb = (u16*)alloc((nwq + 2 * nwk) * 2);    // [wq;wk;wv] 6144x4096
    u16* wob   = (u16*)alloc(nwq * 2);
    u16* qb    = (u16*)alloc(nx * 2);
    u16* kb    = (u16*)alloc(nwk * 2);
    u16* vtb   = (u16*)alloc(nwk * 2);
    float* sin_t = (float*)alloc((size_t)S_LEN * 64 * 4);
    float* cos_t = (float*)alloc((size_t)S_LEN * 64 * 4);
    u16* aob = xb;  // alias: x (bf16) dead after QKV projection

    cvt_all<<<2048, 256, 0, stream>>>(x, wq, wk, wv, wo, xb, wqkvb, wob);
    rope_table_kernel<<<(S_LEN * 64 + 255) / 256, 256, 0, stream>>>(sin_t, cos_t);

    gemm_qkv<<<dim3(48, 32), blk, 0, stream>>>(xb, wqkvb, qb, kb, vtb, DM);

    rope_apply2<<<(((size_t)(nrq + nrk)) * 64 + 255) / 256, 256, 0, stream>>>(
        qb, kb, sin_t, cos_t, scale, nrq, nrk);

    attn_kernel<<<dim3(16, 64), blk, 0, stream>>>(qb, kb, vtb, aob);

    gemm16<0, float><<<dim3(32, 32), blk, 0, stream>>>(aob, wob, (float*)d_out, 4096, DM, DM, 0);
  } else {
    // -------- fallback: proven round-10 path (f32 reg-staged GEMMs) --------
    u16* qb  = (u16*)alloc(nx * 2);
    u16* kb  = (u16*)alloc(nwk * 2);
    u16* vtb = (u16*)alloc(nwk * 2);
    u16* aob = (u16*)alloc(nx * 2);
    float* sin_t = (float*)alloc((size_t)S_LEN * 64 * 4);
    float* cos_t = (float*)alloc((size_t)S_LEN * 64 * 4);

    rope_table_kernel<<<(S_LEN * 64 + 255) / 256, 256, 0, stream>>>(sin_t, cos_t);

    gemm_bt<1, float, float, u16><<<dim3(32, 32), blk, 0, stream>>>(x, wq, qb, 4096, DM, DM, NQH);
    gemm_bt<1, float, float, u16><<<dim3(8, 32), blk, 0, stream>>>(x, wk, kb, 4096, 1024, DM, NKVH);
    gemm_bt<2, float, float, u16><<<dim3(8, 32), blk, 0, stream>>>(x, wv, vtb, 4096, 1024, DM, NKVH);

    rope_apply<<<((size_t)nrq * 64 + 255) / 256, 256, 0, stream>>>(qb, sin_t, cos_t, scale, nrq);
    rope_apply<<<((size_t)nrk * 64 + 255) / 256, 256, 0, stream>>>(kb, sin_t, cos_t, 1.0f, nrk);

    attn_kernel<<<dim3(16, 64), blk, 0, stream>>>(qb, kb, vtb, aob);

    gemm_bt<0, u16, float, float><<<dim3(32, 32), blk, 0, stream>>>(aob, wo, (float*)d_out, 4096, DM, DM, 0);
  }
}

// Round 23
// 712.982 us; speedup vs baseline: 1.0313x; 1.0052x over previous
//
#include <hip/hip_runtime.h>
#include <cstdint>

#define S_LEN 2048
#define DM 4096
#define NQH 32
#define NKVH 8
#define HD 128

typedef __bf16 bf16x8 __attribute__((ext_vector_type(8)));
typedef float f32x4 __attribute__((ext_vector_type(4)));
typedef unsigned short u16;
typedef unsigned short u16x8 __attribute__((ext_vector_type(8)));
typedef unsigned int u32;

__device__ __forceinline__ float bf2f(u16 h) {
  union { u32 u; float f; } v; v.u = ((u32)h) << 16; return v.f;
}
__device__ __forceinline__ u16 f2bf(float f) {
  union { float f; u32 u; } v; v.f = f;
  u32 u = v.u;
  return (u16)((u + 0x7FFFu + ((u >> 16) & 1u)) >> 16);
}

// global -> LDS direct DMA, 16B/lane. LDS dest = wave-uniform base + lane*16;
// global source is per-lane (bit-validated vs reg-staged path).
__device__ __forceinline__ void gload16(const void* g, const void* l) {
  __builtin_amdgcn_global_load_lds(
      (const __attribute__((address_space(1))) u32*)(uintptr_t)g,
      (__attribute__((address_space(3))) u32*)(u32)(uintptr_t)l,
      16, 0, 0);
}

// ---- reg-staging helpers (fallback path): 16 elements global -> LDS
__device__ __forceinline__ void stage16(const float* __restrict__ g, u16* l) {
  const float4* gp = reinterpret_cast<const float4*>(g);
  float4 v0 = gp[0], v1 = gp[1], v2 = gp[2], v3 = gp[3];
  u16x8 a, b;
  a[0] = f2bf(v0.x); a[1] = f2bf(v0.y); a[2] = f2bf(v0.z); a[3] = f2bf(v0.w);
  a[4] = f2bf(v1.x); a[5] = f2bf(v1.y); a[6] = f2bf(v1.z); a[7] = f2bf(v1.w);
  b[0] = f2bf(v2.x); b[1] = f2bf(v2.y); b[2] = f2bf(v2.z); b[3] = f2bf(v2.w);
  b[4] = f2bf(v3.x); b[5] = f2bf(v3.y); b[6] = f2bf(v3.z); b[7] = f2bf(v3.w);
  *reinterpret_cast<u16x8*>(l) = a;
  *reinterpret_cast<u16x8*>(l + 8) = b;
}
__device__ __forceinline__ void stage16(const u16* __restrict__ g, u16* l) {
  *reinterpret_cast<u16x8*>(l) = *reinterpret_cast<const u16x8*>(g);
  *reinterpret_cast<u16x8*>(l + 8) = *reinterpret_cast<const u16x8*>(g + 8);
}

// output store: bf16 (intermediates) or f32 (final d_out)
__device__ __forceinline__ void stc(u16* p, float v) { *p = f2bf(v); }
__device__ __forceinline__ void stc(float* p, float v) { *p = v; }

// ---------------- mega convert: all 5 f32 inputs -> bf16, one launch --------
__device__ __forceinline__ void cvt8(const float* in, u16* out, size_t i8) {
  const float4* gp = reinterpret_cast<const float4*>(in) + i8 * 2;
  float4 a = gp[0], b = gp[1];
  u16x8 o;
  o[0] = f2bf(a.x); o[1] = f2bf(a.y); o[2] = f2bf(a.z); o[3] = f2bf(a.w);
  o[4] = f2bf(b.x); o[5] = f2bf(b.y); o[6] = f2bf(b.z); o[7] = f2bf(b.w);
  reinterpret_cast<u16x8*>(out)[i8] = o;
}
__global__ void cvt_all(const float* x, const float* wq, const float* wk,
                        const float* wv, const float* wo,
                        u16* xb, u16* wqkvb, u16* wob) {
  const size_t NX8 = (size_t)2 * S_LEN * DM / 8;     // 2.097M
  const size_t NW8 = (size_t)DM * DM / 8;            // 2.097M
  const size_t NK8 = (size_t)NKVH * HD * DM / 8;     // 0.524M
  const size_t total = NX8 + NW8 + 2 * NK8 + NW8;
  size_t stride = (size_t)gridDim.x * blockDim.x;
  for (size_t i = (size_t)blockIdx.x * blockDim.x + threadIdx.x; i < total; i += stride) {
    if (i < NX8)                       cvt8(x,  xb,                    i);
    else if (i < NX8 + NW8)            cvt8(wq, wqkvb,                 i - NX8);
    else if (i < NX8 + NW8 + NK8)      cvt8(wk, wqkvb + NW8 * 8,       i - NX8 - NW8);
    else if (i < NX8 + NW8 + 2 * NK8)  cvt8(wv, wqkvb + (NW8 + NK8) * 8, i - NX8 - NW8 - NK8);
    else                               cvt8(wo, wob,                   i - NX8 - NW8 - 2 * NK8);
  }
}

// ---------------- RoPE table (llama3 scaling), fp64 ----------------
__global__ void rope_table_kernel(float* __restrict__ sin_t, float* __restrict__ cos_t) {
  int idx = blockIdx.x * blockDim.x + threadIdx.x;
  if (idx >= S_LEN * 64) return;
  int s = idx >> 6, i = idx & 63;
  const double PI = 3.14159265358979323846;
  double freq = pow(500000.0, -((double)i) / 64.0);
  double wavelen = 2.0 * PI / freq;
  double inv = (wavelen > 8192.0) ? freq / 32.0 : freq;
  if (!(wavelen < 2048.0) && !(wavelen > 8192.0)) {
    double smooth = (8192.0 / wavelen - 1.0) / 3.0;
    inv = (1.0 - smooth) * (freq / 32.0) + smooth * freq;
  }
  double ang = (double)s * inv;
  sin_t[idx] = (float)sin(ang);
  cos_t[idx] = (float)cos(ang);
}

// ---------------- RoPE apply: Q (scaled) and K in ONE launch ----------------
__global__ void rope_apply2(u16* __restrict__ Xq, u16* __restrict__ Xk,
                            const float* __restrict__ sin_t,
                            const float* __restrict__ cos_t,
                            float scale, int nrq, int nrk) {
  int idx = blockIdx.x * blockDim.x + threadIdx.x;
  if (idx >= (nrq + nrk) * 64) return;
  int row = idx >> 6, i = idx & 63;
  u16* X;
  float sc;
  if (row < nrq) { X = Xq; sc = scale; }
  else { X = Xk; row -= nrq; sc = 1.0f; }
  int s = row & (S_LEN - 1);
  size_t base = (size_t)row * HD;
  float lo = bf2f(X[base + i]);
  float hi = bf2f(X[base + i + 64]);
  float sn = sin_t[s * 64 + i];
  float cs = cos_t[s * 64 + i];
  X[base + i] = f2bf((lo * cs - hi * sn) * sc);
  X[base + i + 64] = f2bf((hi * cs + lo * sn) * sc);
}

// ================= GEMM (bf16 inputs, gload16 staging, m97 structure) ========
// C = A(MxK) * B(NxK)^T, f32 acc.  MODE 0: C[m*N+n].
// T2 both-sides LDS swizzle (round-22: conflicts 2.5e7 -> 0).
// launch_bounds (256,4): VGPR 56 + ~64 AGPR fits the 128/wave cap; raises
// resident blocks/CU so one block's barrier drain hides under another's MFMA.
template <int MODE, typename TC>
__global__ __launch_bounds__(256, 4)
void gemm16(const u16* __restrict__ A, const u16* __restrict__ B,
            TC* __restrict__ C, int M, int N, int K, int H) {
  __shared__ u16 sA[128 * 32];
  __shared__ u16 sB[128 * 32];
  const int tid = threadIdx.x;
  const int lane = tid & 63;
  const int wv = tid >> 6;
  const int wr = wv >> 1, wc = wv & 1;
  const int bm = blockIdx.y * 128;
  const int bn = blockIdx.x * 128;
  const int fr = lane & 15, fq = lane >> 4;
  const int srow = lane >> 2;                               // row within 16-row chunk
  const int scol = (((lane & 3) ^ ((lane >> 3) & 3)) * 8);  // swizzled source granule
  const int rsw = (fr >> 1) & 3;                            // read-side XOR (lane const)

  f32x4 zero4 = {0.f, 0.f, 0.f, 0.f};
  f32x4 acc[4][4];
#pragma unroll
  for (int i = 0; i < 4; ++i)
#pragma unroll
    for (int j = 0; j < 4; ++j) acc[i][j] = zero4;

  for (int k0 = 0; k0 < K; k0 += 32) {
    __syncthreads();
#pragma unroll
    for (int j = 0; j < 2; ++j) {
      int c = j * 4 + wv;
      int row = c * 16 + srow;
      gload16(A + (size_t)(bm + row) * K + k0 + scol, sA + c * 512);
      gload16(B + (size_t)(bn + row) * K + k0 + scol, sB + c * 512);
    }
    __syncthreads();
    bf16x8 af[4], bg[4];
#pragma unroll
    for (int i = 0; i < 4; ++i) {
      af[i] = *(const bf16x8*)(sA + (wr * 64 + i * 16 + fr) * 32 + (fq ^ rsw) * 8);
      bg[i] = *(const bf16x8*)(sB + (wc * 64 + i * 16 + fr) * 32 + (fq ^ rsw) * 8);
    }
#pragma unroll
    for (int i = 0; i < 4; ++i)
#pragma unroll
      for (int j = 0; j < 4; ++j)
        acc[i][j] = __builtin_amdgcn_mfma_f32_16x16x32_bf16(af[i], bg[j], acc[i][j], 0, 0, 0);
  }

#pragma unroll
  for (int i = 0; i < 4; ++i)
#pragma unroll
    for (int j = 0; j < 4; ++j)
#pragma unroll
      for (int r = 0; r < 4; ++r) {
        int m = bm + wr * 64 + i * 16 + fq * 4 + r;
        int n = bn + wc * 64 + j * 16 + fr;
        stc(C + (size_t)m * N + n, acc[i][j][r]);
      }
}

// ========== fused QKV projection GEMM: A=x[4096x4096], B=[wq;wk;wv] =========
// N=6144. T2 swizzle + (256,4) occupancy as gemm16. Epilogue scatter by
// segment (block-uniform: boundaries %128==0): n<4096: Q [B,32,S,128];
// 4096<=n<5120: K [B,8,S,128]; else V^T [B,8,128,S].
__global__ __launch_bounds__(256, 4)
void gemm_qkv(const u16* __restrict__ A, const u16* __restrict__ B,
              u16* __restrict__ Cq, u16* __restrict__ Ck, u16* __restrict__ Cv,
              int K) {
  __shared__ u16 sA[128 * 32];
  __shared__ u16 sB[128 * 32];
  const int tid = threadIdx.x;
  const int lane = tid & 63;
  const int wv = tid >> 6;
  const int wr = wv >> 1, wc = wv & 1;
  const int bm = blockIdx.y * 128;
  const int bn = blockIdx.x * 128;
  const int fr = lane & 15, fq = lane >> 4;
  const int srow = lane >> 2;
  const int scol = (((lane & 3) ^ ((lane >> 3) & 3)) * 8);  // swizzled source granule
  const int rsw = (fr >> 1) & 3;

  f32x4 zero4 = {0.f, 0.f, 0.f, 0.f};
  f32x4 acc[4][4];
#pragma unroll
  for (int i = 0; i < 4; ++i)
#pragma unroll
    for (int j = 0; j < 4; ++j) acc[i][j] = zero4;

  for (int k0 = 0; k0 < K; k0 += 32) {
    __syncthreads();
#pragma unroll
    for (int j = 0; j < 2; ++j) {
      int c = j * 4 + wv;
      int row = c * 16 + srow;
      gload16(A + (size_t)(bm + row) * K + k0 + scol, sA + c * 512);
      gload16(B + (size_t)(bn + row) * K + k0 + scol, sB + c * 512);
    }
    __syncthreads();
    bf16x8 af[4], bg[4];
#pragma unroll
    for (int i = 0; i < 4; ++i) {
      af[i] = *(const bf16x8*)(sA + (wr * 64 + i * 16 + fr) * 32 + (fq ^ rsw) * 8);
      bg[i] = *(const bf16x8*)(sB + (wc * 64 + i * 16 + fr) * 32 + (fq ^ rsw) * 8);
    }
#pragma unroll
    for (int i = 0; i < 4; ++i)
#pragma unroll
      for (int j = 0; j < 4; ++j)
        acc[i][j] = __builtin_amdgcn_mfma_f32_16x16x32_bf16(af[i], bg[j], acc[i][j], 0, 0, 0);
  }

#pragma unroll
  for (int i = 0; i < 4; ++i)
#pragma unroll
    for (int j = 0; j < 4; ++j)
#pragma unroll
      for (int r = 0; r < 4; ++r) {
        int m = bm + wr * 64 + i * 16 + fq * 4 + r;
        int n = bn + wc * 64 + j * 16 + fr;
        int b = m >> 11, s = m & 2047;
        u16 hval = f2bf(acc[i][j][r]);
        if (n < 4096) {
          int hh = n >> 7, d = n & 127;
          Cq[(((size_t)(b * NQH + hh)) * S_LEN + s) * HD + d] = hval;
        } else if (n < 5120) {
          int nn = n - 4096;
          int hh = nn >> 7, d = nn & 127;
          Ck[(((size_t)(b * NKVH + hh)) * S_LEN + s) * HD + d] = hval;
        } else {
          int nn = n - 5120;
          int hh = nn >> 7, d = nn & 127;
          Cv[(((size_t)(b * NKVH + hh)) * HD + d) * S_LEN + s] = hval;
        }
      }
}

// ================= GEMM fallback (reg-staged; round-10, templated A/B) =======
template <int MODE, typename TA, typename TB, typename TC>
__global__ __launch_bounds__(256, 2)
void gemm_bt(const TA* __restrict__ A, const TB* __restrict__ B,
             TC* __restrict__ C, int M, int N, int K, int H) {
  __shared__ u16 sA[128 * 32];
  __shared__ u16 sB[128 * 32];
  const int tid = threadIdx.x;
  const int lane = tid & 63;
  const int wv = tid >> 6;
  const int wr = wv >> 1, wc = wv & 1;
  const int bm = blockIdx.y * 128;
  const int bn = blockIdx.x * 128;
  const int fr = lane & 15, fq = lane >> 4;
  const int srow = tid >> 1;
  const int shalf = (tid & 1) * 16;

  f32x4 zero4 = {0.f, 0.f, 0.f, 0.f};
  f32x4 acc[4][4];
#pragma unroll
  for (int i = 0; i < 4; ++i)
#pragma unroll
    for (int j = 0; j < 4; ++j) acc[i][j] = zero4;

  for (int k0 = 0; k0 < K; k0 += 32) {
    __syncthreads();
    stage16(A + (size_t)(bm + srow) * K + k0 + shalf, sA + srow * 32 + shalf);
    stage16(B + (size_t)(bn + srow) * K + k0 + shalf, sB + srow * 32 + shalf);
    __syncthreads();
    bf16x8 af[4], bg[4];
#pragma unroll
    for (int i = 0; i < 4; ++i) {
      af[i] = *(const bf16x8*)(sA + (wr * 64 + i * 16 + fr) * 32 + fq * 8);
      bg[i] = *(const bf16x8*)(sB + (wc * 64 + i * 16 + fr) * 32 + fq * 8);
    }
#pragma unroll
    for (int i = 0; i < 4; ++i)
#pragma unroll
      for (int j = 0; j < 4; ++j)
        acc[i][j] = __builtin_amdgcn_mfma_f32_16x16x32_bf16(af[i], bg[j], acc[i][j], 0, 0, 0);
  }

#pragma unroll
  for (int i = 0; i < 4; ++i)
#pragma unroll
    for (int j = 0; j < 4; ++j)
#pragma unroll
      for (int r = 0; r < 4; ++r) {
        int m = bm + wr * 64 + i * 16 + fq * 4 + r;
        int n = bn + wc * 64 + j * 16 + fr;
        float v = acc[i][j][r];
        if (MODE == 0) {
          stc(C + (size_t)m * N + n, v);
        } else if (MODE == 1) {
          int b = m >> 11, s = m & 2047, hh = n >> 7, d = n & 127;
          stc(C + (((size_t)(b * H + hh)) * S_LEN + s) * HD + d, v);
        } else {
          int b = m >> 11, s = m & 2047, hh = n >> 7, d = n & 127;
          stc(C + (((size_t)(b * H + hh)) * HD + d) * S_LEN + s, v);
        }
      }
}

// ====== causal GQA flash attention (QBLK=128, LPT, defer-max, 40KB LDS) ======
// Q [B,32,S,128], K [B,8,S,128], V^T [B,8,128,S]; out [B*S,4096] bf16.
// grid (16, B*32), block 256. LPT: q0=(15-bx)*128. Wave owns 32 q-rows.
// XOR swizzle granule ^= (row&7) on K/V/P; gload16 with pre-swizzled source.
// Defer-max THR=8; l lane-local, epilogue-reduced. sP halved (8KB): one
// 16-row buffer reused across the two u-fragments -> LDS 40KB.
__global__ __launch_bounds__(256, 2)
void attn_kernel(const u16* __restrict__ Q, const u16* __restrict__ K,
                 const u16* __restrict__ V, u16* __restrict__ O) {
  __shared__ u16 sK[64 * 128];   // [kv][d], swizzled (16 KB)
  __shared__ u16 sV[128 * 64];   // [d][kv], swizzled (16 KB)
  __shared__ u16 sP[4][16 * 64]; // per-wave P (16 rows, reused per u) (8 KB)

  const int tid = threadIdx.x, lane = tid & 63, wv = tid >> 6;
  const int fr = lane & 15, fq = lane >> 4;
  const int q0 = (15 - blockIdx.x) * 128;  // LPT
  const int bh = blockIdx.y;
  const int b = bh >> 5, h = bh & 31;
  const int hkv = h >> 2;
  const u16* Qb = Q + (size_t)bh * S_LEN * HD;
  const u16* Kb = K + (size_t)(b * NKVH + hkv) * S_LEN * HD;
  const u16* Vb = V + (size_t)(b * NKVH + hkv) * HD * S_LEN;

  bf16x8 qf[2][4];
#pragma unroll
  for (int u = 0; u < 2; ++u) {
    int qrow = q0 + wv * 32 + u * 16 + fr;
#pragma unroll
    for (int ks = 0; ks < 4; ++ks)
      qf[u][ks] = *(const bf16x8*)(Qb + (size_t)qrow * HD + ks * 32 + fq * 8);
  }

  f32x4 zero4 = {0.f, 0.f, 0.f, 0.f};
  f32x4 o[2][8];
  float m[2][4], l[2][4];
#pragma unroll
  for (int u = 0; u < 2; ++u) {
#pragma unroll
    for (int dt = 0; dt < 8; ++dt) o[u][dt] = zero4;
#pragma unroll
    for (int r = 0; r < 4; ++r) { m[u][r] = -3.0e38f; l[u][r] = 0.f; }
  }

  const int ntiles = (q0 >> 6) + 2;
  for (int t = 0; t < ntiles; ++t) {
    const int s0 = t * 64;
    __syncthreads();
#pragma unroll
    for (int j = 0; j < 4; ++j) {
      int c = j * 4 + wv;
      {
        int row = c * 4 + (lane >> 4);
        int e = ((lane & 15) ^ (row & 7)) * 8;
        gload16(Kb + (size_t)(s0 + row) * HD + e, sK + c * 512);
      }
      {
        int row = c * 8 + (lane >> 3);
        int e = ((lane & 7) ^ (row & 7)) * 8;
        gload16(Vb + (size_t)row * S_LEN + s0 + e, sV + c * 512);
      }
    }
    __syncthreads();

    f32x4 sc[2][4];
#pragma unroll
    for (int u = 0; u < 2; ++u)
#pragma unroll
      for (int j = 0; j < 4; ++j) sc[u][j] = zero4;
#pragma unroll
    for (int j = 0; j < 4; ++j) {
#pragma unroll
      for (int ks = 0; ks < 4; ++ks) {
        int row = j * 16 + fr;
        int e = (ks * 32 + fq * 8) ^ ((row & 7) << 3);
        bf16x8 kf = *(const bf16x8*)(sK + row * 128 + e);
#pragma unroll
        for (int u = 0; u < 2; ++u)
          sc[u][j] = __builtin_amdgcn_mfma_f32_16x16x32_bf16(qf[u][ks], kf, sc[u][j], 0, 0, 0);
      }
    }

    if (t >= ntiles - 2) {
#pragma unroll
      for (int u = 0; u < 2; ++u)
#pragma unroll
        for (int j = 0; j < 4; ++j)
#pragma unroll
          for (int r = 0; r < 4; ++r) {
            int kvp = s0 + j * 16 + fr;
            int qp = q0 + wv * 32 + u * 16 + fq * 4 + r;
            if (kvp > qp) sc[u][j][r] = -3.0e38f;
          }
    }

    // softmax + P-repack per u-fragment (sP reused across u)
    bf16x8 pa[2][2];
#pragma unroll
    for (int u = 0; u < 2; ++u) {
      float al[4];
      bool resc = false;
#pragma unroll
      for (int r = 0; r < 4; ++r) {
        float v = fmaxf(fmaxf(sc[u][0][r], sc[u][1][r]), fmaxf(sc[u][2][r], sc[u][3][r]));
        v = fmaxf(v, __shfl_xor(v, 1, 64));
        v = fmaxf(v, __shfl_xor(v, 2, 64));
        v = fmaxf(v, __shfl_xor(v, 4, 64));
        v = fmaxf(v, __shfl_xor(v, 8, 64));
        if (v > m[u][r] + 8.f) {
          al[r] = __expf(m[u][r] - v);
          m[u][r] = v;
          resc = true;
        } else {
          al[r] = 1.f;
        }
      }
#pragma unroll
      for (int r = 0; r < 4; ++r) {
        float rs = 0.f;
        int prow = fq * 4 + r;
#pragma unroll
        for (int j = 0; j < 4; ++j) {
          float pv = __expf(sc[u][j][r] - m[u][r]);
          rs += pv;
          int e = (j * 16 + fr) ^ ((prow & 7) << 3);
          sP[wv][prow * 64 + e] = f2bf(pv);
        }
        l[u][r] = l[u][r] * al[r] + rs;
      }
      if (resc) {
#pragma unroll
        for (int r = 0; r < 4; ++r)
#pragma unroll
          for (int dt = 0; dt < 8; ++dt) o[u][dt][r] *= al[r];
      }
#pragma unroll
      for (int ks = 0; ks < 2; ++ks) {
        int e = (ks * 32 + fq * 8) ^ ((fr & 7) << 3);
        pa[u][ks] = *(const bf16x8*)(&sP[wv][fr * 64 + e]);
      }
    }

    // PV: o[u][dt] rows q, cols d=dt*16+fr; each vf feeds both u-fragments
#pragma unroll
    for (int dt = 0; dt < 8; ++dt) {
#pragma unroll
      for (int ks = 0; ks < 2; ++ks) {
        int row = dt * 16 + fr;
        int e = (ks * 32 + fq * 8) ^ ((row & 7) << 3);
        bf16x8 vf = *(const bf16x8*)(sV + row * 64 + e);
#pragma unroll
        for (int u = 0; u < 2; ++u)
          o[u][dt] = __builtin_amdgcn_mfma_f32_16x16x32_bf16(pa[u][ks], vf, o[u][dt], 0, 0, 0);
      }
    }
  }

#pragma unroll
  for (int u = 0; u < 2; ++u)
#pragma unroll
    for (int r = 0; r < 4; ++r) {
      float lt = l[u][r];
      lt += __shfl_xor(lt, 1, 64);
      lt += __shfl_xor(lt, 2, 64);
      lt += __shfl_xor(lt, 4, 64);
      lt += __shfl_xor(lt, 8, 64);
      int qp = q0 + wv * 32 + u * 16 + fq * 4 + r;
      float inv_l = 1.0f / lt;
      size_t base = ((size_t)b * S_LEN + qp) * DM + h * HD;
#pragma unroll
      for (int dt = 0; dt < 8; ++dt)
        O[base + dt * 16 + fr] = f2bf(o[u][dt][r] * inv_l);
    }
}

// ---------------- RoPE apply (fallback path, single-buffer) ----------------
__global__ void rope_apply(u16* __restrict__ X, const float* __restrict__ sin_t,
                           const float* __restrict__ cos_t, float scale, int nrows) {
  int idx = blockIdx.x * blockDim.x + threadIdx.x;
  if (idx >= nrows * 64) return;
  int row = idx >> 6, i = idx & 63;
  int s = row & (S_LEN - 1);
  size_t base = (size_t)row * HD;
  float lo = bf2f(X[base + i]);
  float hi = bf2f(X[base + i + 64]);
  float sn = sin_t[s * 64 + i];
  float cs = cos_t[s * 64 + i];
  X[base + i] = f2bf((lo * cs - hi * sn) * scale);
  X[base + i + 64] = f2bf((hi * cs + lo * sn) * scale);
}

extern "C" void kernel_launch(void* const* d_in, const int* in_sizes, int n_in,
                              void* d_out, int out_size, void* d_ws, size_t ws_size,
                              hipStream_t stream) {
  const float* x  = (const float*)d_in[0];
  const float* wq = (const float*)d_in[1];
  const float* wk = (const float*)d_in[2];
  const float* wv = (const float*)d_in[3];
  const float* wo = (const float*)d_in[4];

  char* ws = (char*)d_ws;
  size_t off = 0;
  auto alloc = [&](size_t bytes) {
    void* p = ws + off;
    off += (bytes + 255) & ~(size_t)255;
    return p;
  };

  const size_t nx  = (size_t)2 * S_LEN * DM;       // 16.78M elements
  const size_t nwq = (size_t)DM * DM;              // 16.78M
  const size_t nwk = (size_t)(NKVH * HD) * DM;     // 4.19M

  const float scale = 0.08838834764831845f;  // 1/sqrt(128), folded into Q
  const int nrq = 2 * NQH * S_LEN, nrk = 2 * NKVH * S_LEN;
  dim3 blk(256);

  if (ws_size >= ((size_t)180 << 20)) {
    // -------- fast path: mega-cvt + fused QKV GEMM + fused rope --------
    u16* xb    = (u16*)alloc(nx * 2);                 // aob aliases after use
    u16* wqkvb = (u16*)alloc((nwq + 2 * nwk) * 2);    // [wq;wk;wv] 6144x4096
    u16* wob   = (u16*)alloc(nwq * 2);
    u16* qb    = (u16*)alloc(nx * 2);
    u16* kb    = (u16*)alloc(nwk * 2);
    u16* vtb   = (u16*)alloc(nwk * 2);
    float* sin_t = (float*)alloc((size_t)S_LEN * 64 * 4);
    float* cos_t = (float*)alloc((size_t)S_LEN * 64 * 4);
    u16* aob = xb;  // alias: x (bf16) dead after QKV projection

    cvt_all<<<2048, 256, 0, stream>>>(x, wq, wk, wv, wo, xb, wqkvb, wob);
    rope_table_kernel<<<(S_LEN * 64 + 255) / 256, 256, 0, stream>>>(sin_t, cos_t);

    gemm_qkv<<<dim3(48, 32), blk, 0, stream>>>(xb, wqkvb, qb, kb, vtb, DM);

    rope_apply2<<<(((size_t)(nrq + nrk)) * 64 + 255) / 256, 256, 0, stream>>>(
        qb, kb, sin_t, cos_t, scale, nrq, nrk);

    attn_kernel<<<dim3(16, 64), blk, 0, stream>>>(qb, kb, vtb, aob);

    gemm16<0, float><<<dim3(32, 32), blk, 0, stream>>>(aob, wob, (float*)d_out, 4096, DM, DM, 0);
  } else {
    // -------- fallback: proven round-10 path (f32 reg-staged GEMMs) --------
    u16* qb  = (u16*)alloc(nx * 2);
    u16* kb  = (u16*)alloc(nwk * 2);
    u16* vtb = (u16*)alloc(nwk * 2);
    u16* aob = (u16*)alloc(nx * 2);
    float* sin_t = (float*)alloc((size_t)S_LEN * 64 * 4);
    float* cos_t = (float*)alloc((size_t)S_LEN * 64 * 4);

    rope_table_kernel<<<(S_LEN * 64 + 255) / 256, 256, 0, stream>>>(sin_t, cos_t);

    gemm_bt<1, float, float, u16><<<dim3(32, 32), blk, 0, stream>>>(x, wq, qb, 4096, DM, DM, NQH);
    gemm_bt<1, float, float, u16><<<dim3(8, 32), blk, 0, stream>>>(x, wk, kb, 4096, 1024, DM, NKVH);
    gemm_bt<2, float, float, u16><<<dim3(8, 32), blk, 0, stream>>>(x, wv, vtb, 4096, 1024, DM, NKVH);

    rope_apply<<<((size_t)nrq * 64 + 255) / 256, 256, 0, stream>>>(qb, sin_t, cos_t, scale, nrq);
    rope_apply<<<((size_t)nrk * 64 + 255) / 256, 256, 0, stream>>>(kb, sin_t, cos_t, 1.0f, nrk);

    attn_kernel<<<dim3(16, 64), blk, 0, stream>>>(qb, kb, vtb, aob);

    gemm_bt<0, u16, float, float><<<dim3(32, 32), blk, 0, stream>>>(aob, wo, (float*)d_out, 4096, DM, DM, 0);
  }
}

// Round 24
// 675.639 us; speedup vs baseline: 1.0883x; 1.0553x over previous
//
#include <hip/hip_runtime.h>
#include <cstdint>

#define S_LEN 2048
#define DM 4096
#define NQH 32
#define NKVH 8
#define HD 128

typedef __bf16 bf16x8 __attribute__((ext_vector_type(8)));
typedef float f32x4 __attribute__((ext_vector_type(4)));
typedef unsigned short u16;
typedef unsigned short u16x8 __attribute__((ext_vector_type(8)));
typedef unsigned int u32;

__device__ __forceinline__ float bf2f(u16 h) {
  union { u32 u; float f; } v; v.u = ((u32)h) << 16; return v.f;
}
__device__ __forceinline__ u16 f2bf(float f) {
  union { float f; u32 u; } v; v.f = f;
  u32 u = v.u;
  return (u16)((u + 0x7FFFu + ((u >> 16) & 1u)) >> 16);
}

// global -> LDS direct DMA, 16B/lane. LDS dest = wave-uniform base + lane*16;
// global source is per-lane (bit-validated vs reg-staged path).
__device__ __forceinline__ void gload16(const void* g, const void* l) {
  __builtin_amdgcn_global_load_lds(
      (const __attribute__((address_space(1))) u32*)(uintptr_t)g,
      (__attribute__((address_space(3))) u32*)(u32)(uintptr_t)l,
      16, 0, 0);
}

// ---- reg-staging helpers (fallback path): 16 elements global -> LDS
__device__ __forceinline__ void stage16(const float* __restrict__ g, u16* l) {
  const float4* gp = reinterpret_cast<const float4*>(g);
  float4 v0 = gp[0], v1 = gp[1], v2 = gp[2], v3 = gp[3];
  u16x8 a, b;
  a[0] = f2bf(v0.x); a[1] = f2bf(v0.y); a[2] = f2bf(v0.z); a[3] = f2bf(v0.w);
  a[4] = f2bf(v1.x); a[5] = f2bf(v1.y); a[6] = f2bf(v1.z); a[7] = f2bf(v1.w);
  b[0] = f2bf(v2.x); b[1] = f2bf(v2.y); b[2] = f2bf(v2.z); b[3] = f2bf(v2.w);
  b[4] = f2bf(v3.x); b[5] = f2bf(v3.y); b[6] = f2bf(v3.z); b[7] = f2bf(v3.w);
  *reinterpret_cast<u16x8*>(l) = a;
  *reinterpret_cast<u16x8*>(l + 8) = b;
}
__device__ __forceinline__ void stage16(const u16* __restrict__ g, u16* l) {
  *reinterpret_cast<u16x8*>(l) = *reinterpret_cast<const u16x8*>(g);
  *reinterpret_cast<u16x8*>(l + 8) = *reinterpret_cast<const u16x8*>(g + 8);
}

// output store: bf16 (intermediates) or f32 (final d_out)
__device__ __forceinline__ void stc(u16* p, float v) { *p = f2bf(v); }
__device__ __forceinline__ void stc(float* p, float v) { *p = v; }

// ---------------- mega convert: all 5 f32 inputs -> bf16, one launch --------
__device__ __forceinline__ void cvt8(const float* in, u16* out, size_t i8) {
  const float4* gp = reinterpret_cast<const float4*>(in) + i8 * 2;
  float4 a = gp[0], b = gp[1];
  u16x8 o;
  o[0] = f2bf(a.x); o[1] = f2bf(a.y); o[2] = f2bf(a.z); o[3] = f2bf(a.w);
  o[4] = f2bf(b.x); o[5] = f2bf(b.y); o[6] = f2bf(b.z); o[7] = f2bf(b.w);
  reinterpret_cast<u16x8*>(out)[i8] = o;
}
__global__ void cvt_all(const float* x, const float* wq, const float* wk,
                        const float* wv, const float* wo,
                        u16* xb, u16* wqkvb, u16* wob) {
  const size_t NX8 = (size_t)2 * S_LEN * DM / 8;     // 2.097M
  const size_t NW8 = (size_t)DM * DM / 8;            // 2.097M
  const size_t NK8 = (size_t)NKVH * HD * DM / 8;     // 0.524M
  const size_t total = NX8 + NW8 + 2 * NK8 + NW8;
  size_t stride = (size_t)gridDim.x * blockDim.x;
  for (size_t i = (size_t)blockIdx.x * blockDim.x + threadIdx.x; i < total; i += stride) {
    if (i < NX8)                       cvt8(x,  xb,                    i);
    else if (i < NX8 + NW8)            cvt8(wq, wqkvb,                 i - NX8);
    else if (i < NX8 + NW8 + NK8)      cvt8(wk, wqkvb + NW8 * 8,       i - NX8 - NW8);
    else if (i < NX8 + NW8 + 2 * NK8)  cvt8(wv, wqkvb + (NW8 + NK8) * 8, i - NX8 - NW8 - NK8);
    else                               cvt8(wo, wob,                   i - NX8 - NW8 - 2 * NK8);
  }
}

// ---------------- RoPE table (llama3 scaling), fp64 ----------------
__global__ void rope_table_kernel(float* __restrict__ sin_t, float* __restrict__ cos_t) {
  int idx = blockIdx.x * blockDim.x + threadIdx.x;
  if (idx >= S_LEN * 64) return;
  int s = idx >> 6, i = idx & 63;
  const double PI = 3.14159265358979323846;
  double freq = pow(500000.0, -((double)i) / 64.0);
  double wavelen = 2.0 * PI / freq;
  double inv = (wavelen > 8192.0) ? freq / 32.0 : freq;
  if (!(wavelen < 2048.0) && !(wavelen > 8192.0)) {
    double smooth = (8192.0 / wavelen - 1.0) / 3.0;
    inv = (1.0 - smooth) * (freq / 32.0) + smooth * freq;
  }
  double ang = (double)s * inv;
  sin_t[idx] = (float)sin(ang);
  cos_t[idx] = (float)cos(ang);
}

// ---------------- RoPE apply: Q (scaled) and K in ONE launch ----------------
__global__ void rope_apply2(u16* __restrict__ Xq, u16* __restrict__ Xk,
                            const float* __restrict__ sin_t,
                            const float* __restrict__ cos_t,
                            float scale, int nrq, int nrk) {
  int idx = blockIdx.x * blockDim.x + threadIdx.x;
  if (idx >= (nrq + nrk) * 64) return;
  int row = idx >> 6, i = idx & 63;
  u16* X;
  float sc;
  if (row < nrq) { X = Xq; sc = scale; }
  else { X = Xk; row -= nrq; sc = 1.0f; }
  int s = row & (S_LEN - 1);
  size_t base = (size_t)row * HD;
  float lo = bf2f(X[base + i]);
  float hi = bf2f(X[base + i + 64]);
  float sn = sin_t[s * 64 + i];
  float cs = cos_t[s * 64 + i];
  X[base + i] = f2bf((lo * cs - hi * sn) * sc);
  X[base + i + 64] = f2bf((hi * cs + lo * sn) * sc);
}

// ================= GEMM (bf16, gload16 staging, BK=64 deep K-tile) ==========
// C = A(MxK) * B(NxK)^T, f32 acc.  MODE 0: C[m*N+n].
// BK=64: two m97 K-steps per barrier pair -> half the vmcnt(0)+s_barrier
// drains. LDS [128][64] (128B rows) with granule^(row&7) swizzle (attn-
// validated class): stage-source granule = (lane&7)^((lane>>3)&7), read
// granule = (4*kk+fq)^(fr&7). Bit-identical accumulation order vs BK=32.
template <int MODE, typename TC>
__global__ __launch_bounds__(256, 4)
void gemm16(const u16* __restrict__ A, const u16* __restrict__ B,
            TC* __restrict__ C, int M, int N, int K, int H) {
  __shared__ u16 sA[128 * 64];
  __shared__ u16 sB[128 * 64];
  const int tid = threadIdx.x;
  const int lane = tid & 63;
  const int wv = tid >> 6;
  const int wr = wv >> 1, wc = wv & 1;
  const int bm = blockIdx.y * 128;
  const int bn = blockIdx.x * 128;
  const int fr = lane & 15, fq = lane >> 4;
  const int srow_base = wv * 8 + (lane >> 3);               // + g*32
  const int sgran = (((lane & 7) ^ ((lane >> 3) & 7))) * 8; // source granule (elems)
  const int rxor = fr & 7;                                  // read-side row XOR

  f32x4 zero4 = {0.f, 0.f, 0.f, 0.f};
  f32x4 acc[4][4];
#pragma unroll
  for (int i = 0; i < 4; ++i)
#pragma unroll
    for (int j = 0; j < 4; ++j) acc[i][j] = zero4;

  for (int k0 = 0; k0 < K; k0 += 64) {
    __syncthreads();
#pragma unroll
    for (int g = 0; g < 4; ++g) {
      int row = g * 32 + srow_base;
      gload16(A + (size_t)(bm + row) * K + k0 + sgran, sA + g * 2048 + wv * 512);
      gload16(B + (size_t)(bn + row) * K + k0 + sgran, sB + g * 2048 + wv * 512);
    }
    __syncthreads();
#pragma unroll
    for (int kk = 0; kk < 2; ++kk) {
      bf16x8 af[4], bg[4];
      const int gofs = ((kk * 4 + fq) ^ rxor) * 8;
#pragma unroll
      for (int i = 0; i < 4; ++i) {
        af[i] = *(const bf16x8*)(sA + (wr * 64 + i * 16 + fr) * 64 + gofs);
        bg[i] = *(const bf16x8*)(sB + (wc * 64 + i * 16 + fr) * 64 + gofs);
      }
#pragma unroll
      for (int i = 0; i < 4; ++i)
#pragma unroll
        for (int j = 0; j < 4; ++j)
          acc[i][j] = __builtin_amdgcn_mfma_f32_16x16x32_bf16(af[i], bg[j], acc[i][j], 0, 0, 0);
    }
  }

#pragma unroll
  for (int i = 0; i < 4; ++i)
#pragma unroll
    for (int j = 0; j < 4; ++j)
#pragma unroll
      for (int r = 0; r < 4; ++r) {
        int m = bm + wr * 64 + i * 16 + fq * 4 + r;
        int n = bn + wc * 64 + j * 16 + fr;
        stc(C + (size_t)m * N + n, acc[i][j][r]);
      }
}

// ========== fused QKV projection GEMM: A=x[4096x4096], B=[wq;wk;wv] =========
// N=6144. BK=64 + granule^(row&7) swizzle as gemm16. Epilogue scatter by
// segment (block-uniform: boundaries %128==0): n<4096: Q [B,32,S,128];
// 4096<=n<5120: K [B,8,S,128]; else V^T [B,8,128,S].
__global__ __launch_bounds__(256, 4)
void gemm_qkv(const u16* __restrict__ A, const u16* __restrict__ B,
              u16* __restrict__ Cq, u16* __restrict__ Ck, u16* __restrict__ Cv,
              int K) {
  __shared__ u16 sA[128 * 64];
  __shared__ u16 sB[128 * 64];
  const int tid = threadIdx.x;
  const int lane = tid & 63;
  const int wv = tid >> 6;
  const int wr = wv >> 1, wc = wv & 1;
  const int bm = blockIdx.y * 128;
  const int bn = blockIdx.x * 128;
  const int fr = lane & 15, fq = lane >> 4;
  const int srow_base = wv * 8 + (lane >> 3);
  const int sgran = (((lane & 7) ^ ((lane >> 3) & 7))) * 8;
  const int rxor = fr & 7;

  f32x4 zero4 = {0.f, 0.f, 0.f, 0.f};
  f32x4 acc[4][4];
#pragma unroll
  for (int i = 0; i < 4; ++i)
#pragma unroll
    for (int j = 0; j < 4; ++j) acc[i][j] = zero4;

  for (int k0 = 0; k0 < K; k0 += 64) {
    __syncthreads();
#pragma unroll
    for (int g = 0; g < 4; ++g) {
      int row = g * 32 + srow_base;
      gload16(A + (size_t)(bm + row) * K + k0 + sgran, sA + g * 2048 + wv * 512);
      gload16(B + (size_t)(bn + row) * K + k0 + sgran, sB + g * 2048 + wv * 512);
    }
    __syncthreads();
#pragma unroll
    for (int kk = 0; kk < 2; ++kk) {
      bf16x8 af[4], bg[4];
      const int gofs = ((kk * 4 + fq) ^ rxor) * 8;
#pragma unroll
      for (int i = 0; i < 4; ++i) {
        af[i] = *(const bf16x8*)(sA + (wr * 64 + i * 16 + fr) * 64 + gofs);
        bg[i] = *(const bf16x8*)(sB + (wc * 64 + i * 16 + fr) * 64 + gofs);
      }
#pragma unroll
      for (int i = 0; i < 4; ++i)
#pragma unroll
        for (int j = 0; j < 4; ++j)
          acc[i][j] = __builtin_amdgcn_mfma_f32_16x16x32_bf16(af[i], bg[j], acc[i][j], 0, 0, 0);
    }
  }

#pragma unroll
  for (int i = 0; i < 4; ++i)
#pragma unroll
    for (int j = 0; j < 4; ++j)
#pragma unroll
      for (int r = 0; r < 4; ++r) {
        int m = bm + wr * 64 + i * 16 + fq * 4 + r;
        int n = bn + wc * 64 + j * 16 + fr;
        int b = m >> 11, s = m & 2047;
        u16 hval = f2bf(acc[i][j][r]);
        if (n < 4096) {
          int hh = n >> 7, d = n & 127;
          Cq[(((size_t)(b * NQH + hh)) * S_LEN + s) * HD + d] = hval;
        } else if (n < 5120) {
          int nn = n - 4096;
          int hh = nn >> 7, d = nn & 127;
          Ck[(((size_t)(b * NKVH + hh)) * S_LEN + s) * HD + d] = hval;
        } else {
          int nn = n - 5120;
          int hh = nn >> 7, d = nn & 127;
          Cv[(((size_t)(b * NKVH + hh)) * HD + d) * S_LEN + s] = hval;
        }
      }
}

// ================= GEMM fallback (reg-staged; round-10, templated A/B) =======
template <int MODE, typename TA, typename TB, typename TC>
__global__ __launch_bounds__(256, 2)
void gemm_bt(const TA* __restrict__ A, const TB* __restrict__ B,
             TC* __restrict__ C, int M, int N, int K, int H) {
  __shared__ u16 sA[128 * 32];
  __shared__ u16 sB[128 * 32];
  const int tid = threadIdx.x;
  const int lane = tid & 63;
  const int wv = tid >> 6;
  const int wr = wv >> 1, wc = wv & 1;
  const int bm = blockIdx.y * 128;
  const int bn = blockIdx.x * 128;
  const int fr = lane & 15, fq = lane >> 4;
  const int srow = tid >> 1;
  const int shalf = (tid & 1) * 16;

  f32x4 zero4 = {0.f, 0.f, 0.f, 0.f};
  f32x4 acc[4][4];
#pragma unroll
  for (int i = 0; i < 4; ++i)
#pragma unroll
    for (int j = 0; j < 4; ++j) acc[i][j] = zero4;

  for (int k0 = 0; k0 < K; k0 += 32) {
    __syncthreads();
    stage16(A + (size_t)(bm + srow) * K + k0 + shalf, sA + srow * 32 + shalf);
    stage16(B + (size_t)(bn + srow) * K + k0 + shalf, sB + srow * 32 + shalf);
    __syncthreads();
    bf16x8 af[4], bg[4];
#pragma unroll
    for (int i = 0; i < 4; ++i) {
      af[i] = *(const bf16x8*)(sA + (wr * 64 + i * 16 + fr) * 32 + fq * 8);
      bg[i] = *(const bf16x8*)(sB + (wc * 64 + i * 16 + fr) * 32 + fq * 8);
    }
#pragma unroll
    for (int i = 0; i < 4; ++i)
#pragma unroll
      for (int j = 0; j < 4; ++j)
        acc[i][j] = __builtin_amdgcn_mfma_f32_16x16x32_bf16(af[i], bg[j], acc[i][j], 0, 0, 0);
  }

#pragma unroll
  for (int i = 0; i < 4; ++i)
#pragma unroll
    for (int j = 0; j < 4; ++j)
#pragma unroll
      for (int r = 0; r < 4; ++r) {
        int m = bm + wr * 64 + i * 16 + fq * 4 + r;
        int n = bn + wc * 64 + j * 16 + fr;
        float v = acc[i][j][r];
        if (MODE == 0) {
          stc(C + (size_t)m * N + n, v);
        } else if (MODE == 1) {
          int b = m >> 11, s = m & 2047, hh = n >> 7, d = n & 127;
          stc(C + (((size_t)(b * H + hh)) * S_LEN + s) * HD + d, v);
        } else {
          int b = m >> 11, s = m & 2047, hh = n >> 7, d = n & 127;
          stc(C + (((size_t)(b * H + hh)) * HD + d) * S_LEN + s, v);
        }
      }
}

// ====== causal GQA flash attention (QBLK=128, LPT, defer-max, 40KB LDS) ======
// Q [B,32,S,128], K [B,8,S,128], V^T [B,8,128,S]; out [B*S,4096] bf16.
// grid (16, B*32), block 256. LPT: q0=(15-bx)*128. Wave owns 32 q-rows.
// XOR swizzle granule ^= (row&7) on K/V/P; gload16 with pre-swizzled source.
// Defer-max THR=8; l lane-local, epilogue-reduced. sP halved (8KB): one
// 16-row buffer reused across the two u-fragments -> LDS 40KB.
__global__ __launch_bounds__(256, 2)
void attn_kernel(const u16* __restrict__ Q, const u16* __restrict__ K,
                 const u16* __restrict__ V, u16* __restrict__ O) {
  __shared__ u16 sK[64 * 128];   // [kv][d], swizzled (16 KB)
  __shared__ u16 sV[128 * 64];   // [d][kv], swizzled (16 KB)
  __shared__ u16 sP[4][16 * 64]; // per-wave P (16 rows, reused per u) (8 KB)

  const int tid = threadIdx.x, lane = tid & 63, wv = tid >> 6;
  const int fr = lane & 15, fq = lane >> 4;
  const int q0 = (15 - blockIdx.x) * 128;  // LPT
  const int bh = blockIdx.y;
  const int b = bh >> 5, h = bh & 31;
  const int hkv = h >> 2;
  const u16* Qb = Q + (size_t)bh * S_LEN * HD;
  const u16* Kb = K + (size_t)(b * NKVH + hkv) * S_LEN * HD;
  const u16* Vb = V + (size_t)(b * NKVH + hkv) * HD * S_LEN;

  bf16x8 qf[2][4];
#pragma unroll
  for (int u = 0; u < 2; ++u) {
    int qrow = q0 + wv * 32 + u * 16 + fr;
#pragma unroll
    for (int ks = 0; ks < 4; ++ks)
      qf[u][ks] = *(const bf16x8*)(Qb + (size_t)qrow * HD + ks * 32 + fq * 8);
  }

  f32x4 zero4 = {0.f, 0.f, 0.f, 0.f};
  f32x4 o[2][8];
  float m[2][4], l[2][4];
#pragma unroll
  for (int u = 0; u < 2; ++u) {
#pragma unroll
    for (int dt = 0; dt < 8; ++dt) o[u][dt] = zero4;
#pragma unroll
    for (int r = 0; r < 4; ++r) { m[u][r] = -3.0e38f; l[u][r] = 0.f; }
  }

  const int ntiles = (q0 >> 6) + 2;
  for (int t = 0; t < ntiles; ++t) {
    const int s0 = t * 64;
    __syncthreads();
#pragma unroll
    for (int j = 0; j < 4; ++j) {
      int c = j * 4 + wv;
      {
        int row = c * 4 + (lane >> 4);
        int e = ((lane & 15) ^ (row & 7)) * 8;
        gload16(Kb + (size_t)(s0 + row) * HD + e, sK + c * 512);
      }
      {
        int row = c * 8 + (lane >> 3);
        int e = ((lane & 7) ^ (row & 7)) * 8;
        gload16(Vb + (size_t)row * S_LEN + s0 + e, sV + c * 512);
      }
    }
    __syncthreads();

    f32x4 sc[2][4];
#pragma unroll
    for (int u = 0; u < 2; ++u)
#pragma unroll
      for (int j = 0; j < 4; ++j) sc[u][j] = zero4;
#pragma unroll
    for (int j = 0; j < 4; ++j) {
#pragma unroll
      for (int ks = 0; ks < 4; ++ks) {
        int row = j * 16 + fr;
        int e = (ks * 32 + fq * 8) ^ ((row & 7) << 3);
        bf16x8 kf = *(const bf16x8*)(sK + row * 128 + e);
#pragma unroll
        for (int u = 0; u < 2; ++u)
          sc[u][j] = __builtin_amdgcn_mfma_f32_16x16x32_bf16(qf[u][ks], kf, sc[u][j], 0, 0, 0);
      }
    }

    if (t >= ntiles - 2) {
#pragma unroll
      for (int u = 0; u < 2; ++u)
#pragma unroll
        for (int j = 0; j < 4; ++j)
#pragma unroll
          for (int r = 0; r < 4; ++r) {
            int kvp = s0 + j * 16 + fr;
            int qp = q0 + wv * 32 + u * 16 + fq * 4 + r;
            if (kvp > qp) sc[u][j][r] = -3.0e38f;
          }
    }

    // softmax + P-repack per u-fragment (sP reused across u)
    bf16x8 pa[2][2];
#pragma unroll
    for (int u = 0; u < 2; ++u) {
      float al[4];
      bool resc = false;
#pragma unroll
      for (int r = 0; r < 4; ++r) {
        float v = fmaxf(fmaxf(sc[u][0][r], sc[u][1][r]), fmaxf(sc[u][2][r], sc[u][3][r]));
        v = fmaxf(v, __shfl_xor(v, 1, 64));
        v = fmaxf(v, __shfl_xor(v, 2, 64));
        v = fmaxf(v, __shfl_xor(v, 4, 64));
        v = fmaxf(v, __shfl_xor(v, 8, 64));
        if (v > m[u][r] + 8.f) {
          al[r] = __expf(m[u][r] - v);
          m[u][r] = v;
          resc = true;
        } else {
          al[r] = 1.f;
        }
      }
#pragma unroll
      for (int r = 0; r < 4; ++r) {
        float rs = 0.f;
        int prow = fq * 4 + r;
#pragma unroll
        for (int j = 0; j < 4; ++j) {
          float pv = __expf(sc[u][j][r] - m[u][r]);
          rs += pv;
          int e = (j * 16 + fr) ^ ((prow & 7) << 3);
          sP[wv][prow * 64 + e] = f2bf(pv);
        }
        l[u][r] = l[u][r] * al[r] + rs;
      }
      if (resc) {
#pragma unroll
        for (int r = 0; r < 4; ++r)
#pragma unroll
          for (int dt = 0; dt < 8; ++dt) o[u][dt][r] *= al[r];
      }
#pragma unroll
      for (int ks = 0; ks < 2; ++ks) {
        int e = (ks * 32 + fq * 8) ^ ((fr & 7) << 3);
        pa[u][ks] = *(const bf16x8*)(&sP[wv][fr * 64 + e]);
      }
    }

    // PV: o[u][dt] rows q, cols d=dt*16+fr; each vf feeds both u-fragments
#pragma unroll
    for (int dt = 0; dt < 8; ++dt) {
#pragma unroll
      for (int ks = 0; ks < 2; ++ks) {
        int row = dt * 16 + fr;
        int e = (ks * 32 + fq * 8) ^ ((row & 7) << 3);
        bf16x8 vf = *(const bf16x8*)(sV + row * 64 + e);
#pragma unroll
        for (int u = 0; u < 2; ++u)
          o[u][dt] = __builtin_amdgcn_mfma_f32_16x16x32_bf16(pa[u][ks], vf, o[u][dt], 0, 0, 0);
      }
    }
  }

#pragma unroll
  for (int u = 0; u < 2; ++u)
#pragma unroll
    for (int r = 0; r < 4; ++r) {
      float lt = l[u][r];
      lt += __shfl_xor(lt, 1, 64);
      lt += __shfl_xor(lt, 2, 64);
      lt += __shfl_xor(lt, 4, 64);
      lt += __shfl_xor(lt, 8, 64);
      int qp = q0 + wv * 32 + u * 16 + fq * 4 + r;
      float inv_l = 1.0f / lt;
      size_t base = ((size_t)b * S_LEN + qp) * DM + h * HD;
#pragma unroll
      for (int dt = 0; dt < 8; ++dt)
        O[base + dt * 16 + fr] = f2bf(o[u][dt][r] * inv_l);
    }
}

// ---------------- RoPE apply (fallback path, single-buffer) ----------------
__global__ void rope_apply(u16* __restrict__ X, const float* __restrict__ sin_t,
                           const float* __restrict__ cos_t, float scale, int nrows) {
  int idx = blockIdx.x * blockDim.x + threadIdx.x;
  if (idx >= nrows * 64) return;
  int row = idx >> 6, i = idx & 63;
  int s = row & (S_LEN - 1);
  size_t base = (size_t)row * HD;
  float lo = bf2f(X[base + i]);
  float hi = bf2f(X[base + i + 64]);
  float sn = sin_t[s * 64 + i];
  float cs = cos_t[s * 64 + i];
  X[base + i] = f2bf((lo * cs - hi * sn) * scale);
  X[base + i + 64] = f2bf((hi * cs + lo * sn) * scale);
}

extern "C" void kernel_launch(void* const* d_in, const int* in_sizes, int n_in,
                              void* d_out, int out_size, void* d_ws, size_t ws_size,
                              hipStream_t stream) {
  const float* x  = (const float*)d_in[0];
  const float* wq = (const float*)d_in[1];
  const float* wk = (const float*)d_in[2];
  const float* wv = (const float*)d_in[3];
  const float* wo = (const float*)d_in[4];

  char* ws = (char*)d_ws;
  size_t off = 0;
  auto alloc = [&](size_t bytes) {
    void* p = ws + off;
    off += (bytes + 255) & ~(size_t)255;
    return p;
  };

  const size_t nx  = (size_t)2 * S_LEN * DM;       // 16.78M elements
  const size_t nwq = (size_t)DM * DM;              // 16.78M
  const size_t nwk = (size_t)(NKVH * HD) * DM;     // 4.19M

  const float scale = 0.08838834764831845f;  // 1/sqrt(128), folded into Q
  const int nrq = 2 * NQH * S_LEN, nrk = 2 * NKVH * S_LEN;
  dim3 blk(256);

  if (ws_size >= ((size_t)180 << 20)) {
    // -------- fast path: mega-cvt + fused QKV GEMM + fused rope --------
    u16* xb    = (u16*)alloc(nx * 2);                 // aob aliases after use
    u16* wqkvb = (u16*)alloc((nwq + 2 * nwk) * 2);    // [wq;wk;wv] 6144x4096
    u16* wob   = (u16*)alloc(nwq * 2);
    u16* qb    = (u16*)alloc(nx * 2);
    u16* kb    = (u16*)alloc(nwk * 2);
    u16* vtb   = (u16*)alloc(nwk * 2);
    float* sin_t = (float*)alloc((size_t)S_LEN * 64 * 4);
    float* cos_t = (float*)alloc((size_t)S_LEN * 64 * 4);
    u16* aob = xb;  // alias: x (bf16) dead after QKV projection

    cvt_all<<<2048, 256, 0, stream>>>(x, wq, wk, wv, wo, xb, wqkvb, wob);
    rope_table_kernel<<<(S_LEN * 64 + 255) / 256, 256, 0, stream>>>(sin_t, cos_t);

    gemm_qkv<<<dim3(48, 32), blk, 0, stream>>>(xb, wqkvb, qb, kb, vtb, DM);

    rope_apply2<<<(((size_t)(nrq + nrk)) * 64 + 255) / 256, 256, 0, stream>>>(
        qb, kb, sin_t, cos_t, scale, nrq, nrk);

    attn_kernel<<<dim3(16, 64), blk, 0, stream>>>(qb, kb, vtb, aob);

    gemm16<0, float><<<dim3(32, 32), blk, 0, stream>>>(aob, wob, (float*)d_out, 4096, DM, DM, 0);
  } else {
    // -------- fallback: proven round-10 path (f32 reg-staged GEMMs) --------
    u16* qb  = (u16*)alloc(nx * 2);
    u16* kb  = (u16*)alloc(nwk * 2);
    u16* vtb = (u16*)alloc(nwk * 2);
    u16* aob = (u16*)alloc(nx * 2);
    float* sin_t = (float*)alloc((size_t)S_LEN * 64 * 4);
    float* cos_t = (float*)alloc((size_t)S_LEN * 64 * 4);

    rope_table_kernel<<<(S_LEN * 64 + 255) / 256, 256, 0, stream>>>(sin_t, cos_t);

    gemm_bt<1, float, float, u16><<<dim3(32, 32), blk, 0, stream>>>(x, wq, qb, 4096, DM, DM, NQH);
    gemm_bt<1, float, float, u16><<<dim3(8, 32), blk, 0, stream>>>(x, wk, kb, 4096, 1024, DM, NKVH);
    gemm_bt<2, float, float, u16><<<dim3(8, 32), blk, 0, stream>>>(x, wv, vtb, 4096, 1024, DM, NKVH);

    rope_apply<<<((size_t)nrq * 64 + 255) / 256, 256, 0, stream>>>(qb, sin_t, cos_t, scale, nrq);
    rope_apply<<<((size_t)nrk * 64 + 255) / 256, 256, 0, stream>>>(kb, sin_t, cos_t, 1.0f, nrk);

    attn_kernel<<<dim3(16, 64), blk, 0, stream>>>(qb, kb, vtb, aob);

    gemm_bt<0, u16, float, float><<<dim3(32, 32), blk, 0, stream>>>(aob, wo, (float*)d_out, 4096, DM, DM, 0);
  }
}

// Round 25
// 662.415 us; speedup vs baseline: 1.1100x; 1.0200x over previous
//
#include <hip/hip_runtime.h>
#include <cstdint>

#define S_LEN 2048
#define DM 4096
#define NQH 32
#define NKVH 8
#define HD 128

typedef __bf16 bf16x8 __attribute__((ext_vector_type(8)));
typedef float f32x4 __attribute__((ext_vector_type(4)));
typedef unsigned short u16;
typedef unsigned short u16x8 __attribute__((ext_vector_type(8)));
typedef unsigned int u32;

__device__ __forceinline__ float bf2f(u16 h) {
  union { u32 u; float f; } v; v.u = ((u32)h) << 16; return v.f;
}
__device__ __forceinline__ u16 f2bf(float f) {
  union { float f; u32 u; } v; v.f = f;
  u32 u = v.u;
  return (u16)((u + 0x7FFFu + ((u >> 16) & 1u)) >> 16);
}

// global -> LDS direct DMA, 16B/lane. LDS dest = wave-uniform base + lane*16;
// global source is per-lane (bit-validated vs reg-staged path).
__device__ __forceinline__ void gload16(const void* g, const void* l) {
  __builtin_amdgcn_global_load_lds(
      (const __attribute__((address_space(1))) u32*)(uintptr_t)g,
      (__attribute__((address_space(3))) u32*)(u32)(uintptr_t)l,
      16, 0, 0);
}

// ---- reg-staging helpers (fallback path): 16 elements global -> LDS
__device__ __forceinline__ void stage16(const float* __restrict__ g, u16* l) {
  const float4* gp = reinterpret_cast<const float4*>(g);
  float4 v0 = gp[0], v1 = gp[1], v2 = gp[2], v3 = gp[3];
  u16x8 a, b;
  a[0] = f2bf(v0.x); a[1] = f2bf(v0.y); a[2] = f2bf(v0.z); a[3] = f2bf(v0.w);
  a[4] = f2bf(v1.x); a[5] = f2bf(v1.y); a[6] = f2bf(v1.z); a[7] = f2bf(v1.w);
  b[0] = f2bf(v2.x); b[1] = f2bf(v2.y); b[2] = f2bf(v2.z); b[3] = f2bf(v2.w);
  b[4] = f2bf(v3.x); b[5] = f2bf(v3.y); b[6] = f2bf(v3.z); b[7] = f2bf(v3.w);
  *reinterpret_cast<u16x8*>(l) = a;
  *reinterpret_cast<u16x8*>(l + 8) = b;
}
__device__ __forceinline__ void stage16(const u16* __restrict__ g, u16* l) {
  *reinterpret_cast<u16x8*>(l) = *reinterpret_cast<const u16x8*>(g);
  *reinterpret_cast<u16x8*>(l + 8) = *reinterpret_cast<const u16x8*>(g + 8);
}

// output store: bf16 (intermediates) or f32 (final d_out)
__device__ __forceinline__ void stc(u16* p, float v) { *p = f2bf(v); }
__device__ __forceinline__ void stc(float* p, float v) { *p = v; }

// ---------------- mega convert: all 5 f32 inputs -> bf16, one launch --------
__device__ __forceinline__ void cvt8(const float* in, u16* out, size_t i8) {
  const float4* gp = reinterpret_cast<const float4*>(in) + i8 * 2;
  float4 a = gp[0], b = gp[1];
  u16x8 o;
  o[0] = f2bf(a.x); o[1] = f2bf(a.y); o[2] = f2bf(a.z); o[3] = f2bf(a.w);
  o[4] = f2bf(b.x); o[5] = f2bf(b.y); o[6] = f2bf(b.z); o[7] = f2bf(b.w);
  reinterpret_cast<u16x8*>(out)[i8] = o;
}
__global__ void cvt_all(const float* x, const float* wq, const float* wk,
                        const float* wv, const float* wo,
                        u16* xb, u16* wqkvb, u16* wob) {
  const size_t NX8 = (size_t)2 * S_LEN * DM / 8;     // 2.097M
  const size_t NW8 = (size_t)DM * DM / 8;            // 2.097M
  const size_t NK8 = (size_t)NKVH * HD * DM / 8;     // 0.524M
  const size_t total = NX8 + NW8 + 2 * NK8 + NW8;
  size_t stride = (size_t)gridDim.x * blockDim.x;
  for (size_t i = (size_t)blockIdx.x * blockDim.x + threadIdx.x; i < total; i += stride) {
    if (i < NX8)                       cvt8(x,  xb,                    i);
    else if (i < NX8 + NW8)            cvt8(wq, wqkvb,                 i - NX8);
    else if (i < NX8 + NW8 + NK8)      cvt8(wk, wqkvb + NW8 * 8,       i - NX8 - NW8);
    else if (i < NX8 + NW8 + 2 * NK8)  cvt8(wv, wqkvb + (NW8 + NK8) * 8, i - NX8 - NW8 - NK8);
    else                               cvt8(wo, wob,                   i - NX8 - NW8 - 2 * NK8);
  }
}

// ---------------- RoPE table (llama3 scaling), fp64 ----------------
__global__ void rope_table_kernel(float* __restrict__ sin_t, float* __restrict__ cos_t) {
  int idx = blockIdx.x * blockDim.x + threadIdx.x;
  if (idx >= S_LEN * 64) return;
  int s = idx >> 6, i = idx & 63;
  const double PI = 3.14159265358979323846;
  double freq = pow(500000.0, -((double)i) / 64.0);
  double wavelen = 2.0 * PI / freq;
  double inv = (wavelen > 8192.0) ? freq / 32.0 : freq;
  if (!(wavelen < 2048.0) && !(wavelen > 8192.0)) {
    double smooth = (8192.0 / wavelen - 1.0) / 3.0;
    inv = (1.0 - smooth) * (freq / 32.0) + smooth * freq;
  }
  double ang = (double)s * inv;
  sin_t[idx] = (float)sin(ang);
  cos_t[idx] = (float)cos(ang);
}

// ---------------- RoPE apply in place on [B,H,S,128] bf16 (K path) ----------
__global__ void rope_apply(u16* __restrict__ X, const float* __restrict__ sin_t,
                           const float* __restrict__ cos_t, float scale, int nrows) {
  int idx = blockIdx.x * blockDim.x + threadIdx.x;
  if (idx >= nrows * 64) return;
  int row = idx >> 6, i = idx & 63;
  int s = row & (S_LEN - 1);
  size_t base = (size_t)row * HD;
  float lo = bf2f(X[base + i]);
  float hi = bf2f(X[base + i + 64]);
  float sn = sin_t[s * 64 + i];
  float cs = cos_t[s * 64 + i];
  X[base + i] = f2bf((lo * cs - hi * sn) * scale);
  X[base + i + 64] = f2bf((hi * cs + lo * sn) * scale);
}

// ================= GEMM (bf16, gload16 staging, BK=64 deep K-tile) ==========
// C = A(MxK) * B(NxK)^T, f32 acc.  MODE 0: C[m*N+n].
// BK=64: two m97 K-steps per barrier pair -> half the vmcnt(0)+s_barrier
// drains. LDS [128][64] with granule^(row&7) swizzle (round-24: 41.7% MfmaUtil).
template <int MODE, typename TC>
__global__ __launch_bounds__(256, 4)
void gemm16(const u16* __restrict__ A, const u16* __restrict__ B,
            TC* __restrict__ C, int M, int N, int K, int H) {
  __shared__ u16 sA[128 * 64];
  __shared__ u16 sB[128 * 64];
  const int tid = threadIdx.x;
  const int lane = tid & 63;
  const int wv = tid >> 6;
  const int wr = wv >> 1, wc = wv & 1;
  const int bm = blockIdx.y * 128;
  const int bn = blockIdx.x * 128;
  const int fr = lane & 15, fq = lane >> 4;
  const int srow_base = wv * 8 + (lane >> 3);
  const int sgran = (((lane & 7) ^ ((lane >> 3) & 7))) * 8;
  const int rxor = fr & 7;

  f32x4 zero4 = {0.f, 0.f, 0.f, 0.f};
  f32x4 acc[4][4];
#pragma unroll
  for (int i = 0; i < 4; ++i)
#pragma unroll
    for (int j = 0; j < 4; ++j) acc[i][j] = zero4;

  for (int k0 = 0; k0 < K; k0 += 64) {
    __syncthreads();
#pragma unroll
    for (int g = 0; g < 4; ++g) {
      int row = g * 32 + srow_base;
      gload16(A + (size_t)(bm + row) * K + k0 + sgran, sA + g * 2048 + wv * 512);
      gload16(B + (size_t)(bn + row) * K + k0 + sgran, sB + g * 2048 + wv * 512);
    }
    __syncthreads();
#pragma unroll
    for (int kk = 0; kk < 2; ++kk) {
      bf16x8 af[4], bg[4];
      const int gofs = ((kk * 4 + fq) ^ rxor) * 8;
#pragma unroll
      for (int i = 0; i < 4; ++i) {
        af[i] = *(const bf16x8*)(sA + (wr * 64 + i * 16 + fr) * 64 + gofs);
        bg[i] = *(const bf16x8*)(sB + (wc * 64 + i * 16 + fr) * 64 + gofs);
      }
#pragma unroll
      for (int i = 0; i < 4; ++i)
#pragma unroll
        for (int j = 0; j < 4; ++j)
          acc[i][j] = __builtin_amdgcn_mfma_f32_16x16x32_bf16(af[i], bg[j], acc[i][j], 0, 0, 0);
    }
  }

#pragma unroll
  for (int i = 0; i < 4; ++i)
#pragma unroll
    for (int j = 0; j < 4; ++j)
#pragma unroll
      for (int r = 0; r < 4; ++r) {
        int m = bm + wr * 64 + i * 16 + fq * 4 + r;
        int n = bn + wc * 64 + j * 16 + fr;
        stc(C + (size_t)m * N + n, acc[i][j][r]);
      }
}

// ========== fused QKV projection GEMM: A=x[4096x4096], B=[wq;wk;wv] =========
// N=6144. BK=64 + granule^(row&7) swizzle. Epilogue scatter by segment:
// n<4096: Q [B,32,S,128]; 4096<=n<5120: K [B,8,S,128]; else V^T [B,8,128,S].
__global__ __launch_bounds__(256, 4)
void gemm_qkv(const u16* __restrict__ A, const u16* __restrict__ B,
              u16* __restrict__ Cq, u16* __restrict__ Ck, u16* __restrict__ Cv,
              int K) {
  __shared__ u16 sA[128 * 64];
  __shared__ u16 sB[128 * 64];
  const int tid = threadIdx.x;
  const int lane = tid & 63;
  const int wv = tid >> 6;
  const int wr = wv >> 1, wc = wv & 1;
  const int bm = blockIdx.y * 128;
  const int bn = blockIdx.x * 128;
  const int fr = lane & 15, fq = lane >> 4;
  const int srow_base = wv * 8 + (lane >> 3);
  const int sgran = (((lane & 7) ^ ((lane >> 3) & 7))) * 8;
  const int rxor = fr & 7;

  f32x4 zero4 = {0.f, 0.f, 0.f, 0.f};
  f32x4 acc[4][4];
#pragma unroll
  for (int i = 0; i < 4; ++i)
#pragma unroll
    for (int j = 0; j < 4; ++j) acc[i][j] = zero4;

  for (int k0 = 0; k0 < K; k0 += 64) {
    __syncthreads();
#pragma unroll
    for (int g = 0; g < 4; ++g) {
      int row = g * 32 + srow_base;
      gload16(A + (size_t)(bm + row) * K + k0 + sgran, sA + g * 2048 + wv * 512);
      gload16(B + (size_t)(bn + row) * K + k0 + sgran, sB + g * 2048 + wv * 512);
    }
    __syncthreads();
#pragma unroll
    for (int kk = 0; kk < 2; ++kk) {
      bf16x8 af[4], bg[4];
      const int gofs = ((kk * 4 + fq) ^ rxor) * 8;
#pragma unroll
      for (int i = 0; i < 4; ++i) {
        af[i] = *(const bf16x8*)(sA + (wr * 64 + i * 16 + fr) * 64 + gofs);
        bg[i] = *(const bf16x8*)(sB + (wc * 64 + i * 16 + fr) * 64 + gofs);
      }
#pragma unroll
      for (int i = 0; i < 4; ++i)
#pragma unroll
        for (int j = 0; j < 4; ++j)
          acc[i][j] = __builtin_amdgcn_mfma_f32_16x16x32_bf16(af[i], bg[j], acc[i][j], 0, 0, 0);
    }
  }

#pragma unroll
  for (int i = 0; i < 4; ++i)
#pragma unroll
    for (int j = 0; j < 4; ++j)
#pragma unroll
      for (int r = 0; r < 4; ++r) {
        int m = bm + wr * 64 + i * 16 + fq * 4 + r;
        int n = bn + wc * 64 + j * 16 + fr;
        int b = m >> 11, s = m & 2047;
        u16 hval = f2bf(acc[i][j][r]);
        if (n < 4096) {
          int hh = n >> 7, d = n & 127;
          Cq[(((size_t)(b * NQH + hh)) * S_LEN + s) * HD + d] = hval;
        } else if (n < 5120) {
          int nn = n - 4096;
          int hh = nn >> 7, d = nn & 127;
          Ck[(((size_t)(b * NKVH + hh)) * S_LEN + s) * HD + d] = hval;
        } else {
          int nn = n - 5120;
          int hh = nn >> 7, d = nn & 127;
          Cv[(((size_t)(b * NKVH + hh)) * HD + d) * S_LEN + s] = hval;
        }
      }
}

// ================= GEMM fallback (reg-staged; round-10, templated A/B) =======
template <int MODE, typename TA, typename TB, typename TC>
__global__ __launch_bounds__(256, 2)
void gemm_bt(const TA* __restrict__ A, const TB* __restrict__ B,
             TC* __restrict__ C, int M, int N, int K, int H) {
  __shared__ u16 sA[128 * 32];
  __shared__ u16 sB[128 * 32];
  const int tid = threadIdx.x;
  const int lane = tid & 63;
  const int wv = tid >> 6;
  const int wr = wv >> 1, wc = wv & 1;
  const int bm = blockIdx.y * 128;
  const int bn = blockIdx.x * 128;
  const int fr = lane & 15, fq = lane >> 4;
  const int srow = tid >> 1;
  const int shalf = (tid & 1) * 16;

  f32x4 zero4 = {0.f, 0.f, 0.f, 0.f};
  f32x4 acc[4][4];
#pragma unroll
  for (int i = 0; i < 4; ++i)
#pragma unroll
    for (int j = 0; j < 4; ++j) acc[i][j] = zero4;

  for (int k0 = 0; k0 < K; k0 += 32) {
    __syncthreads();
    stage16(A + (size_t)(bm + srow) * K + k0 + shalf, sA + srow * 32 + shalf);
    stage16(B + (size_t)(bn + srow) * K + k0 + shalf, sB + srow * 32 + shalf);
    __syncthreads();
    bf16x8 af[4], bg[4];
#pragma unroll
    for (int i = 0; i < 4; ++i) {
      af[i] = *(const bf16x8*)(sA + (wr * 64 + i * 16 + fr) * 32 + fq * 8);
      bg[i] = *(const bf16x8*)(sB + (wc * 64 + i * 16 + fr) * 32 + fq * 8);
    }
#pragma unroll
    for (int i = 0; i < 4; ++i)
#pragma unroll
      for (int j = 0; j < 4; ++j)
        acc[i][j] = __builtin_amdgcn_mfma_f32_16x16x32_bf16(af[i], bg[j], acc[i][j], 0, 0, 0);
  }

#pragma unroll
  for (int i = 0; i < 4; ++i)
#pragma unroll
    for (int j = 0; j < 4; ++j)
#pragma unroll
      for (int r = 0; r < 4; ++r) {
        int m = bm + wr * 64 + i * 16 + fq * 4 + r;
        int n = bn + wc * 64 + j * 16 + fr;
        float v = acc[i][j][r];
        if (MODE == 0) {
          stc(C + (size_t)m * N + n, v);
        } else if (MODE == 1) {
          int b = m >> 11, s = m & 2047, hh = n >> 7, d = n & 127;
          stc(C + (((size_t)(b * H + hh)) * S_LEN + s) * HD + d, v);
        } else {
          int b = m >> 11, s = m & 2047, hh = n >> 7, d = n & 127;
          stc(C + (((size_t)(b * H + hh)) * HD + d) * S_LEN + s, v);
        }
      }
}

// ====== causal GQA flash attention (QBLK=128, LPT, defer-max, fused Q-RoPE) ==
// Q_raw [B,32,S,128] (pre-rope), K [B,8,S,128] (rope'd), V^T [B,8,128,S].
// grid (16, B*32), block 256. LPT: q0=(15-bx)*128. Wave owns 32 q-rows.
// Q-RoPE applied in-register at fragment load (pairs (d,d+64) = (ks,ks+2)
// at same fq/j; same bf16->f32->RNE-bf16 path as the old rope_apply).
// XOR swizzle granule ^= (row&7) on K/V/P; gload16 pre-swizzled source.
// Defer-max THR=8; l lane-local, epilogue-reduced; sP reused across u (40KB).
// T5 setprio(1) around MFMA clusters (m191: +4-7% on multi-block attn).
__global__ __launch_bounds__(256, 2)
void attn_kernel(const u16* __restrict__ Q, const u16* __restrict__ K,
                 const u16* __restrict__ V, u16* __restrict__ O,
                 const float* __restrict__ sin_t, const float* __restrict__ cos_t,
                 float scale) {
  __shared__ u16 sK[64 * 128];   // [kv][d], swizzled (16 KB)
  __shared__ u16 sV[128 * 64];   // [d][kv], swizzled (16 KB)
  __shared__ u16 sP[4][16 * 64]; // per-wave P (16 rows, reused per u) (8 KB)

  const int tid = threadIdx.x, lane = tid & 63, wv = tid >> 6;
  const int fr = lane & 15, fq = lane >> 4;
  const int q0 = (15 - blockIdx.x) * 128;  // LPT
  const int bh = blockIdx.y;
  const int b = bh >> 5, h = bh & 31;
  const int hkv = h >> 2;
  const u16* Qb = Q + (size_t)bh * S_LEN * HD;
  const u16* Kb = K + (size_t)(b * NKVH + hkv) * S_LEN * HD;
  const u16* Vb = V + (size_t)(b * NKVH + hkv) * HD * S_LEN;

  // Q fragments with fused RoPE + scale
  u16x8 qfu[2][4];
#pragma unroll
  for (int u = 0; u < 2; ++u) {
    int qrow = q0 + wv * 32 + u * 16 + fr;   // == s (0..2047)
    const u16* qp = Qb + (size_t)qrow * HD;
    u16x8 raw[4];
#pragma unroll
    for (int ks = 0; ks < 4; ++ks)
      raw[ks] = *(const u16x8*)(qp + ks * 32 + fq * 8);
#pragma unroll
    for (int p = 0; p < 2; ++p) {
      const float* cb = cos_t + (size_t)qrow * 64 + p * 32 + fq * 8;
      const float* sb = sin_t + (size_t)qrow * 64 + p * 32 + fq * 8;
      float4 c0 = ((const float4*)cb)[0], c1 = ((const float4*)cb)[1];
      float4 s0 = ((const float4*)sb)[0], s1 = ((const float4*)sb)[1];
      float cs[8] = {c0.x, c0.y, c0.z, c0.w, c1.x, c1.y, c1.z, c1.w};
      float sn[8] = {s0.x, s0.y, s0.z, s0.w, s1.x, s1.y, s1.z, s1.w};
#pragma unroll
      for (int j = 0; j < 8; ++j) {
        float lo = bf2f(raw[p][j]);
        float hi = bf2f(raw[p + 2][j]);
        qfu[u][p][j]     = f2bf((lo * cs[j] - hi * sn[j]) * scale);
        qfu[u][p + 2][j] = f2bf((hi * cs[j] + lo * sn[j]) * scale);
      }
    }
  }
  const bf16x8* qf0 = (const bf16x8*)&qfu[0][0];
  const bf16x8* qf1 = (const bf16x8*)&qfu[1][0];

  f32x4 zero4 = {0.f, 0.f, 0.f, 0.f};
  f32x4 o[2][8];
  float m[2][4], l[2][4];
#pragma unroll
  for (int u = 0; u < 2; ++u) {
#pragma unroll
    for (int dt = 0; dt < 8; ++dt) o[u][dt] = zero4;
#pragma unroll
    for (int r = 0; r < 4; ++r) { m[u][r] = -3.0e38f; l[u][r] = 0.f; }
  }

  const int ntiles = (q0 >> 6) + 2;
  for (int t = 0; t < ntiles; ++t) {
    const int s0 = t * 64;
    __syncthreads();
#pragma unroll
    for (int j = 0; j < 4; ++j) {
      int c = j * 4 + wv;
      {
        int row = c * 4 + (lane >> 4);
        int e = ((lane & 15) ^ (row & 7)) * 8;
        gload16(Kb + (size_t)(s0 + row) * HD + e, sK + c * 512);
      }
      {
        int row = c * 8 + (lane >> 3);
        int e = ((lane & 7) ^ (row & 7)) * 8;
        gload16(Vb + (size_t)row * S_LEN + s0 + e, sV + c * 512);
      }
    }
    __syncthreads();

    f32x4 sc[2][4];
#pragma unroll
    for (int u = 0; u < 2; ++u)
#pragma unroll
      for (int j = 0; j < 4; ++j) sc[u][j] = zero4;
    __builtin_amdgcn_s_setprio(1);
#pragma unroll
    for (int j = 0; j < 4; ++j) {
#pragma unroll
      for (int ks = 0; ks < 4; ++ks) {
        int row = j * 16 + fr;
        int e = (ks * 32 + fq * 8) ^ ((row & 7) << 3);
        bf16x8 kf = *(const bf16x8*)(sK + row * 128 + e);
        sc[0][j] = __builtin_amdgcn_mfma_f32_16x16x32_bf16(qf0[ks], kf, sc[0][j], 0, 0, 0);
        sc[1][j] = __builtin_amdgcn_mfma_f32_16x16x32_bf16(qf1[ks], kf, sc[1][j], 0, 0, 0);
      }
    }
    __builtin_amdgcn_s_setprio(0);

    if (t >= ntiles - 2) {
#pragma unroll
      for (int u = 0; u < 2; ++u)
#pragma unroll
        for (int j = 0; j < 4; ++j)
#pragma unroll
          for (int r = 0; r < 4; ++r) {
            int kvp = s0 + j * 16 + fr;
            int qp = q0 + wv * 32 + u * 16 + fq * 4 + r;
            if (kvp > qp) sc[u][j][r] = -3.0e38f;
          }
    }

    // softmax + P-repack per u-fragment (sP reused across u)
    bf16x8 pa[2][2];
#pragma unroll
    for (int u = 0; u < 2; ++u) {
      float al[4];
      bool resc = false;
#pragma unroll
      for (int r = 0; r < 4; ++r) {
        float v = fmaxf(fmaxf(sc[u][0][r], sc[u][1][r]), fmaxf(sc[u][2][r], sc[u][3][r]));
        v = fmaxf(v, __shfl_xor(v, 1, 64));
        v = fmaxf(v, __shfl_xor(v, 2, 64));
        v = fmaxf(v, __shfl_xor(v, 4, 64));
        v = fmaxf(v, __shfl_xor(v, 8, 64));
        if (v > m[u][r] + 8.f) {
          al[r] = __expf(m[u][r] - v);
          m[u][r] = v;
          resc = true;
        } else {
          al[r] = 1.f;
        }
      }
#pragma unroll
      for (int r = 0; r < 4; ++r) {
        float rs = 0.f;
        int prow = fq * 4 + r;
#pragma unroll
        for (int j = 0; j < 4; ++j) {
          float pv = __expf(sc[u][j][r] - m[u][r]);
          rs += pv;
          int e = (j * 16 + fr) ^ ((prow & 7) << 3);
          sP[wv][prow * 64 + e] = f2bf(pv);
        }
        l[u][r] = l[u][r] * al[r] + rs;
      }
      if (resc) {
#pragma unroll
        for (int r = 0; r < 4; ++r)
#pragma unroll
          for (int dt = 0; dt < 8; ++dt) o[u][dt][r] *= al[r];
      }
#pragma unroll
      for (int ks = 0; ks < 2; ++ks) {
        int e = (ks * 32 + fq * 8) ^ ((fr & 7) << 3);
        pa[u][ks] = *(const bf16x8*)(&sP[wv][fr * 64 + e]);
      }
    }

    // PV: o[u][dt] rows q, cols d=dt*16+fr; each vf feeds both u-fragments
    __builtin_amdgcn_s_setprio(1);
#pragma unroll
    for (int dt = 0; dt < 8; ++dt) {
#pragma unroll
      for (int ks = 0; ks < 2; ++ks) {
        int row = dt * 16 + fr;
        int e = (ks * 32 + fq * 8) ^ ((row & 7) << 3);
        bf16x8 vf = *(const bf16x8*)(sV + row * 64 + e);
#pragma unroll
        for (int u = 0; u < 2; ++u)
          o[u][dt] = __builtin_amdgcn_mfma_f32_16x16x32_bf16(pa[u][ks], vf, o[u][dt], 0, 0, 0);
      }
    }
    __builtin_amdgcn_s_setprio(0);
  }

#pragma unroll
  for (int u = 0; u < 2; ++u)
#pragma unroll
    for (int r = 0; r < 4; ++r) {
      float lt = l[u][r];
      lt += __shfl_xor(lt, 1, 64);
      lt += __shfl_xor(lt, 2, 64);
      lt += __shfl_xor(lt, 4, 64);
      lt += __shfl_xor(lt, 8, 64);
      int qp = q0 + wv * 32 + u * 16 + fq * 4 + r;
      float inv_l = 1.0f / lt;
      size_t base = ((size_t)b * S_LEN + qp) * DM + h * HD;
#pragma unroll
      for (int dt = 0; dt < 8; ++dt)
        O[base + dt * 16 + fr] = f2bf(o[u][dt][r] * inv_l);
    }
}

extern "C" void kernel_launch(void* const* d_in, const int* in_sizes, int n_in,
                              void* d_out, int out_size, void* d_ws, size_t ws_size,
                              hipStream_t stream) {
  const float* x  = (const float*)d_in[0];
  const float* wq = (const float*)d_in[1];
  const float* wk = (const float*)d_in[2];
  const float* wv = (const float*)d_in[3];
  const float* wo = (const float*)d_in[4];

  char* ws = (char*)d_ws;
  size_t off = 0;
  auto alloc = [&](size_t bytes) {
    void* p = ws + off;
    off += (bytes + 255) & ~(size_t)255;
    return p;
  };

  const size_t nx  = (size_t)2 * S_LEN * DM;       // 16.78M elements
  const size_t nwq = (size_t)DM * DM;              // 16.78M
  const size_t nwk = (size_t)(NKVH * HD) * DM;     // 4.19M

  const float scale = 0.08838834764831845f;  // 1/sqrt(128), folded into Q-rope
  const int nrk = 2 * NKVH * S_LEN;
  dim3 blk(256);

  if (ws_size >= ((size_t)180 << 20)) {
    // -------- fast path: mega-cvt + fused QKV GEMM + fused Q-rope in attn ----
    u16* xb    = (u16*)alloc(nx * 2);                 // aob aliases after use
    u16* wqkvb = (u16*)alloc((nwq + 2 * nwk) * 2);    // [wq;wk;wv] 6144x4096
    u16* wob   = (u16*)alloc(nwq * 2);
    u16* qb    = (u16*)alloc(nx * 2);
    u16* kb    = (u16*)alloc(nwk * 2);
    u16* vtb   = (u16*)alloc(nwk * 2);
    float* sin_t = (float*)alloc((size_t)S_LEN * 64 * 4);
    float* cos_t = (float*)alloc((size_t)S_LEN * 64 * 4);
    u16* aob = xb;  // alias: x (bf16) dead after QKV projection

    cvt_all<<<2048, 256, 0, stream>>>(x, wq, wk, wv, wo, xb, wqkvb, wob);
    rope_table_kernel<<<(S_LEN * 64 + 255) / 256, 256, 0, stream>>>(sin_t, cos_t);

    gemm_qkv<<<dim3(48, 32), blk, 0, stream>>>(xb, wqkvb, qb, kb, vtb, DM);

    rope_apply<<<((size_t)nrk * 64 + 255) / 256, 256, 0, stream>>>(kb, sin_t, cos_t, 1.0f, nrk);

    attn_kernel<<<dim3(16, 64), blk, 0, stream>>>(qb, kb, vtb, aob, sin_t, cos_t, scale);

    gemm16<0, float><<<dim3(32, 32), blk, 0, stream>>>(aob, wob, (float*)d_out, 4096, DM, DM, 0);
  } else {
    // -------- fallback: proven round-10 path (f32 reg-staged GEMMs) --------
    u16* qb  = (u16*)alloc(nx * 2);
    u16* kb  = (u16*)alloc(nwk * 2);
    u16* vtb = (u16*)alloc(nwk * 2);
    u16* aob = (u16*)alloc(nx * 2);
    float* sin_t = (float*)alloc((size_t)S_LEN * 64 * 4);
    float* cos_t = (float*)alloc((size_t)S_LEN * 64 * 4);

    rope_table_kernel<<<(S_LEN * 64 + 255) / 256, 256, 0, stream>>>(sin_t, cos_t);

    gemm_bt<1, float, float, u16><<<dim3(32, 32), blk, 0, stream>>>(x, wq, qb, 4096, DM, DM, NQH);
    gemm_bt<1, float, float, u16><<<dim3(8, 32), blk, 0, stream>>>(x, wk, kb, 4096, 1024, DM, NKVH);
    gemm_bt<2, float, float, u16><<<dim3(8, 32), blk, 0, stream>>>(x, wv, vtb, 4096, 1024, DM, NKVH);

    rope_apply<<<((size_t)nrk * 64 + 255) / 256, 256, 0, stream>>>(kb, sin_t, cos_t, 1.0f, nrk);

    attn_kernel<<<dim3(16, 64), blk, 0, stream>>>(qb, kb, vtb, aob, sin_t, cos_t, scale);

    gemm_bt<0, u16, float, float><<<dim3(32, 32), blk, 0, stream>>>(aob, wo, (float*)d_out, 4096, DM, DM, 0);
  }
}

// Round 26
// 571.506 us; speedup vs baseline: 1.2866x; 1.1591x over previous
//
#include <hip/hip_runtime.h>
#include <cstdint>

#define S_LEN 2048
#define DM 4096
#define NQH 32
#define NKVH 8
#define HD 128

typedef __bf16 bf16x8 __attribute__((ext_vector_type(8)));
typedef float f32x4 __attribute__((ext_vector_type(4)));
typedef unsigned short u16;
typedef unsigned short u16x8 __attribute__((ext_vector_type(8)));
typedef unsigned int u32;

__device__ __forceinline__ float bf2f(u16 h) {
  union { u32 u; float f; } v; v.u = ((u32)h) << 16; return v.f;
}
__device__ __forceinline__ u16 f2bf(float f) {
  union { float f; u32 u; } v; v.f = f;
  u32 u = v.u;
  return (u16)((u + 0x7FFFu + ((u >> 16) & 1u)) >> 16);
}

// global -> LDS direct DMA, 16B/lane. LDS dest = wave-uniform base + lane*16;
// global source is per-lane (bit-validated vs reg-staged path).
__device__ __forceinline__ void gload16(const void* g, const void* l) {
  __builtin_amdgcn_global_load_lds(
      (const __attribute__((address_space(1))) u32*)(uintptr_t)g,
      (__attribute__((address_space(3))) u32*)(u32)(uintptr_t)l,
      16, 0, 0);
}

// ---- reg-staging helpers (fallback path): 16 elements global -> LDS
__device__ __forceinline__ void stage16(const float* __restrict__ g, u16* l) {
  const float4* gp = reinterpret_cast<const float4*>(g);
  float4 v0 = gp[0], v1 = gp[1], v2 = gp[2], v3 = gp[3];
  u16x8 a, b;
  a[0] = f2bf(v0.x); a[1] = f2bf(v0.y); a[2] = f2bf(v0.z); a[3] = f2bf(v0.w);
  a[4] = f2bf(v1.x); a[5] = f2bf(v1.y); a[6] = f2bf(v1.z); a[7] = f2bf(v1.w);
  b[0] = f2bf(v2.x); b[1] = f2bf(v2.y); b[2] = f2bf(v2.z); b[3] = f2bf(v2.w);
  b[4] = f2bf(v3.x); b[5] = f2bf(v3.y); b[6] = f2bf(v3.z); b[7] = f2bf(v3.w);
  *reinterpret_cast<u16x8*>(l) = a;
  *reinterpret_cast<u16x8*>(l + 8) = b;
}
__device__ __forceinline__ void stage16(const u16* __restrict__ g, u16* l) {
  *reinterpret_cast<u16x8*>(l) = *reinterpret_cast<const u16x8*>(g);
  *reinterpret_cast<u16x8*>(l + 8) = *reinterpret_cast<const u16x8*>(g + 8);
}

// output store: bf16 (intermediates) or f32 (final d_out)
__device__ __forceinline__ void stc(u16* p, float v) { *p = f2bf(v); }
__device__ __forceinline__ void stc(float* p, float v) { *p = v; }

// ---------------- mega convert: all 5 f32 inputs -> bf16, one launch --------
__device__ __forceinline__ void cvt8(const float* in, u16* out, size_t i8) {
  const float4* gp = reinterpret_cast<const float4*>(in) + i8 * 2;
  float4 a = gp[0], b = gp[1];
  u16x8 o;
  o[0] = f2bf(a.x); o[1] = f2bf(a.y); o[2] = f2bf(a.z); o[3] = f2bf(a.w);
  o[4] = f2bf(b.x); o[5] = f2bf(b.y); o[6] = f2bf(b.z); o[7] = f2bf(b.w);
  reinterpret_cast<u16x8*>(out)[i8] = o;
}
__global__ void cvt_all(const float* x, const float* wq, const float* wk,
                        const float* wv, const float* wo,
                        u16* xb, u16* wqkvb, u16* wob) {
  const size_t NX8 = (size_t)2 * S_LEN * DM / 8;     // 2.097M
  const size_t NW8 = (size_t)DM * DM / 8;            // 2.097M
  const size_t NK8 = (size_t)NKVH * HD * DM / 8;     // 0.524M
  const size_t total = NX8 + NW8 + 2 * NK8 + NW8;
  size_t stride = (size_t)gridDim.x * blockDim.x;
  for (size_t i = (size_t)blockIdx.x * blockDim.x + threadIdx.x; i < total; i += stride) {
    if (i < NX8)                       cvt8(x,  xb,                    i);
    else if (i < NX8 + NW8)            cvt8(wq, wqkvb,                 i - NX8);
    else if (i < NX8 + NW8 + NK8)      cvt8(wk, wqkvb + NW8 * 8,       i - NX8 - NW8);
    else if (i < NX8 + NW8 + 2 * NK8)  cvt8(wv, wqkvb + (NW8 + NK8) * 8, i - NX8 - NW8 - NK8);
    else                               cvt8(wo, wob,                   i - NX8 - NW8 - 2 * NK8);
  }
}

// ---------------- RoPE table (llama3 scaling), fp64 ----------------
__global__ void rope_table_kernel(float* __restrict__ sin_t, float* __restrict__ cos_t) {
  int idx = blockIdx.x * blockDim.x + threadIdx.x;
  if (idx >= S_LEN * 64) return;
  int s = idx >> 6, i = idx & 63;
  const double PI = 3.14159265358979323846;
  double freq = pow(500000.0, -((double)i) / 64.0);
  double wavelen = 2.0 * PI / freq;
  double inv = (wavelen > 8192.0) ? freq / 32.0 : freq;
  if (!(wavelen < 2048.0) && !(wavelen > 8192.0)) {
    double smooth = (8192.0 / wavelen - 1.0) / 3.0;
    inv = (1.0 - smooth) * (freq / 32.0) + smooth * freq;
  }
  double ang = (double)s * inv;
  sin_t[idx] = (float)sin(ang);
  cos_t[idx] = (float)cos(ang);
}

// ---------------- RoPE apply in place on [B,H,S,128] bf16 (K path) ----------
__global__ void rope_apply(u16* __restrict__ X, const float* __restrict__ sin_t,
                           const float* __restrict__ cos_t, float scale, int nrows) {
  int idx = blockIdx.x * blockDim.x + threadIdx.x;
  if (idx >= nrows * 64) return;
  int row = idx >> 6, i = idx & 63;
  int s = row & (S_LEN - 1);
  size_t base = (size_t)row * HD;
  float lo = bf2f(X[base + i]);
  float hi = bf2f(X[base + i + 64]);
  float sn = sin_t[s * 64 + i];
  float cs = cos_t[s * 64 + i];
  X[base + i] = f2bf((lo * cs - hi * sn) * scale);
  X[base + i + 64] = f2bf((hi * cs + lo * sn) * scale);
}

// ================= GEMM (bf16, gload16 staging, BK=64 deep K-tile) ==========
// C = A(MxK) * B(NxK)^T, f32 acc.  MODE 0: C[m*N+n].
// BK=64: two m97 K-steps per barrier pair. LDS [128][64] with granule^(row&7)
// swizzle (round-24: 41.7% MfmaUtil, 0 conflicts).
template <int MODE, typename TC>
__global__ __launch_bounds__(256, 4)
void gemm16(const u16* __restrict__ A, const u16* __restrict__ B,
            TC* __restrict__ C, int M, int N, int K, int H) {
  __shared__ u16 sA[128 * 64];
  __shared__ u16 sB[128 * 64];
  const int tid = threadIdx.x;
  const int lane = tid & 63;
  const int wv = tid >> 6;
  const int wr = wv >> 1, wc = wv & 1;
  const int bm = blockIdx.y * 128;
  const int bn = blockIdx.x * 128;
  const int fr = lane & 15, fq = lane >> 4;
  const int srow_base = wv * 8 + (lane >> 3);
  const int sgran = (((lane & 7) ^ ((lane >> 3) & 7))) * 8;
  const int rxor = fr & 7;

  f32x4 zero4 = {0.f, 0.f, 0.f, 0.f};
  f32x4 acc[4][4];
#pragma unroll
  for (int i = 0; i < 4; ++i)
#pragma unroll
    for (int j = 0; j < 4; ++j) acc[i][j] = zero4;

  for (int k0 = 0; k0 < K; k0 += 64) {
    __syncthreads();
#pragma unroll
    for (int g = 0; g < 4; ++g) {
      int row = g * 32 + srow_base;
      gload16(A + (size_t)(bm + row) * K + k0 + sgran, sA + g * 2048 + wv * 512);
      gload16(B + (size_t)(bn + row) * K + k0 + sgran, sB + g * 2048 + wv * 512);
    }
    __syncthreads();
#pragma unroll
    for (int kk = 0; kk < 2; ++kk) {
      bf16x8 af[4], bg[4];
      const int gofs = ((kk * 4 + fq) ^ rxor) * 8;
#pragma unroll
      for (int i = 0; i < 4; ++i) {
        af[i] = *(const bf16x8*)(sA + (wr * 64 + i * 16 + fr) * 64 + gofs);
        bg[i] = *(const bf16x8*)(sB + (wc * 64 + i * 16 + fr) * 64 + gofs);
      }
#pragma unroll
      for (int i = 0; i < 4; ++i)
#pragma unroll
        for (int j = 0; j < 4; ++j)
          acc[i][j] = __builtin_amdgcn_mfma_f32_16x16x32_bf16(af[i], bg[j], acc[i][j], 0, 0, 0);
    }
  }

#pragma unroll
  for (int i = 0; i < 4; ++i)
#pragma unroll
    for (int j = 0; j < 4; ++j)
#pragma unroll
      for (int r = 0; r < 4; ++r) {
        int m = bm + wr * 64 + i * 16 + fq * 4 + r;
        int n = bn + wc * 64 + j * 16 + fr;
        stc(C + (size_t)m * N + n, acc[i][j][r]);
      }
}

// ========== fused QKV projection GEMM: A=x[4096x4096], B=[wq;wk;wv] =========
// N=6144. BK=64 + granule^(row&7) swizzle. Epilogue scatter by segment:
// n<4096: Q [B,32,S,128]; 4096<=n<5120: K [B,8,S,128]; else V^T [B,8,128,S].
__global__ __launch_bounds__(256, 4)
void gemm_qkv(const u16* __restrict__ A, const u16* __restrict__ B,
              u16* __restrict__ Cq, u16* __restrict__ Ck, u16* __restrict__ Cv,
              int K) {
  __shared__ u16 sA[128 * 64];
  __shared__ u16 sB[128 * 64];
  const int tid = threadIdx.x;
  const int lane = tid & 63;
  const int wv = tid >> 6;
  const int wr = wv >> 1, wc = wv & 1;
  const int bm = blockIdx.y * 128;
  const int bn = blockIdx.x * 128;
  const int fr = lane & 15, fq = lane >> 4;
  const int srow_base = wv * 8 + (lane >> 3);
  const int sgran = (((lane & 7) ^ ((lane >> 3) & 7))) * 8;
  const int rxor = fr & 7;

  f32x4 zero4 = {0.f, 0.f, 0.f, 0.f};
  f32x4 acc[4][4];
#pragma unroll
  for (int i = 0; i < 4; ++i)
#pragma unroll
    for (int j = 0; j < 4; ++j) acc[i][j] = zero4;

  for (int k0 = 0; k0 < K; k0 += 64) {
    __syncthreads();
#pragma unroll
    for (int g = 0; g < 4; ++g) {
      int row = g * 32 + srow_base;
      gload16(A + (size_t)(bm + row) * K + k0 + sgran, sA + g * 2048 + wv * 512);
      gload16(B + (size_t)(bn + row) * K + k0 + sgran, sB + g * 2048 + wv * 512);
    }
    __syncthreads();
#pragma unroll
    for (int kk = 0; kk < 2; ++kk) {
      bf16x8 af[4], bg[4];
      const int gofs = ((kk * 4 + fq) ^ rxor) * 8;
#pragma unroll
      for (int i = 0; i < 4; ++i) {
        af[i] = *(const bf16x8*)(sA + (wr * 64 + i * 16 + fr) * 64 + gofs);
        bg[i] = *(const bf16x8*)(sB + (wc * 64 + i * 16 + fr) * 64 + gofs);
      }
#pragma unroll
      for (int i = 0; i < 4; ++i)
#pragma unroll
        for (int j = 0; j < 4; ++j)
          acc[i][j] = __builtin_amdgcn_mfma_f32_16x16x32_bf16(af[i], bg[j], acc[i][j], 0, 0, 0);
    }
  }

#pragma unroll
  for (int i = 0; i < 4; ++i)
#pragma unroll
    for (int j = 0; j < 4; ++j)
#pragma unroll
      for (int r = 0; r < 4; ++r) {
        int m = bm + wr * 64 + i * 16 + fq * 4 + r;
        int n = bn + wc * 64 + j * 16 + fr;
        int b = m >> 11, s = m & 2047;
        u16 hval = f2bf(acc[i][j][r]);
        if (n < 4096) {
          int hh = n >> 7, d = n & 127;
          Cq[(((size_t)(b * NQH + hh)) * S_LEN + s) * HD + d] = hval;
        } else if (n < 5120) {
          int nn = n - 4096;
          int hh = nn >> 7, d = nn & 127;
          Ck[(((size_t)(b * NKVH + hh)) * S_LEN + s) * HD + d] = hval;
        } else {
          int nn = n - 5120;
          int hh = nn >> 7, d = nn & 127;
          Cv[(((size_t)(b * NKVH + hh)) * HD + d) * S_LEN + s] = hval;
        }
      }
}

// ================= GEMM fallback (reg-staged; round-10, templated A/B) =======
template <int MODE, typename TA, typename TB, typename TC>
__global__ __launch_bounds__(256, 2)
void gemm_bt(const TA* __restrict__ A, const TB* __restrict__ B,
             TC* __restrict__ C, int M, int N, int K, int H) {
  __shared__ u16 sA[128 * 32];
  __shared__ u16 sB[128 * 32];
  const int tid = threadIdx.x;
  const int lane = tid & 63;
  const int wv = tid >> 6;
  const int wr = wv >> 1, wc = wv & 1;
  const int bm = blockIdx.y * 128;
  const int bn = blockIdx.x * 128;
  const int fr = lane & 15, fq = lane >> 4;
  const int srow = tid >> 1;
  const int shalf = (tid & 1) * 16;

  f32x4 zero4 = {0.f, 0.f, 0.f, 0.f};
  f32x4 acc[4][4];
#pragma unroll
  for (int i = 0; i < 4; ++i)
#pragma unroll
    for (int j = 0; j < 4; ++j) acc[i][j] = zero4;

  for (int k0 = 0; k0 < K; k0 += 32) {
    __syncthreads();
    stage16(A + (size_t)(bm + srow) * K + k0 + shalf, sA + srow * 32 + shalf);
    stage16(B + (size_t)(bn + srow) * K + k0 + shalf, sB + srow * 32 + shalf);
    __syncthreads();
    bf16x8 af[4], bg[4];
#pragma unroll
    for (int i = 0; i < 4; ++i) {
      af[i] = *(const bf16x8*)(sA + (wr * 64 + i * 16 + fr) * 32 + fq * 8);
      bg[i] = *(const bf16x8*)(sB + (wc * 64 + i * 16 + fr) * 32 + fq * 8);
    }
#pragma unroll
    for (int i = 0; i < 4; ++i)
#pragma unroll
      for (int j = 0; j < 4; ++j)
        acc[i][j] = __builtin_amdgcn_mfma_f32_16x16x32_bf16(af[i], bg[j], acc[i][j], 0, 0, 0);
  }

#pragma unroll
  for (int i = 0; i < 4; ++i)
#pragma unroll
    for (int j = 0; j < 4; ++j)
#pragma unroll
      for (int r = 0; r < 4; ++r) {
        int m = bm + wr * 64 + i * 16 + fq * 4 + r;
        int n = bn + wc * 64 + j * 16 + fr;
        float v = acc[i][j][r];
        if (MODE == 0) {
          stc(C + (size_t)m * N + n, v);
        } else if (MODE == 1) {
          int b = m >> 11, s = m & 2047, hh = n >> 7, d = n & 127;
          stc(C + (((size_t)(b * H + hh)) * S_LEN + s) * HD + d, v);
        } else {
          int b = m >> 11, s = m & 2047, hh = n >> 7, d = n & 127;
          stc(C + (((size_t)(b * H + hh)) * HD + d) * S_LEN + s, v);
        }
      }
}

// == causal GQA flash attention (PAIRED q-blocks: uniform 34 tile-units) ======
// Q_raw [B,32,S,128] (pre-rope), K [B,8,S,128] (rope'd), V^T [B,8,128,S].
// grid (8, B*32), block 256. Each block processes q-tiles (15-bx) then bx:
// (32-2bx) + (2bx+2) = 34 tile-units for EVERY block -> zero makespan tail
// (round-25's LPT still had a 34-vs-17 max/mean imbalance).
// Q-RoPE fused in-register at fragment load. XOR swizzle granule ^= (row&7)
// on K/V/P; gload16 pre-swizzled source. Defer-max THR=8; l lane-local,
// epilogue-reduced; sP reused across u (40KB LDS). T5 setprio around MFMA.
__global__ __launch_bounds__(256, 2)
void attn_kernel(const u16* __restrict__ Q, const u16* __restrict__ K,
                 const u16* __restrict__ V, u16* __restrict__ O,
                 const float* __restrict__ sin_t, const float* __restrict__ cos_t,
                 float scale) {
  __shared__ u16 sK[64 * 128];   // [kv][d], swizzled (16 KB)
  __shared__ u16 sV[128 * 64];   // [d][kv], swizzled (16 KB)
  __shared__ u16 sP[4][16 * 64]; // per-wave P (16 rows, reused per u) (8 KB)

  const int tid = threadIdx.x, lane = tid & 63, wv = tid >> 6;
  const int fr = lane & 15, fq = lane >> 4;
  const int bx = blockIdx.x;            // 0..7
  const int bh = blockIdx.y;
  const int b = bh >> 5, h = bh & 31;
  const int hkv = h >> 2;
  const u16* Qb = Q + (size_t)bh * S_LEN * HD;
  const u16* Kb = K + (size_t)(b * NKVH + hkv) * S_LEN * HD;
  const u16* Vb = V + (size_t)(b * NKVH + hkv) * HD * S_LEN;

  for (int half = 0; half < 2; ++half) {
    const int q0 = (half == 0 ? (15 - bx) : bx) * 128;  // long half first

    // Q fragments with fused RoPE + scale
    u16x8 qfu[2][4];
#pragma unroll
    for (int u = 0; u < 2; ++u) {
      int qrow = q0 + wv * 32 + u * 16 + fr;   // == s (0..2047)
      const u16* qp = Qb + (size_t)qrow * HD;
      u16x8 raw[4];
#pragma unroll
      for (int ks = 0; ks < 4; ++ks)
        raw[ks] = *(const u16x8*)(qp + ks * 32 + fq * 8);
#pragma unroll
      for (int p = 0; p < 2; ++p) {
        const float* cb = cos_t + (size_t)qrow * 64 + p * 32 + fq * 8;
        const float* sb = sin_t + (size_t)qrow * 64 + p * 32 + fq * 8;
        float4 c0 = ((const float4*)cb)[0], c1 = ((const float4*)cb)[1];
        float4 s0 = ((const float4*)sb)[0], s1 = ((const float4*)sb)[1];
        float cs[8] = {c0.x, c0.y, c0.z, c0.w, c1.x, c1.y, c1.z, c1.w};
        float sn[8] = {s0.x, s0.y, s0.z, s0.w, s1.x, s1.y, s1.z, s1.w};
#pragma unroll
        for (int j = 0; j < 8; ++j) {
          float lo = bf2f(raw[p][j]);
          float hi = bf2f(raw[p + 2][j]);
          qfu[u][p][j]     = f2bf((lo * cs[j] - hi * sn[j]) * scale);
          qfu[u][p + 2][j] = f2bf((hi * cs[j] + lo * sn[j]) * scale);
        }
      }
    }
    const bf16x8* qf0 = (const bf16x8*)&qfu[0][0];
    const bf16x8* qf1 = (const bf16x8*)&qfu[1][0];

    f32x4 zero4 = {0.f, 0.f, 0.f, 0.f};
    f32x4 o[2][8];
    float m[2][4], l[2][4];
#pragma unroll
    for (int u = 0; u < 2; ++u) {
#pragma unroll
      for (int dt = 0; dt < 8; ++dt) o[u][dt] = zero4;
#pragma unroll
      for (int r = 0; r < 4; ++r) { m[u][r] = -3.0e38f; l[u][r] = 0.f; }
    }

    const int ntiles = (q0 >> 6) + 2;
    for (int t = 0; t < ntiles; ++t) {
      const int s0 = t * 64;
      __syncthreads();
#pragma unroll
      for (int j = 0; j < 4; ++j) {
        int c = j * 4 + wv;
        {
          int row = c * 4 + (lane >> 4);
          int e = ((lane & 15) ^ (row & 7)) * 8;
          gload16(Kb + (size_t)(s0 + row) * HD + e, sK + c * 512);
        }
        {
          int row = c * 8 + (lane >> 3);
          int e = ((lane & 7) ^ (row & 7)) * 8;
          gload16(Vb + (size_t)row * S_LEN + s0 + e, sV + c * 512);
        }
      }
      __syncthreads();

      f32x4 sc[2][4];
#pragma unroll
      for (int u = 0; u < 2; ++u)
#pragma unroll
        for (int j = 0; j < 4; ++j) sc[u][j] = zero4;
      __builtin_amdgcn_s_setprio(1);
#pragma unroll
      for (int j = 0; j < 4; ++j) {
#pragma unroll
        for (int ks = 0; ks < 4; ++ks) {
          int row = j * 16 + fr;
          int e = (ks * 32 + fq * 8) ^ ((row & 7) << 3);
          bf16x8 kf = *(const bf16x8*)(sK + row * 128 + e);
          sc[0][j] = __builtin_amdgcn_mfma_f32_16x16x32_bf16(qf0[ks], kf, sc[0][j], 0, 0, 0);
          sc[1][j] = __builtin_amdgcn_mfma_f32_16x16x32_bf16(qf1[ks], kf, sc[1][j], 0, 0, 0);
        }
      }
      __builtin_amdgcn_s_setprio(0);

      if (t >= ntiles - 2) {
#pragma unroll
        for (int u = 0; u < 2; ++u)
#pragma unroll
          for (int j = 0; j < 4; ++j)
#pragma unroll
            for (int r = 0; r < 4; ++r) {
              int kvp = s0 + j * 16 + fr;
              int qp = q0 + wv * 32 + u * 16 + fq * 4 + r;
              if (kvp > qp) sc[u][j][r] = -3.0e38f;
            }
      }

      // softmax + P-repack per u-fragment (sP reused across u)
      bf16x8 pa[2][2];
#pragma unroll
      for (int u = 0; u < 2; ++u) {
        float al[4];
        bool resc = false;
#pragma unroll
        for (int r = 0; r < 4; ++r) {
          float v = fmaxf(fmaxf(sc[u][0][r], sc[u][1][r]), fmaxf(sc[u][2][r], sc[u][3][r]));
          v = fmaxf(v, __shfl_xor(v, 1, 64));
          v = fmaxf(v, __shfl_xor(v, 2, 64));
          v = fmaxf(v, __shfl_xor(v, 4, 64));
          v = fmaxf(v, __shfl_xor(v, 8, 64));
          if (v > m[u][r] + 8.f) {
            al[r] = __expf(m[u][r] - v);
            m[u][r] = v;
            resc = true;
          } else {
            al[r] = 1.f;
          }
        }
#pragma unroll
        for (int r = 0; r < 4; ++r) {
          float rs = 0.f;
          int prow = fq * 4 + r;
#pragma unroll
          for (int j = 0; j < 4; ++j) {
            float pv = __expf(sc[u][j][r] - m[u][r]);
            rs += pv;
            int e = (j * 16 + fr) ^ ((prow & 7) << 3);
            sP[wv][prow * 64 + e] = f2bf(pv);
          }
          l[u][r] = l[u][r] * al[r] + rs;
        }
        if (resc) {
#pragma unroll
          for (int r = 0; r < 4; ++r)
#pragma unroll
            for (int dt = 0; dt < 8; ++dt) o[u][dt][r] *= al[r];
        }
#pragma unroll
        for (int ks = 0; ks < 2; ++ks) {
          int e = (ks * 32 + fq * 8) ^ ((fr & 7) << 3);
          pa[u][ks] = *(const bf16x8*)(&sP[wv][fr * 64 + e]);
        }
      }

      // PV: o[u][dt] rows q, cols d=dt*16+fr; each vf feeds both u-fragments
      __builtin_amdgcn_s_setprio(1);
#pragma unroll
      for (int dt = 0; dt < 8; ++dt) {
#pragma unroll
        for (int ks = 0; ks < 2; ++ks) {
          int row = dt * 16 + fr;
          int e = (ks * 32 + fq * 8) ^ ((row & 7) << 3);
          bf16x8 vf = *(const bf16x8*)(sV + row * 64 + e);
#pragma unroll
          for (int u = 0; u < 2; ++u)
            o[u][dt] = __builtin_amdgcn_mfma_f32_16x16x32_bf16(pa[u][ks], vf, o[u][dt], 0, 0, 0);
        }
      }
      __builtin_amdgcn_s_setprio(0);
    }

#pragma unroll
    for (int u = 0; u < 2; ++u)
#pragma unroll
      for (int r = 0; r < 4; ++r) {
        float lt = l[u][r];
        lt += __shfl_xor(lt, 1, 64);
        lt += __shfl_xor(lt, 2, 64);
        lt += __shfl_xor(lt, 4, 64);
        lt += __shfl_xor(lt, 8, 64);
        int qp = q0 + wv * 32 + u * 16 + fq * 4 + r;
        float inv_l = 1.0f / lt;
        size_t base = ((size_t)b * S_LEN + qp) * DM + h * HD;
#pragma unroll
        for (int dt = 0; dt < 8; ++dt)
          O[base + dt * 16 + fr] = f2bf(o[u][dt][r] * inv_l);
      }
  }
}

extern "C" void kernel_launch(void* const* d_in, const int* in_sizes, int n_in,
                              void* d_out, int out_size, void* d_ws, size_t ws_size,
                              hipStream_t stream) {
  const float* x  = (const float*)d_in[0];
  const float* wq = (const float*)d_in[1];
  const float* wk = (const float*)d_in[2];
  const float* wv = (const float*)d_in[3];
  const float* wo = (const float*)d_in[4];

  char* ws = (char*)d_ws;
  size_t off = 0;
  auto alloc = [&](size_t bytes) {
    void* p = ws + off;
    off += (bytes + 255) & ~(size_t)255;
    return p;
  };

  const size_t nx  = (size_t)2 * S_LEN * DM;       // 16.78M elements
  const size_t nwq = (size_t)DM * DM;              // 16.78M
  const size_t nwk = (size_t)(NKVH * HD) * DM;     // 4.19M

  const float scale = 0.08838834764831845f;  // 1/sqrt(128), folded into Q-rope
  const int nrk = 2 * NKVH * S_LEN;
  dim3 blk(256);

  if (ws_size >= ((size_t)180 << 20)) {
    // -------- fast path: mega-cvt + fused QKV GEMM + fused Q-rope in attn ----
    u16* xb    = (u16*)alloc(nx * 2);                 // aob aliases after use
    u16* wqkvb = (u16*)alloc((nwq + 2 * nwk) * 2);    // [wq;wk;wv] 6144x4096
    u16* wob   = (u16*)alloc(nwq * 2);
    u16* qb    = (u16*)alloc(nx * 2);
    u16* kb    = (u16*)alloc(nwk * 2);
    u16* vtb   = (u16*)alloc(nwk * 2);
    float* sin_t = (float*)alloc((size_t)S_LEN * 64 * 4);
    float* cos_t = (float*)alloc((size_t)S_LEN * 64 * 4);
    u16* aob = xb;  // alias: x (bf16) dead after QKV projection

    cvt_all<<<2048, 256, 0, stream>>>(x, wq, wk, wv, wo, xb, wqkvb, wob);
    rope_table_kernel<<<(S_LEN * 64 + 255) / 256, 256, 0, stream>>>(sin_t, cos_t);

    gemm_qkv<<<dim3(48, 32), blk, 0, stream>>>(xb, wqkvb, qb, kb, vtb, DM);

    rope_apply<<<((size_t)nrk * 64 + 255) / 256, 256, 0, stream>>>(kb, sin_t, cos_t, 1.0f, nrk);

    attn_kernel<<<dim3(8, 64), blk, 0, stream>>>(qb, kb, vtb, aob, sin_t, cos_t, scale);

    gemm16<0, float><<<dim3(32, 32), blk, 0, stream>>>(aob, wob, (float*)d_out, 4096, DM, DM, 0);
  } else {
    // -------- fallback: proven round-10 path (f32 reg-staged GEMMs) --------
    u16* qb  = (u16*)alloc(nx * 2);
    u16* kb  = (u16*)alloc(nwk * 2);
    u16* vtb = (u16*)alloc(nwk * 2);
    u16* aob = (u16*)alloc(nx * 2);
    float* sin_t = (float*)alloc((size_t)S_LEN * 64 * 4);
    float* cos_t = (float*)alloc((size_t)S_LEN * 64 * 4);

    rope_table_kernel<<<(S_LEN * 64 + 255) / 256, 256, 0, stream>>>(sin_t, cos_t);

    gemm_bt<1, float, float, u16><<<dim3(32, 32), blk, 0, stream>>>(x, wq, qb, 4096, DM, DM, NQH);
    gemm_bt<1, float, float, u16><<<dim3(8, 32), blk, 0, stream>>>(x, wk, kb, 4096, 1024, DM, NKVH);
    gemm_bt<2, float, float, u16><<<dim3(8, 32), blk, 0, stream>>>(x, wv, vtb, 4096, 1024, DM, NKVH);

    rope_apply<<<((size_t)nrk * 64 + 255) / 256, 256, 0, stream>>>(kb, sin_t, cos_t, 1.0f, nrk);

    attn_kernel<<<dim3(8, 64), blk, 0, stream>>>(qb, kb, vtb, aob, sin_t, cos_t, scale);

    gemm_bt<0, u16, float, float><<<dim3(32, 32), blk, 0, stream>>>(aob, wo, (float*)d_out, 4096, DM, DM, 0);
  }
}

// Round 27
// 569.919 us; speedup vs baseline: 1.2902x; 1.0028x over previous
//
#include <hip/hip_runtime.h>
#include <cstdint>

#define S_LEN 2048
#define DM 4096
#define NQH 32
#define NKVH 8
#define HD 128

typedef __bf16 bf16x8 __attribute__((ext_vector_type(8)));
typedef float f32x4 __attribute__((ext_vector_type(4)));
typedef unsigned short u16;
typedef unsigned short u16x8 __attribute__((ext_vector_type(8)));
typedef unsigned int u32;

__device__ __forceinline__ float bf2f(u16 h) {
  union { u32 u; float f; } v; v.u = ((u32)h) << 16; return v.f;
}
__device__ __forceinline__ u16 f2bf(float f) {
  union { float f; u32 u; } v; v.f = f;
  u32 u = v.u;
  return (u16)((u + 0x7FFFu + ((u >> 16) & 1u)) >> 16);
}

// global -> LDS direct DMA, 16B/lane. LDS dest = wave-uniform base + lane*16;
// global source is per-lane (bit-validated vs reg-staged path).
__device__ __forceinline__ void gload16(const void* g, const void* l) {
  __builtin_amdgcn_global_load_lds(
      (const __attribute__((address_space(1))) u32*)(uintptr_t)g,
      (__attribute__((address_space(3))) u32*)(u32)(uintptr_t)l,
      16, 0, 0);
}

// ---- reg-staging helpers (fallback path): 16 elements global -> LDS
__device__ __forceinline__ void stage16(const float* __restrict__ g, u16* l) {
  const float4* gp = reinterpret_cast<const float4*>(g);
  float4 v0 = gp[0], v1 = gp[1], v2 = gp[2], v3 = gp[3];
  u16x8 a, b;
  a[0] = f2bf(v0.x); a[1] = f2bf(v0.y); a[2] = f2bf(v0.z); a[3] = f2bf(v0.w);
  a[4] = f2bf(v1.x); a[5] = f2bf(v1.y); a[6] = f2bf(v1.z); a[7] = f2bf(v1.w);
  b[0] = f2bf(v2.x); b[1] = f2bf(v2.y); b[2] = f2bf(v2.z); b[3] = f2bf(v2.w);
  b[4] = f2bf(v3.x); b[5] = f2bf(v3.y); b[6] = f2bf(v3.z); b[7] = f2bf(v3.w);
  *reinterpret_cast<u16x8*>(l) = a;
  *reinterpret_cast<u16x8*>(l + 8) = b;
}
__device__ __forceinline__ void stage16(const u16* __restrict__ g, u16* l) {
  *reinterpret_cast<u16x8*>(l) = *reinterpret_cast<const u16x8*>(g);
  *reinterpret_cast<u16x8*>(l + 8) = *reinterpret_cast<const u16x8*>(g + 8);
}

// output store: bf16 (intermediates) or f32 (final d_out)
__device__ __forceinline__ void stc(u16* p, float v) { *p = f2bf(v); }
__device__ __forceinline__ void stc(float* p, float v) { *p = v; }

// ---------------- mega convert: all 5 f32 inputs -> bf16, one launch --------
__device__ __forceinline__ void cvt8(const float* in, u16* out, size_t i8) {
  const float4* gp = reinterpret_cast<const float4*>(in) + i8 * 2;
  float4 a = gp[0], b = gp[1];
  u16x8 o;
  o[0] = f2bf(a.x); o[1] = f2bf(a.y); o[2] = f2bf(a.z); o[3] = f2bf(a.w);
  o[4] = f2bf(b.x); o[5] = f2bf(b.y); o[6] = f2bf(b.z); o[7] = f2bf(b.w);
  reinterpret_cast<u16x8*>(out)[i8] = o;
}
__global__ void cvt_all(const float* x, const float* wq, const float* wk,
                        const float* wv, const float* wo,
                        u16* xb, u16* wqkvb, u16* wob) {
  const size_t NX8 = (size_t)2 * S_LEN * DM / 8;     // 2.097M
  const size_t NW8 = (size_t)DM * DM / 8;            // 2.097M
  const size_t NK8 = (size_t)NKVH * HD * DM / 8;     // 0.524M
  const size_t total = NX8 + NW8 + 2 * NK8 + NW8;
  size_t stride = (size_t)gridDim.x * blockDim.x;
  for (size_t i = (size_t)blockIdx.x * blockDim.x + threadIdx.x; i < total; i += stride) {
    if (i < NX8)                       cvt8(x,  xb,                    i);
    else if (i < NX8 + NW8)            cvt8(wq, wqkvb,                 i - NX8);
    else if (i < NX8 + NW8 + NK8)      cvt8(wk, wqkvb + NW8 * 8,       i - NX8 - NW8);
    else if (i < NX8 + NW8 + 2 * NK8)  cvt8(wv, wqkvb + (NW8 + NK8) * 8, i - NX8 - NW8 - NK8);
    else                               cvt8(wo, wob,                   i - NX8 - NW8 - 2 * NK8);
  }
}

// ---------------- RoPE table (llama3 scaling), fp64 ----------------
__global__ void rope_table_kernel(float* __restrict__ sin_t, float* __restrict__ cos_t) {
  int idx = blockIdx.x * blockDim.x + threadIdx.x;
  if (idx >= S_LEN * 64) return;
  int s = idx >> 6, i = idx & 63;
  const double PI = 3.14159265358979323846;
  double freq = pow(500000.0, -((double)i) / 64.0);
  double wavelen = 2.0 * PI / freq;
  double inv = (wavelen > 8192.0) ? freq / 32.0 : freq;
  if (!(wavelen < 2048.0) && !(wavelen > 8192.0)) {
    double smooth = (8192.0 / wavelen - 1.0) / 3.0;
    inv = (1.0 - smooth) * (freq / 32.0) + smooth * freq;
  }
  double ang = (double)s * inv;
  sin_t[idx] = (float)sin(ang);
  cos_t[idx] = (float)cos(ang);
}

// ---------------- RoPE apply in place on [B,H,S,128] bf16 (K path) ----------
__global__ void rope_apply(u16* __restrict__ X, const float* __restrict__ sin_t,
                           const float* __restrict__ cos_t, float scale, int nrows) {
  int idx = blockIdx.x * blockDim.x + threadIdx.x;
  if (idx >= nrows * 64) return;
  int row = idx >> 6, i = idx & 63;
  int s = row & (S_LEN - 1);
  size_t base = (size_t)row * HD;
  float lo = bf2f(X[base + i]);
  float hi = bf2f(X[base + i + 64]);
  float sn = sin_t[s * 64 + i];
  float cs = cos_t[s * 64 + i];
  X[base + i] = f2bf((lo * cs - hi * sn) * scale);
  X[base + i + 64] = f2bf((hi * cs + lo * sn) * scale);
}

// ================= GEMM (bf16, gload16 staging, BK=64 deep K-tile) ==========
// C = A(MxK) * B(NxK)^T, f32 acc.  MODE 0: C[m*N+n].
// BK=64: two m97 K-steps per barrier pair. LDS [128][64] with granule^(row&7)
// swizzle (round-24: 41.7% MfmaUtil, 0 conflicts).
template <int MODE, typename TC>
__global__ __launch_bounds__(256, 4)
void gemm16(const u16* __restrict__ A, const u16* __restrict__ B,
            TC* __restrict__ C, int M, int N, int K, int H) {
  __shared__ u16 sA[128 * 64];
  __shared__ u16 sB[128 * 64];
  const int tid = threadIdx.x;
  const int lane = tid & 63;
  const int wv = tid >> 6;
  const int wr = wv >> 1, wc = wv & 1;
  const int bm = blockIdx.y * 128;
  const int bn = blockIdx.x * 128;
  const int fr = lane & 15, fq = lane >> 4;
  const int srow_base = wv * 8 + (lane >> 3);
  const int sgran = (((lane & 7) ^ ((lane >> 3) & 7))) * 8;
  const int rxor = fr & 7;

  f32x4 zero4 = {0.f, 0.f, 0.f, 0.f};
  f32x4 acc[4][4];
#pragma unroll
  for (int i = 0; i < 4; ++i)
#pragma unroll
    for (int j = 0; j < 4; ++j) acc[i][j] = zero4;

  for (int k0 = 0; k0 < K; k0 += 64) {
    __syncthreads();
#pragma unroll
    for (int g = 0; g < 4; ++g) {
      int row = g * 32 + srow_base;
      gload16(A + (size_t)(bm + row) * K + k0 + sgran, sA + g * 2048 + wv * 512);
      gload16(B + (size_t)(bn + row) * K + k0 + sgran, sB + g * 2048 + wv * 512);
    }
    __syncthreads();
#pragma unroll
    for (int kk = 0; kk < 2; ++kk) {
      bf16x8 af[4], bg[4];
      const int gofs = ((kk * 4 + fq) ^ rxor) * 8;
#pragma unroll
      for (int i = 0; i < 4; ++i) {
        af[i] = *(const bf16x8*)(sA + (wr * 64 + i * 16 + fr) * 64 + gofs);
        bg[i] = *(const bf16x8*)(sB + (wc * 64 + i * 16 + fr) * 64 + gofs);
      }
#pragma unroll
      for (int i = 0; i < 4; ++i)
#pragma unroll
        for (int j = 0; j < 4; ++j)
          acc[i][j] = __builtin_amdgcn_mfma_f32_16x16x32_bf16(af[i], bg[j], acc[i][j], 0, 0, 0);
    }
  }

#pragma unroll
  for (int i = 0; i < 4; ++i)
#pragma unroll
    for (int j = 0; j < 4; ++j)
#pragma unroll
      for (int r = 0; r < 4; ++r) {
        int m = bm + wr * 64 + i * 16 + fq * 4 + r;
        int n = bn + wc * 64 + j * 16 + fr;
        stc(C + (size_t)m * N + n, acc[i][j][r]);
      }
}

// ========== fused QKV projection GEMM: A=x[4096x4096], B=[wq;wk;wv] =========
// N=6144. BK=64 + granule^(row&7) swizzle. Epilogue scatter by segment:
// n<4096: Q [B,32,S,128]; 4096<=n<5120: K [B,8,S,128]; else V^T [B,8,128,S].
__global__ __launch_bounds__(256, 4)
void gemm_qkv(const u16* __restrict__ A, const u16* __restrict__ B,
              u16* __restrict__ Cq, u16* __restrict__ Ck, u16* __restrict__ Cv,
              int K) {
  __shared__ u16 sA[128 * 64];
  __shared__ u16 sB[128 * 64];
  const int tid = threadIdx.x;
  const int lane = tid & 63;
  const int wv = tid >> 6;
  const int wr = wv >> 1, wc = wv & 1;
  const int bm = blockIdx.y * 128;
  const int bn = blockIdx.x * 128;
  const int fr = lane & 15, fq = lane >> 4;
  const int srow_base = wv * 8 + (lane >> 3);
  const int sgran = (((lane & 7) ^ ((lane >> 3) & 7))) * 8;
  const int rxor = fr & 7;

  f32x4 zero4 = {0.f, 0.f, 0.f, 0.f};
  f32x4 acc[4][4];
#pragma unroll
  for (int i = 0; i < 4; ++i)
#pragma unroll
    for (int j = 0; j < 4; ++j) acc[i][j] = zero4;

  for (int k0 = 0; k0 < K; k0 += 64) {
    __syncthreads();
#pragma unroll
    for (int g = 0; g < 4; ++g) {
      int row = g * 32 + srow_base;
      gload16(A + (size_t)(bm + row) * K + k0 + sgran, sA + g * 2048 + wv * 512);
      gload16(B + (size_t)(bn + row) * K + k0 + sgran, sB + g * 2048 + wv * 512);
    }
    __syncthreads();
#pragma unroll
    for (int kk = 0; kk < 2; ++kk) {
      bf16x8 af[4], bg[4];
      const int gofs = ((kk * 4 + fq) ^ rxor) * 8;
#pragma unroll
      for (int i = 0; i < 4; ++i) {
        af[i] = *(const bf16x8*)(sA + (wr * 64 + i * 16 + fr) * 64 + gofs);
        bg[i] = *(const bf16x8*)(sB + (wc * 64 + i * 16 + fr) * 64 + gofs);
      }
#pragma unroll
      for (int i = 0; i < 4; ++i)
#pragma unroll
        for (int j = 0; j < 4; ++j)
          acc[i][j] = __builtin_amdgcn_mfma_f32_16x16x32_bf16(af[i], bg[j], acc[i][j], 0, 0, 0);
    }
  }

#pragma unroll
  for (int i = 0; i < 4; ++i)
#pragma unroll
    for (int j = 0; j < 4; ++j)
#pragma unroll
      for (int r = 0; r < 4; ++r) {
        int m = bm + wr * 64 + i * 16 + fq * 4 + r;
        int n = bn + wc * 64 + j * 16 + fr;
        int b = m >> 11, s = m & 2047;
        u16 hval = f2bf(acc[i][j][r]);
        if (n < 4096) {
          int hh = n >> 7, d = n & 127;
          Cq[(((size_t)(b * NQH + hh)) * S_LEN + s) * HD + d] = hval;
        } else if (n < 5120) {
          int nn = n - 4096;
          int hh = nn >> 7, d = nn & 127;
          Ck[(((size_t)(b * NKVH + hh)) * S_LEN + s) * HD + d] = hval;
        } else {
          int nn = n - 5120;
          int hh = nn >> 7, d = nn & 127;
          Cv[(((size_t)(b * NKVH + hh)) * HD + d) * S_LEN + s] = hval;
        }
      }
}

// ================= GEMM fallback (reg-staged; round-10, templated A/B) =======
template <int MODE, typename TA, typename TB, typename TC>
__global__ __launch_bounds__(256, 2)
void gemm_bt(const TA* __restrict__ A, const TB* __restrict__ B,
             TC* __restrict__ C, int M, int N, int K, int H) {
  __shared__ u16 sA[128 * 32];
  __shared__ u16 sB[128 * 32];
  const int tid = threadIdx.x;
  const int lane = tid & 63;
  const int wv = tid >> 6;
  const int wr = wv >> 1, wc = wv & 1;
  const int bm = blockIdx.y * 128;
  const int bn = blockIdx.x * 128;
  const int fr = lane & 15, fq = lane >> 4;
  const int srow = tid >> 1;
  const int shalf = (tid & 1) * 16;

  f32x4 zero4 = {0.f, 0.f, 0.f, 0.f};
  f32x4 acc[4][4];
#pragma unroll
  for (int i = 0; i < 4; ++i)
#pragma unroll
    for (int j = 0; j < 4; ++j) acc[i][j] = zero4;

  for (int k0 = 0; k0 < K; k0 += 32) {
    __syncthreads();
    stage16(A + (size_t)(bm + srow) * K + k0 + shalf, sA + srow * 32 + shalf);
    stage16(B + (size_t)(bn + srow) * K + k0 + shalf, sB + srow * 32 + shalf);
    __syncthreads();
    bf16x8 af[4], bg[4];
#pragma unroll
    for (int i = 0; i < 4; ++i) {
      af[i] = *(const bf16x8*)(sA + (wr * 64 + i * 16 + fr) * 32 + fq * 8);
      bg[i] = *(const bf16x8*)(sB + (wc * 64 + i * 16 + fr) * 32 + fq * 8);
    }
#pragma unroll
    for (int i = 0; i < 4; ++i)
#pragma unroll
      for (int j = 0; j < 4; ++j)
        acc[i][j] = __builtin_amdgcn_mfma_f32_16x16x32_bf16(af[i], bg[j], acc[i][j], 0, 0, 0);
  }

#pragma unroll
  for (int i = 0; i < 4; ++i)
#pragma unroll
    for (int j = 0; j < 4; ++j)
#pragma unroll
      for (int r = 0; r < 4; ++r) {
        int m = bm + wr * 64 + i * 16 + fq * 4 + r;
        int n = bn + wc * 64 + j * 16 + fr;
        float v = acc[i][j][r];
        if (MODE == 0) {
          stc(C + (size_t)m * N + n, v);
        } else if (MODE == 1) {
          int b = m >> 11, s = m & 2047, hh = n >> 7, d = n & 127;
          stc(C + (((size_t)(b * H + hh)) * S_LEN + s) * HD + d, v);
        } else {
          int b = m >> 11, s = m & 2047, hh = n >> 7, d = n & 127;
          stc(C + (((size_t)(b * H + hh)) * HD + d) * S_LEN + s, v);
        }
      }
}

// == causal GQA flash attention (paired q-blocks + 2-phase dbuf KV staging) ===
// Q_raw [B,32,S,128] (pre-rope), K [B,8,S,128] (rope'd), V^T [B,8,128,S].
// grid (8, B*32), block 256. Block processes q-tiles (15-bx) then bx: uniform
// 34 tile-units per block (round-26: zero makespan tail).
// NEW: K/V double-buffered with the T3 minimum-2-phase pattern — STAGE(t+1)
// issued BEFORE compute(t), ONE __syncthreads() per tile (its implicit
// vmcnt(0)+lgkmcnt(0)+s_barrier is exactly the required drain). Stage latency
// hides under QK^T+softmax+PV. LDS 72KB (grid gives 2 blocks/CU either way).
// Q-RoPE fused in-register. XOR swizzle granule^=(row&7) on K/V/P. Defer-max
// THR=8; l lane-local, epilogue-reduced; sP reused across u. T5 setprio.
__global__ __launch_bounds__(256, 2)
void attn_kernel(const u16* __restrict__ Q, const u16* __restrict__ K,
                 const u16* __restrict__ V, u16* __restrict__ O,
                 const float* __restrict__ sin_t, const float* __restrict__ cos_t,
                 float scale) {
  __shared__ u16 sK[2][64 * 128];  // [buf][kv][d], swizzled (32 KB)
  __shared__ u16 sV[2][128 * 64];  // [buf][d][kv], swizzled (32 KB)
  __shared__ u16 sP[4][16 * 64];   // per-wave P (16 rows, reused per u) (8 KB)

  const int tid = threadIdx.x, lane = tid & 63, wv = tid >> 6;
  const int fr = lane & 15, fq = lane >> 4;
  const int bx = blockIdx.x;            // 0..7
  const int bh = blockIdx.y;
  const int b = bh >> 5, h = bh & 31;
  const int hkv = h >> 2;
  const u16* Qb = Q + (size_t)bh * S_LEN * HD;
  const u16* Kb = K + (size_t)(b * NKVH + hkv) * S_LEN * HD;
  const u16* Vb = V + (size_t)(b * NKVH + hkv) * HD * S_LEN;

  // staging coords (constant per thread)
  const int krow_l = lane >> 4, ke_l = lane & 15;
  const int vrow_l = lane >> 3, ve_l = lane & 7;

  for (int half = 0; half < 2; ++half) {
    const int q0 = (half == 0 ? (15 - bx) : bx) * 128;  // long half first

    // Q fragments with fused RoPE + scale
    u16x8 qfu[2][4];
#pragma unroll
    for (int u = 0; u < 2; ++u) {
      int qrow = q0 + wv * 32 + u * 16 + fr;   // == s (0..2047)
      const u16* qp = Qb + (size_t)qrow * HD;
      u16x8 raw[4];
#pragma unroll
      for (int ks = 0; ks < 4; ++ks)
        raw[ks] = *(const u16x8*)(qp + ks * 32 + fq * 8);
#pragma unroll
      for (int p = 0; p < 2; ++p) {
        const float* cb = cos_t + (size_t)qrow * 64 + p * 32 + fq * 8;
        const float* sb = sin_t + (size_t)qrow * 64 + p * 32 + fq * 8;
        float4 c0 = ((const float4*)cb)[0], c1 = ((const float4*)cb)[1];
        float4 s0 = ((const float4*)sb)[0], s1 = ((const float4*)sb)[1];
        float cs[8] = {c0.x, c0.y, c0.z, c0.w, c1.x, c1.y, c1.z, c1.w};
        float sn[8] = {s0.x, s0.y, s0.z, s0.w, s1.x, s1.y, s1.z, s1.w};
#pragma unroll
        for (int j = 0; j < 8; ++j) {
          float lo = bf2f(raw[p][j]);
          float hi = bf2f(raw[p + 2][j]);
          qfu[u][p][j]     = f2bf((lo * cs[j] - hi * sn[j]) * scale);
          qfu[u][p + 2][j] = f2bf((hi * cs[j] + lo * sn[j]) * scale);
        }
      }
    }
    const bf16x8* qf0 = (const bf16x8*)&qfu[0][0];
    const bf16x8* qf1 = (const bf16x8*)&qfu[1][0];

    f32x4 zero4 = {0.f, 0.f, 0.f, 0.f};
    f32x4 o[2][8];
    float m[2][4], l[2][4];
#pragma unroll
    for (int u = 0; u < 2; ++u) {
#pragma unroll
      for (int dt = 0; dt < 8; ++dt) o[u][dt] = zero4;
#pragma unroll
      for (int r = 0; r < 4; ++r) { m[u][r] = -3.0e38f; l[u][r] = 0.f; }
    }

    const int ntiles = (q0 >> 6) + 2;

    // stage tile t into buffer buf: 8 gload16/thread (4 K + 4 V chunks)
    auto STAGE = [&](int buf, int t) {
      const int s0k = t * 64;
#pragma unroll
      for (int j = 0; j < 4; ++j) {
        int c = j * 4 + wv;
        {
          int row = c * 4 + krow_l;
          int e = (ke_l ^ (row & 7)) * 8;
          gload16(Kb + (size_t)(s0k + row) * HD + e, sK[buf] + c * 512);
        }
        {
          int row = c * 8 + vrow_l;
          int e = (ve_l ^ (row & 7)) * 8;
          gload16(Vb + (size_t)row * S_LEN + s0k + e, sV[buf] + c * 512);
        }
      }
    };

    STAGE(0, 0);
    __syncthreads();   // implicit vmcnt(0): tile 0 landed
    int cur = 0;

    for (int t = 0; t < ntiles; ++t) {
      const int s0 = t * 64;
      if (t + 1 < ntiles) STAGE(cur ^ 1, t + 1);  // issue next tile's loads NOW

      const u16* sKc = sK[cur];
      const u16* sVc = sV[cur];

      f32x4 sc[2][4];
#pragma unroll
      for (int u = 0; u < 2; ++u)
#pragma unroll
        for (int j = 0; j < 4; ++j) sc[u][j] = zero4;
      __builtin_amdgcn_s_setprio(1);
#pragma unroll
      for (int j = 0; j < 4; ++j) {
#pragma unroll
        for (int ks = 0; ks < 4; ++ks) {
          int row = j * 16 + fr;
          int e = (ks * 32 + fq * 8) ^ ((row & 7) << 3);
          bf16x8 kf = *(const bf16x8*)(sKc + row * 128 + e);
          sc[0][j] = __builtin_amdgcn_mfma_f32_16x16x32_bf16(qf0[ks], kf, sc[0][j], 0, 0, 0);
          sc[1][j] = __builtin_amdgcn_mfma_f32_16x16x32_bf16(qf1[ks], kf, sc[1][j], 0, 0, 0);
        }
      }
      __builtin_amdgcn_s_setprio(0);

      if (t >= ntiles - 2) {  // diagonal tiles: causal mask
#pragma unroll
        for (int u = 0; u < 2; ++u)
#pragma unroll
          for (int j = 0; j < 4; ++j)
#pragma unroll
            for (int r = 0; r < 4; ++r) {
              int kvp = s0 + j * 16 + fr;
              int qp = q0 + wv * 32 + u * 16 + fq * 4 + r;
              if (kvp > qp) sc[u][j][r] = -3.0e38f;
            }
      }

      // softmax + P-repack per u-fragment (sP reused across u)
      bf16x8 pa[2][2];
#pragma unroll
      for (int u = 0; u < 2; ++u) {
        float al[4];
        bool resc = false;
#pragma unroll
        for (int r = 0; r < 4; ++r) {
          float v = fmaxf(fmaxf(sc[u][0][r], sc[u][1][r]), fmaxf(sc[u][2][r], sc[u][3][r]));
          v = fmaxf(v, __shfl_xor(v, 1, 64));
          v = fmaxf(v, __shfl_xor(v, 2, 64));
          v = fmaxf(v, __shfl_xor(v, 4, 64));
          v = fmaxf(v, __shfl_xor(v, 8, 64));
          if (v > m[u][r] + 8.f) {
            al[r] = __expf(m[u][r] - v);
            m[u][r] = v;
            resc = true;
          } else {
            al[r] = 1.f;
          }
        }
#pragma unroll
        for (int r = 0; r < 4; ++r) {
          float rs = 0.f;
          int prow = fq * 4 + r;
#pragma unroll
          for (int j = 0; j < 4; ++j) {
            float pv = __expf(sc[u][j][r] - m[u][r]);
            rs += pv;
            int e = (j * 16 + fr) ^ ((prow & 7) << 3);
            sP[wv][prow * 64 + e] = f2bf(pv);
          }
          l[u][r] = l[u][r] * al[r] + rs;
        }
        if (resc) {
#pragma unroll
          for (int r = 0; r < 4; ++r)
#pragma unroll
            for (int dt = 0; dt < 8; ++dt) o[u][dt][r] *= al[r];
        }
#pragma unroll
        for (int ks = 0; ks < 2; ++ks) {
          int e = (ks * 32 + fq * 8) ^ ((fr & 7) << 3);
          pa[u][ks] = *(const bf16x8*)(&sP[wv][fr * 64 + e]);
        }
      }

      // PV: o[u][dt] rows q, cols d=dt*16+fr; each vf feeds both u-fragments
      __builtin_amdgcn_s_setprio(1);
#pragma unroll
      for (int dt = 0; dt < 8; ++dt) {
#pragma unroll
        for (int ks = 0; ks < 2; ++ks) {
          int row = dt * 16 + fr;
          int e = (ks * 32 + fq * 8) ^ ((row & 7) << 3);
          bf16x8 vf = *(const bf16x8*)(sVc + row * 64 + e);
#pragma unroll
          for (int u = 0; u < 2; ++u)
            o[u][dt] = __builtin_amdgcn_mfma_f32_16x16x32_bf16(pa[u][ks], vf, o[u][dt], 0, 0, 0);
        }
      }
      __builtin_amdgcn_s_setprio(0);

      __syncthreads();   // drains t+1 loads (vmcnt 0) + all reads of cur done
      cur ^= 1;
    }

#pragma unroll
    for (int u = 0; u < 2; ++u)
#pragma unroll
      for (int r = 0; r < 4; ++r) {
        float lt = l[u][r];
        lt += __shfl_xor(lt, 1, 64);
        lt += __shfl_xor(lt, 2, 64);
        lt += __shfl_xor(lt, 4, 64);
        lt += __shfl_xor(lt, 8, 64);
        int qp = q0 + wv * 32 + u * 16 + fq * 4 + r;
        float inv_l = 1.0f / lt;
        size_t base = ((size_t)b * S_LEN + qp) * DM + h * HD;
#pragma unroll
        for (int dt = 0; dt < 8; ++dt)
          O[base + dt * 16 + fr] = f2bf(o[u][dt][r] * inv_l);
      }
  }
}

extern "C" void kernel_launch(void* const* d_in, const int* in_sizes, int n_in,
                              void* d_out, int out_size, void* d_ws, size_t ws_size,
                              hipStream_t stream) {
  const float* x  = (const float*)d_in[0];
  const float* wq = (const float*)d_in[1];
  const float* wk = (const float*)d_in[2];
  const float* wv = (const float*)d_in[3];
  const float* wo = (const float*)d_in[4];

  char* ws = (char*)d_ws;
  size_t off = 0;
  auto alloc = [&](size_t bytes) {
    void* p = ws + off;
    off += (bytes + 255) & ~(size_t)255;
    return p;
  };

  const size_t nx  = (size_t)2 * S_LEN * DM;       // 16.78M elements
  const size_t nwq = (size_t)DM * DM;              // 16.78M
  const size_t nwk = (size_t)(NKVH * HD) * DM;     // 4.19M

  const float scale = 0.08838834764831845f;  // 1/sqrt(128), folded into Q-rope
  const int nrk = 2 * NKVH * S_LEN;
  dim3 blk(256);

  if (ws_size >= ((size_t)180 << 20)) {
    // -------- fast path: mega-cvt + fused QKV GEMM + fused Q-rope in attn ----
    u16* xb    = (u16*)alloc(nx * 2);                 // aob aliases after use
    u16* wqkvb = (u16*)alloc((nwq + 2 * nwk) * 2);    // [wq;wk;wv] 6144x4096
    u16* wob   = (u16*)alloc(nwq * 2);
    u16* qb    = (u16*)alloc(nx * 2);
    u16* kb    = (u16*)alloc(nwk * 2);
    u16* vtb   = (u16*)alloc(nwk * 2);
    float* sin_t = (float*)alloc((size_t)S_LEN * 64 * 4);
    float* cos_t = (float*)alloc((size_t)S_LEN * 64 * 4);
    u16* aob = xb;  // alias: x (bf16) dead after QKV projection

    cvt_all<<<2048, 256, 0, stream>>>(x, wq, wk, wv, wo, xb, wqkvb, wob);
    rope_table_kernel<<<(S_LEN * 64 + 255) / 256, 256, 0, stream>>>(sin_t, cos_t);

    gemm_qkv<<<dim3(48, 32), blk, 0, stream>>>(xb, wqkvb, qb, kb, vtb, DM);

    rope_apply<<<((size_t)nrk * 64 + 255) / 256, 256, 0, stream>>>(kb, sin_t, cos_t, 1.0f, nrk);

    attn_kernel<<<dim3(8, 64), blk, 0, stream>>>(qb, kb, vtb, aob, sin_t, cos_t, scale);

    gemm16<0, float><<<dim3(32, 32), blk, 0, stream>>>(aob, wob, (float*)d_out, 4096, DM, DM, 0);
  } else {
    // -------- fallback: proven round-10 path (f32 reg-staged GEMMs) --------
    u16* qb  = (u16*)alloc(nx * 2);
    u16* kb  = (u16*)alloc(nwk * 2);
    u16* vtb = (u16*)alloc(nwk * 2);
    u16* aob = (u16*)alloc(nx * 2);
    float* sin_t = (float*)alloc((size_t)S_LEN * 64 * 4);
    float* cos_t = (float*)alloc((size_t)S_LEN * 64 * 4);

    rope_table_kernel<<<(S_LEN * 64 + 255) / 256, 256, 0, stream>>>(sin_t, cos_t);

    gemm_bt<1, float, float, u16><<<dim3(32, 32), blk, 0, stream>>>(x, wq, qb, 4096, DM, DM, NQH);
    gemm_bt<1, float, float, u16><<<dim3(8, 32), blk, 0, stream>>>(x, wk, kb, 4096, 1024, DM, NKVH);
    gemm_bt<2, float, float, u16><<<dim3(8, 32), blk, 0, stream>>>(x, wv, vtb, 4096, 1024, DM, NKVH);

    rope_apply<<<((size_t)nrk * 64 + 255) / 256, 256, 0, stream>>>(kb, sin_t, cos_t, 1.0f, nrk);

    attn_kernel<<<dim3(8, 64), blk, 0, stream>>>(qb, kb, vtb, aob, sin_t, cos_t, scale);

    gemm_bt<0, u16, float, float><<<dim3(32, 32), blk, 0, stream>>>(aob, wo, (float*)d_out, 4096, DM, DM, 0);
  }
}